// Round 3
// baseline (355.287 us; speedup 1.0000x reference)
//
#include <hip/hip_runtime.h>

#define N_ 4096
#define DIM_ 512
#define H_ 8
#define DH_ 64
#define M_ 266
#define MP_ 272      // ksum/qp live range padded to 272 (17 tiles of 16)
#define MP2_ 288     // out-GEMM K padded to 9 chunks of 32
#define MP3_ 320     // ksuma / projp m padded to 5 chunks of 64
#define SLABM_ 280   // ctx partial-slab m extent (>= M_=266, trimmed to fit overlay)
#define NZ_ 8        // n-split for ctxfused
#define NT_ 16384
#define BH_ 32

#define NORMC 0.3535533905932738f   // 64^-0.25
#define RATIOC 0.06131393394849658f // 266^-0.5
#define EPSK 1e-4f
#define DIAGC 0.0625f               // 0.5 * normalizer^2
// folded exp2 constants: qp = exp2(min(raw*KA + Cl, LOG2R)) + REPS
#define KA 0.51006971f              // NORMC * log2(e)
#define LOG2R -4.0276408f           // log2(RATIOC)
#define LOG2E 1.4426950408889634f
#define REPS 6.131393e-6f           // RATIOC * EPSK

// ---- ws layout (byte offsets), total ~71.0 MB ----
// ctx slabs (18,350,080 B) overlay xbf+wqb+wkb+wvb, dead after qkv_mfma.
#define PROJP_B 0ul            // 40960
#define KMAX_B  40960ul        // 128
#define KSUMA_B 41088ul        // 40960
#define WO_B    82048ul        // 524288
#define CTXT_B  606336ul       // 1179648
#define DIAGQ_B 1785984ul      // 262144
#define DIAGK_B 2048128ul      // 262144
#define XBF_B   2310272ul      // 16777216
#define WQ_B    19087488ul     // 524288
#define WK_B    19611776ul     // 524288
#define WV_B    20136064ul     // 524288
#define CTXA_B  2310272ul      // == XBF_B, 32*8*280*64*4 = 18350080 (ends at Q_B)
#define Q_B     20660352ul     // 16777216
#define K_B     37437568ul     // 16777216
#define VT_B    54214784ul     // 16777216

typedef __bf16 bf16x8 __attribute__((ext_vector_type(8)));
typedef float f32x4 __attribute__((ext_vector_type(4)));
#define MFMA16(a, b, c) __builtin_amdgcn_mfma_f32_16x16x32_bf16((a), (b), (c), 0, 0, 0)

__device__ __forceinline__ float bfu(unsigned short u) {
  union { unsigned int i; float f; } x; x.i = ((unsigned int)u) << 16; return x.f;
}
__device__ __forceinline__ unsigned short f2bf(float f) {
  union { float f; unsigned int i; } u; u.f = f;
  unsigned int r = u.i + 0x7fffu + ((u.i >> 16) & 1u);
  return (unsigned short)(r >> 16);
}
__device__ __forceinline__ void atomicMaxF(float* addr, float val) {
  int* ai = (int*)addr;
  while (true) {
    float cur = __int_as_float(*(volatile int*)ai);
    if (val <= cur) break;
    int old = atomicCAS(ai, __float_as_int(cur), __float_as_int(val));
    if (old == __float_as_int(cur)) break;
  }
}

// ---------------- fp32 -> bf16 conversion ----------------
__global__ void cvt_kernel(const float* __restrict__ src, unsigned short* __restrict__ dst, int n) {
  int i = (blockIdx.x * 256 + threadIdx.x) * 4;
  const int stride = gridDim.x * 1024;
  for (; i < n; i += stride) {
    const float4 v = *(const float4*)(src + i);
    ushort4 u;
    u.x = f2bf(v.x); u.y = f2bf(v.y); u.z = f2bf(v.z); u.w = f2bf(v.w);
    *(ushort4*)(dst + i) = u;
  }
}

// ---------------- setup: proj cvt+pad(320), kmax init, ksuma zero ----------------
__global__ void setup_kernel(const float* __restrict__ proj,
                             unsigned short* __restrict__ projp,
                             float* __restrict__ kmax,
                             float* __restrict__ ksuma) {
  const int i = blockIdx.x * 256 + threadIdx.x;
  const int stride = gridDim.x * 256;
  for (int j = i; j < MP3_ * DH_; j += stride)
    projp[j] = (j < M_ * DH_) ? f2bf(proj[j]) : (unsigned short)0;
  for (int j = i; j < BH_; j += stride) kmax[j] = -3e38f;
  for (int j = i; j < BH_ * MP3_; j += stride) ksuma[j] = 0.f;
}

// ---------------- QKV projection: 128x128 LDS-staged MFMA GEMM ----------------
__global__ __launch_bounds__(256) void qkv_mfma(
    const unsigned short* __restrict__ x, const unsigned short* __restrict__ Wq,
    const unsigned short* __restrict__ Wk, const unsigned short* __restrict__ Wv,
    unsigned short* __restrict__ Q, unsigned short* __restrict__ K,
    unsigned short* __restrict__ VT) {
  __shared__ unsigned short As[128 * 64];
  __shared__ unsigned short Bs[128 * 64];
  const int z = blockIdx.z;
  const unsigned short* W = (z == 0) ? Wq : (z == 1) ? Wk : Wv;
  const int t0 = blockIdx.x * 128, e0 = blockIdx.y * 128;
  const int tid = threadIdx.x;
  const int wv = tid >> 6, lane = tid & 63;
  const int r = lane & 15, q = lane >> 4;
  const int wr = (wv >> 1) * 64, wc = (wv & 1) * 64;
  f32x4 acc[4][4];
#pragma unroll
  for (int i = 0; i < 4; ++i)
#pragma unroll
    for (int j = 0; j < 4; ++j) acc[i][j] = (f32x4){0.f, 0.f, 0.f, 0.f};
  const int srow = tid >> 3, scol = (tid & 7) * 8;
  for (int k0 = 0; k0 < DIM_; k0 += 64) {
#pragma unroll
    for (int j = 0; j < 4; ++j) {
      const int rr = srow + j * 32;
      *(uint4*)&As[rr * 64 + scol] = *(const uint4*)&x[(size_t)(t0 + rr) * DIM_ + k0 + scol];
      *(uint4*)&Bs[rr * 64 + scol] = *(const uint4*)&W[(size_t)(e0 + rr) * DIM_ + k0 + scol];
    }
    __syncthreads();
#pragma unroll
    for (int kc = 0; kc < 2; ++kc) {
      bf16x8 af[4], bfr[4];
#pragma unroll
      for (int rt = 0; rt < 4; ++rt)
        af[rt] = *(const bf16x8*)&As[(wr + rt * 16 + r) * 64 + kc * 32 + q * 8];
#pragma unroll
      for (int ct = 0; ct < 4; ++ct)
        bfr[ct] = *(const bf16x8*)&Bs[(wc + ct * 16 + r) * 64 + kc * 32 + q * 8];
#pragma unroll
      for (int rt = 0; rt < 4; ++rt)
#pragma unroll
        for (int ct = 0; ct < 4; ++ct)
          acc[rt][ct] = MFMA16(af[rt], bfr[ct], acc[rt][ct]);
    }
    __syncthreads();
  }
  if (z < 2) {
    unsigned short* dst = (z == 0) ? Q : K;
#pragma unroll
    for (int rt = 0; rt < 4; ++rt) {
#pragma unroll
      for (int ct = 0; ct < 4; ++ct) {
        const int e = e0 + wc + ct * 16 + r;
#pragma unroll
        for (int i = 0; i < 4; ++i) {
          const int t = t0 + wr + rt * 16 + q * 4 + i;
          dst[(size_t)t * DIM_ + e] = f2bf(acc[rt][ct][i]);
        }
      }
    }
  } else {
#pragma unroll
    for (int rt = 0; rt < 4; ++rt) {
      const int t = t0 + wr + rt * 16 + q * 4;
      const int b_ = t >> 12, n = t & (N_ - 1);
#pragma unroll
      for (int ct = 0; ct < 4; ++ct) {
        const int e = e0 + wc + ct * 16 + r;
        const int h = e >> 6, dh = e & 63;
        ushort4 pk;
        pk.x = f2bf(acc[rt][ct][0]); pk.y = f2bf(acc[rt][ct][1]);
        pk.z = f2bf(acc[rt][ct][2]); pk.w = f2bf(acc[rt][ct][3]);
        *(ushort4*)&VT[((size_t)((b_ * H_ + h) * DH_ + dh)) * N_ + n] = pk;
      }
    }
  }
}

// ---------------- diag: DIAGC * sum(t*t) per (bh, n), stored bf16 ----------------
__global__ void diag_kernel(const unsigned short* __restrict__ Q,
                            const unsigned short* __restrict__ K,
                            unsigned short* __restrict__ dq, unsigned short* __restrict__ dk) {
  const int i = blockIdx.x * 256 + threadIdx.x;
  const int bh = i >> 12, n = i & (N_ - 1);
  const int b_ = bh >> 3, h = bh & 7;
  const unsigned short* src = ((blockIdx.y == 0) ? Q : K) + (size_t)(b_ * N_ + n) * DIM_ + h * DH_;
  float s = 0.f;
#pragma unroll
  for (int c = 0; c < 16; ++c) {
    const ushort4 u = ((const ushort4*)src)[c];
    const float a = bfu(u.x), b2 = bfu(u.y), cc = bfu(u.z), d = bfu(u.w);
    s += a * a + b2 * b2 + cc * cc + d * d;
  }
  ((blockIdx.y == 0) ? dq : dk)[i] = f2bf(s * DIAGC);
}

// ---------------- kmax (MFMA): 2 n-strips per wave, 68 MFMAs/wave ----------------
__global__ __launch_bounds__(256) void kmax_mfma(
    const unsigned short* __restrict__ K, const unsigned short* __restrict__ projp,
    float* __restrict__ kmax) {
  const int bh = blockIdx.x, n0 = blockIdx.y * 128;
  const int wv = threadIdx.x >> 6, lane = threadIdx.x & 63;
  const int r = lane & 15, q = lane >> 4;
  const int b_ = bh >> 3, h = bh & 7;
  bf16x8 kb[2][2];
#pragma unroll
  for (int nt = 0; nt < 2; ++nt) {
    const int n = n0 + wv * 32 + nt * 16 + r;
    const unsigned short* krow = K + (size_t)(b_ * N_ + n) * DIM_ + h * DH_;
    kb[nt][0] = *(const bf16x8*)(krow + q * 8);
    kb[nt][1] = *(const bf16x8*)(krow + 32 + q * 8);
  }
  float runmax = -3e38f;
  for (int mt = 0; mt < 17; ++mt) {
    const unsigned short* prow = projp + (size_t)(mt * 16 + r) * DH_;
    const bf16x8 a0 = *(const bf16x8*)(prow + q * 8);
    const bf16x8 a1 = *(const bf16x8*)(prow + 32 + q * 8);
#pragma unroll
    for (int nt = 0; nt < 2; ++nt) {
      f32x4 acc = (f32x4){0.f, 0.f, 0.f, 0.f};
      acc = MFMA16(a0, kb[nt][0], acc);
      acc = MFMA16(a1, kb[nt][1], acc);
#pragma unroll
      for (int i = 0; i < 4; ++i) {
        const int m = mt * 16 + q * 4 + i;
        if (m < M_) runmax = fmaxf(runmax, acc[i]);
      }
    }
  }
  for (int s2 = 1; s2 < 64; s2 <<= 1) runmax = fmaxf(runmax, __shfl_xor(runmax, s2, 64));
  __shared__ float wm[4];
  if (lane == 0) wm[wv] = runmax;
  __syncthreads();
  if (threadIdx.x == 0) {
    const float m = fmaxf(fmaxf(wm[0], wm[1]), fmaxf(wm[2], wm[3])) * NORMC;
    atomicMaxF(&kmax[bh], m);
  }
}

// ---------------- fused: td -> exp -> kp; ctx += kp x VT; ksum ----------------
__global__ __launch_bounds__(256) void ctxfused_mfma(
    const unsigned short* __restrict__ K, const unsigned short* __restrict__ VT,
    const unsigned short* __restrict__ projp, const unsigned short* __restrict__ diag_k,
    const float* __restrict__ kmaxv, float* __restrict__ ksuma,
    float* __restrict__ slab) {
  __shared__ unsigned short kll[64][72];
  __shared__ unsigned short vtl[64][72];
  __shared__ unsigned short kpl[64][72];
  __shared__ float dgl[64];
  const int bh = blockIdx.x, m0 = blockIdx.y * 64, zi = blockIdx.z;
  const int nbase = zi * 512;
  const int tid = threadIdx.x;
  const int wv = tid >> 6, lane = tid & 63;
  const int r = lane & 15, q = lane >> 4;
  const int b_ = bh >> 3, h = bh & 7;
  const float km = kmaxv[bh];
  const unsigned short* prow = projp + (size_t)(m0 + wv * 16 + r) * DH_;
  const bf16x8 p0 = *(const bf16x8*)(prow + q * 8);
  const bf16x8 p1 = *(const bf16x8*)(prow + 32 + q * 8);
  const unsigned short* kbase = K + (size_t)(b_ * N_) * DIM_ + h * DH_;
  const unsigned short* vbase = VT + (size_t)bh * DH_ * N_;
  f32x4 cacc[4];
#pragma unroll
  for (int i = 0; i < 4; ++i) cacc[i] = (f32x4){0.f, 0.f, 0.f, 0.f};
  float ksa[4] = {0.f, 0.f, 0.f, 0.f};
  for (int nc = 0; nc < 8; ++nc) {
    const int n0c = nbase + nc * 64;
#pragma unroll
    for (int j = 0; j < 4; ++j) {
      const int idx = tid + j * 256;
      const int rr = idx >> 4, c4 = (idx & 15) << 2;
      *(ushort4*)&kll[rr][c4] = *(const ushort4*)&kbase[(size_t)(n0c + rr) * DIM_ + c4];
      *(ushort4*)&vtl[rr][c4] = *(const ushort4*)&vbase[(size_t)rr * N_ + n0c + c4];
    }
    if (tid < 16) {
      const ushort4 du = *(const ushort4*)&diag_k[bh * N_ + n0c + tid * 4];
      dgl[tid * 4 + 0] = bfu(du.x); dgl[tid * 4 + 1] = bfu(du.y);
      dgl[tid * 4 + 2] = bfu(du.z); dgl[tid * 4 + 3] = bfu(du.w);
    }
    __syncthreads();
#pragma unroll
    for (int nt = 0; nt < 4; ++nt) {
      const bf16x8 kb0 = *(const bf16x8*)&kll[nt * 16 + r][q * 8];
      const bf16x8 kb1 = *(const bf16x8*)&kll[nt * 16 + r][32 + q * 8];
      f32x4 acc = (f32x4){0.f, 0.f, 0.f, 0.f};
      acc = MFMA16(p0, kb0, acc);
      acc = MFMA16(p1, kb1, acc);
      const float dgk = dgl[nt * 16 + r];
#pragma unroll
      for (int i = 0; i < 4; ++i) {
        const int m = m0 + wv * 16 + q * 4 + i;
        float kp = 0.f;
        if (m < M_) {
          const float arg = fminf(NORMC * acc[i] - dgk - km, 0.f);
          kp = RATIOC * (__expf(arg) + EPSK);
        }
        kpl[wv * 16 + q * 4 + i][nt * 16 + r] = f2bf(kp);
        ksa[i] += kp;
      }
    }
    __syncthreads();
    {
      const bf16x8 a0 = *(const bf16x8*)&kpl[wv * 16 + r][q * 8];
      const bf16x8 a1 = *(const bf16x8*)&kpl[wv * 16 + r][32 + q * 8];
#pragma unroll
      for (int ct = 0; ct < 4; ++ct) {
        const bf16x8 b0 = *(const bf16x8*)&vtl[ct * 16 + r][q * 8];
        const bf16x8 b1 = *(const bf16x8*)&vtl[ct * 16 + r][32 + q * 8];
        cacc[ct] = MFMA16(a0, b0, cacc[ct]);
        cacc[ct] = MFMA16(a1, b1, cacc[ct]);
      }
    }
    __syncthreads();
  }
#pragma unroll
  for (int i = 0; i < 4; ++i)
    for (int s2 = 1; s2 < 16; s2 <<= 1) ksa[i] += __shfl_xor(ksa[i], s2, 64);
  if (r == 0) {
#pragma unroll
    for (int i = 0; i < 4; ++i)
      atomicAdd(&ksuma[bh * MP3_ + m0 + wv * 16 + q * 4 + i], ksa[i]);
  }
  float* sl = slab + (size_t)(bh * NZ_ + zi) * SLABM_ * DH_;
#pragma unroll
  for (int ct = 0; ct < 4; ++ct) {
#pragma unroll
    for (int i = 0; i < 4; ++i) {
      const int m = m0 + wv * 16 + q * 4 + i;
      if (m < SLABM_) sl[(size_t)m * DH_ + ct * 16 + r] = cacc[ct][i];
    }
  }
}

// ---------------- pack: reduce 8 z-slabs [m][d] fp32 -> transpose -> ctxT [d][288] bf16 ----
__global__ __launch_bounds__(256) void pack_kernel(const float* __restrict__ slab,
                                                   unsigned short* __restrict__ ctxT) {
  __shared__ float t[64][65];
  const int bh = blockIdx.x, m0 = blockIdx.y * 64;
  const int tid = threadIdx.x;
  const int mr = tid >> 4, d4 = (tid & 15) * 4;
#pragma unroll
  for (int pass = 0; pass < 4; ++pass) {
    const int ml = pass * 16 + mr;
    const int m = m0 + ml;
    float4 s = {0.f, 0.f, 0.f, 0.f};
    if (m < SLABM_) {
#pragma unroll
      for (int z = 0; z < NZ_; ++z) {
        const float4 v =
            *(const float4*)&slab[((size_t)(bh * NZ_ + z) * SLABM_ + m) * DH_ + d4];
        s.x += v.x; s.y += v.y; s.z += v.z; s.w += v.w;
      }
    }
    t[ml][d4 + 0] = s.x; t[ml][d4 + 1] = s.y; t[ml][d4 + 2] = s.z; t[ml][d4 + 3] = s.w;
  }
  __syncthreads();
  const int mc = tid & 63, dbase = tid >> 6;
  const int mo = m0 + mc;
  if (mo < MP2_) {
#pragma unroll
    for (int j = 0; j < 16; ++j) {
      const int d = dbase + j * 4;
      ctxT[((size_t)bh * DH_ + d) * MP2_ + mo] = f2bf(t[mc][d]);
    }
  }
}

// ---------------- fused QP + out GEMM: swapped-operand, two-pass recompute ----------------
// Pass 1: mfma(proj, Q) with only a running per-n max (no big live arrays).
// Pass 2: recompute td (independent loads via projp2 defeat CSE), fuse
// exp2+cvt_pk and write packed qp rows straight into a WAVE-PRIVATE LDS tile
// [16 n-rows][148 u32]; denominator partial accumulated in the same loop.
// Phase C: A-fragments via ds_read_b128 from own tile -- no barriers, no shuffles.
__global__ __launch_bounds__(256) void qpout_mfma(
    const unsigned short* __restrict__ Qb, const unsigned short* __restrict__ projp,
    const unsigned short* projp2,
    const unsigned short* __restrict__ diag_q, const float* __restrict__ ksuma,
    const unsigned short* __restrict__ ctxT, unsigned short* __restrict__ attn) {
  __shared__ unsigned int qps[4][16][148];  // per-wave tile, row stride 148 u32 (592 B)
  const int bh = blockIdx.x, n0 = blockIdx.y * 64;
  const int wv = threadIdx.x >> 6, lane = threadIdx.x & 63;
  const int r = lane & 15, q = lane >> 4;
  const int b_ = bh >> 3, h = bh & 7;
  // zero-fill u32 cols 136..143 (bf16 cols 272..287; ctxT is 0 there but avoid NaN*0)
  *(uint2*)&qps[wv][r][136 + q * 2] = make_uint2(0u, 0u);
  bf16x8 qb0, qb1;
  {
    const unsigned short* qrow = Qb + (size_t)(b_ * N_ + n0 + wv * 16 + r) * DIM_ + h * DH_;
    qb0 = *(const bf16x8*)(qrow + q * 8);
    qb1 = *(const bf16x8*)(qrow + 32 + q * 8);
  }
  // pass 1: rm = max over valid m of raw td for this lane's n (= n0 + wv*16 + r)
  float rm = -3e38f;
#pragma unroll
  for (int mt = 0; mt < 17; ++mt) {
    const unsigned short* prow = projp + (size_t)(mt * 16 + r) * DH_;
    const bf16x8 p0 = *(const bf16x8*)(prow + q * 8);
    const bf16x8 p1 = *(const bf16x8*)(prow + 32 + q * 8);
    f32x4 acc = (f32x4){0.f, 0.f, 0.f, 0.f};
    acc = MFMA16(p0, qb0, acc);
    acc = MFMA16(p1, qb1, acc);
    if (mt < 16) {
      rm = fmaxf(rm, fmaxf(fmaxf(acc[0], acc[1]), fmaxf(acc[2], acc[3])));
    } else {
#pragma unroll
      for (int i = 0; i < 4; ++i)
        if (q * 4 + i < 10) rm = fmaxf(rm, acc[i]);  // m = 256+q*4+i valid iff < 266
    }
  }
  rm = fmaxf(rm, __shfl_xor(rm, 16, 64));
  rm = fmaxf(rm, __shfl_xor(rm, 32, 64));
  const float dg = bfu(diag_q[bh * N_ + n0 + wv * 16 + r]);
  const float Cl = LOG2R - dg * LOG2E - rm * KA;
  asm volatile("" : "+v"(qb0), "+v"(qb1));  // block CSE of pass-2 MFMAs with pass 1
  // pass 2: recompute td, exp+pack -> LDS, denominator partial (rounded qp)
  float part = 0.f;
#pragma unroll
  for (int mt = 0; mt < 17; ++mt) {
    const unsigned short* prow = projp2 + (size_t)(mt * 16 + r) * DH_;
    const bf16x8 p0 = *(const bf16x8*)(prow + q * 8);
    const bf16x8 p1 = *(const bf16x8*)(prow + 32 + q * 8);
    f32x4 acc = (f32x4){0.f, 0.f, 0.f, 0.f};
    acc = MFMA16(p0, qb0, acc);
    acc = MFMA16(p1, qb1, acc);
    const f32x4 kl = *(const f32x4*)&ksuma[bh * MP3_ + mt * 16 + q * 4];
    unsigned int pkw0, pkw1;
    {
      const float s0 = fminf(acc[0] * KA + Cl, LOG2R);
      const float s1 = fminf(acc[1] * KA + Cl, LOG2R);
      const float e0 = exp2f(s0) + REPS;
      const float e1 = exp2f(s1) + REPS;
      asm("v_cvt_pk_bf16_f32 %0, %1, %2" : "=v"(pkw0) : "v"(e0), "v"(e1));
      union { unsigned int u; float f; } lo, hi;
      lo.u = pkw0 << 16; hi.u = pkw0 & 0xffff0000u;
      part += lo.f * kl[0] + hi.f * kl[1];
    }
    {
      const float s0 = fminf(acc[2] * KA + Cl, LOG2R);
      const float s1 = fminf(acc[3] * KA + Cl, LOG2R);
      const float e0 = exp2f(s0) + REPS;
      const float e1 = exp2f(s1) + REPS;
      asm("v_cvt_pk_bf16_f32 %0, %1, %2" : "=v"(pkw1) : "v"(e0), "v"(e1));
      union { unsigned int u; float f; } lo, hi;
      lo.u = pkw1 << 16; hi.u = pkw1 & 0xffff0000u;
      part += lo.f * kl[2] + hi.f * kl[3];
    }
    // row = n-local (r), bf16 cols m = mt*16 + q*4 .. +3  -> u32 cols mt*8 + q*2
    *(uint2*)&qps[wv][r][mt * 8 + q * 2] = make_uint2(pkw0, pkw1);
  }
  part += __shfl_xor(part, 16, 64);
  part += __shfl_xor(part, 32, 64);
  const float dinv = 1.f / fmaxf(part, 1e-30f);
  // Phase C: out = qp . ctxT (K = 288); A-frags from wave-private LDS tile
  f32x4 oacc[4];
#pragma unroll
  for (int i = 0; i < 4; ++i) oacc[i] = (f32x4){0.f, 0.f, 0.f, 0.f};
  const unsigned short* cbase = ctxT + (size_t)bh * DH_ * MP2_;
#pragma unroll
  for (int kc = 0; kc < 9; ++kc) {
    const bf16x8 af = *(const bf16x8*)&qps[wv][r][kc * 16 + q * 4];
#pragma unroll
    for (int dt = 0; dt < 4; ++dt) {
      const bf16x8 bfr = *(const bf16x8*)&cbase[(size_t)(dt * 16 + r) * MP2_ + kc * 32 + q * 8];
      oacc[dt] = MFMA16(af, bfr, oacc[dt]);
    }
  }
  // dinv lives at lane with r = n-local; output rows n-local = q*4+i
  float dv[4];
#pragma unroll
  for (int i = 0; i < 4; ++i)
    dv[i] = __shfl(dinv, (lane & 48) | (q * 4 + i), 64);
#pragma unroll
  for (int dt = 0; dt < 4; ++dt) {
    const int d = dt * 16 + r;
#pragma unroll
    for (int i = 0; i < 4; ++i) {
      const int nn = wv * 16 + q * 4 + i;
      attn[(size_t)(b_ * N_ + n0 + nn) * DIM_ + h * DH_ + d] = f2bf(oacc[dt][i] * dv[i]);
    }
  }
}

// ---------------- final: 128x128 LDS-staged MFMA GEMM + residual (fp32 I/O) ----------------
__global__ __launch_bounds__(256) void final_mfma(
    const unsigned short* __restrict__ attn, const unsigned short* __restrict__ Wo,
    const float* __restrict__ bo, const float* __restrict__ x,
    float* __restrict__ out) {
  __shared__ unsigned short As[128 * 64];
  __shared__ unsigned short Bs[128 * 64];
  const int t0 = blockIdx.x * 128, e0 = blockIdx.y * 128;
  const int tid = threadIdx.x;
  const int wv = tid >> 6, lane = tid & 63;
  const int r = lane & 15, q = lane >> 4;
  const int wr = (wv >> 1) * 64, wc = (wv & 1) * 64;
  f32x4 acc[4][4];
#pragma unroll
  for (int i = 0; i < 4; ++i)
#pragma unroll
    for (int j = 0; j < 4; ++j) acc[i][j] = (f32x4){0.f, 0.f, 0.f, 0.f};
  const int srow = tid >> 3, scol = (tid & 7) * 8;
  for (int k0 = 0; k0 < DIM_; k0 += 64) {
#pragma unroll
    for (int j = 0; j < 4; ++j) {
      const int rr = srow + j * 32;
      *(uint4*)&As[rr * 64 + scol] = *(const uint4*)&attn[(size_t)(t0 + rr) * DIM_ + k0 + scol];
      *(uint4*)&Bs[rr * 64 + scol] = *(const uint4*)&Wo[(size_t)(e0 + rr) * DIM_ + k0 + scol];
    }
    __syncthreads();
#pragma unroll
    for (int kc = 0; kc < 2; ++kc) {
      bf16x8 af[4], bfr[4];
#pragma unroll
      for (int rt = 0; rt < 4; ++rt)
        af[rt] = *(const bf16x8*)&As[(wr + rt * 16 + r) * 64 + kc * 32 + q * 8];
#pragma unroll
      for (int ct = 0; ct < 4; ++ct)
        bfr[ct] = *(const bf16x8*)&Bs[(wc + ct * 16 + r) * 64 + kc * 32 + q * 8];
#pragma unroll
      for (int rt = 0; rt < 4; ++rt)
#pragma unroll
        for (int ct = 0; ct < 4; ++ct)
          acc[rt][ct] = MFMA16(af[rt], bfr[ct], acc[rt][ct]);
    }
    __syncthreads();
  }
#pragma unroll
  for (int rt = 0; rt < 4; ++rt) {
#pragma unroll
    for (int ct = 0; ct < 4; ++ct) {
      const int c = e0 + wc + ct * 16 + r;
      const float bov = bo[c];
#pragma unroll
      for (int i = 0; i < 4; ++i) {
        const int t = t0 + wr + rt * 16 + q * 4 + i;
        out[(size_t)t * DIM_ + c] = acc[rt][ct][i] + bov + x[(size_t)t * DIM_ + c];
      }
    }
  }
}

extern "C" void kernel_launch(void* const* d_in, const int* in_sizes, int n_in,
                              void* d_out, int out_size, void* d_ws, size_t ws_size,
                              hipStream_t stream) {
  const float* x = (const float*)d_in[0];
  const float* Wq = (const float*)d_in[1];
  const float* Wk = (const float*)d_in[2];
  const float* Wv = (const float*)d_in[3];
  const float* Wo = (const float*)d_in[4];
  const float* bo = (const float*)d_in[5];
  const float* proj = (const float*)d_in[6];
  char* ws = (char*)d_ws;
  unsigned short* projp = (unsigned short*)(ws + PROJP_B);
  float* kmax = (float*)(ws + KMAX_B);
  float* ksuma = (float*)(ws + KSUMA_B);
  float* ctxa = (float*)(ws + CTXA_B);
  unsigned short* ctxT = (unsigned short*)(ws + CTXT_B);
  unsigned short* diag_q = (unsigned short*)(ws + DIAGQ_B);
  unsigned short* diag_k = (unsigned short*)(ws + DIAGK_B);
  unsigned short* xbf = (unsigned short*)(ws + XBF_B);
  unsigned short* wqb = (unsigned short*)(ws + WQ_B);
  unsigned short* wkb = (unsigned short*)(ws + WK_B);
  unsigned short* wvb = (unsigned short*)(ws + WV_B);
  unsigned short* wob = (unsigned short*)(ws + WO_B);
  unsigned short* Q = (unsigned short*)(ws + Q_B);
  unsigned short* K = (unsigned short*)(ws + K_B);
  unsigned short* VT = (unsigned short*)(ws + VT_B);
  unsigned short* attn = K;  // K dead after ctxfused_mfma
  float* out = (float*)d_out;

  cvt_kernel<<<1024, 256, 0, stream>>>(x, xbf, 8388608);
  cvt_kernel<<<128, 256, 0, stream>>>(Wq, wqb, 262144);
  cvt_kernel<<<128, 256, 0, stream>>>(Wk, wkb, 262144);
  cvt_kernel<<<128, 256, 0, stream>>>(Wv, wvb, 262144);
  cvt_kernel<<<128, 256, 0, stream>>>(Wo, wob, 262144);
  setup_kernel<<<80, 256, 0, stream>>>(proj, projp, kmax, ksuma);
  qkv_mfma<<<dim3(NT_ / 128, DIM_ / 128, 3), 256, 0, stream>>>(xbf, wqb, wkb, wvb, Q, K, VT);
  diag_kernel<<<dim3(512, 2), 256, 0, stream>>>(Q, K, diag_q, diag_k);
  kmax_mfma<<<dim3(BH_, 32), 256, 0, stream>>>(K, projp, kmax);
  ctxfused_mfma<<<dim3(BH_, 5, NZ_), 256, 0, stream>>>(K, VT, projp, diag_k, kmax, ksuma, ctxa);
  pack_kernel<<<dim3(BH_, 5), 256, 0, stream>>>(ctxa, ctxT);
  qpout_mfma<<<dim3(BH_, 64), 256, 0, stream>>>(Q, projp, projp, diag_q, ksuma, ctxT, attn);
  final_mfma<<<dim3(NT_ / 128, DIM_ / 128), 256, 0, stream>>>(attn, wob, bo, x, out);
}

// Round 4
// 336.003 us; speedup vs baseline: 1.0574x; 1.0574x over previous
//
#include <hip/hip_runtime.h>

#define N_ 4096
#define DIM_ 512
#define H_ 8
#define DH_ 64
#define M_ 266
#define MP_ 272      // ksum/qp live range padded to 272 (17 tiles of 16)
#define MP2_ 288     // out-GEMM K padded to 9 chunks of 32
#define MP3_ 320     // ksuma / projp m padded to 5 chunks of 64
#define SLABM_ 280   // ctx partial-slab m extent (>= M_=266, trimmed to fit overlay)
#define NZ_ 8        // n-split for ctxfused
#define NT_ 16384
#define BH_ 32

#define NORMC 0.3535533905932738f   // 64^-0.25
#define RATIOC 0.06131393394849658f // 266^-0.5
#define EPSK 1e-4f
#define DIAGC 0.0625f               // 0.5 * normalizer^2
// folded exp2 constants: qp = exp2(min(raw*KA + Cl, LOG2R)) + REPS
#define KA 0.51006971f              // NORMC * log2(e)
#define LOG2R -4.0276408f           // log2(RATIOC)
#define LOG2E 1.4426950408889634f
#define REPS 6.131393e-6f           // RATIOC * EPSK

// ---- ws layout (byte offsets), total ~71.5 MB ----
// ctx slabs (18,350,080 B) overlay xbf+wqb+wkb+wvb, dead after qkv_mfma.
#define PROJP_B 0ul            // 40960
#define KMAX_B  40960ul        // 128
#define KSUMA_B 41088ul        // 40960
#define WO_B    82048ul        // 524288
#define CTXT_B  606336ul       // 1179648
#define DIAGQ_B 1785984ul      // 262144
#define DIAGK_B 2048128ul      // 262144
#define XBF_B   2310272ul      // 16777216
#define WQ_B    19087488ul     // 524288
#define WK_B    19611776ul     // 524288
#define WV_B    20136064ul     // 524288
#define CTXA_B  2310272ul      // == XBF_B, 32*8*280*64*4 = 18350080 (ends at Q_B)
#define Q_B     20660352ul     // 16777216
#define K_B     37437568ul     // 16777216
#define VT_B    54214784ul     // 16777216
#define RMAXQ_B 70992000ul     // 524288 (32*4096 f32) -> end 71,516,288

typedef __bf16 bf16x8 __attribute__((ext_vector_type(8)));
typedef float f32x4 __attribute__((ext_vector_type(4)));
#define MFMA16(a, b, c) __builtin_amdgcn_mfma_f32_16x16x32_bf16((a), (b), (c), 0, 0, 0)

__device__ __forceinline__ float bfu(unsigned short u) {
  union { unsigned int i; float f; } x; x.i = ((unsigned int)u) << 16; return x.f;
}
__device__ __forceinline__ unsigned short f2bf(float f) {
  union { float f; unsigned int i; } u; u.f = f;
  unsigned int r = u.i + 0x7fffu + ((u.i >> 16) & 1u);
  return (unsigned short)(r >> 16);
}
__device__ __forceinline__ void atomicMaxF(float* addr, float val) {
  int* ai = (int*)addr;
  while (true) {
    float cur = __int_as_float(*(volatile int*)ai);
    if (val <= cur) break;
    int old = atomicCAS(ai, __float_as_int(cur), __float_as_int(val));
    if (old == __float_as_int(cur)) break;
  }
}

// ---------------- fp32 -> bf16 conversion ----------------
__global__ void cvt_kernel(const float* __restrict__ src, unsigned short* __restrict__ dst, int n) {
  int i = (blockIdx.x * 256 + threadIdx.x) * 4;
  const int stride = gridDim.x * 1024;
  for (; i < n; i += stride) {
    const float4 v = *(const float4*)(src + i);
    ushort4 u;
    u.x = f2bf(v.x); u.y = f2bf(v.y); u.z = f2bf(v.z); u.w = f2bf(v.w);
    *(ushort4*)(dst + i) = u;
  }
}

// ---------------- setup: proj cvt+pad(320), kmax init, ksuma zero ----------------
__global__ void setup_kernel(const float* __restrict__ proj,
                             unsigned short* __restrict__ projp,
                             float* __restrict__ kmax,
                             float* __restrict__ ksuma) {
  const int i = blockIdx.x * 256 + threadIdx.x;
  const int stride = gridDim.x * 256;
  for (int j = i; j < MP3_ * DH_; j += stride)
    projp[j] = (j < M_ * DH_) ? f2bf(proj[j]) : (unsigned short)0;
  for (int j = i; j < BH_; j += stride) kmax[j] = -3e38f;
  for (int j = i; j < BH_ * MP3_; j += stride) ksuma[j] = 0.f;
}

// ---------------- QKV projection: 128x128 LDS-staged MFMA GEMM ----------------
__global__ __launch_bounds__(256) void qkv_mfma(
    const unsigned short* __restrict__ x, const unsigned short* __restrict__ Wq,
    const unsigned short* __restrict__ Wk, const unsigned short* __restrict__ Wv,
    unsigned short* __restrict__ Q, unsigned short* __restrict__ K,
    unsigned short* __restrict__ VT) {
  __shared__ unsigned short As[128 * 64];
  __shared__ unsigned short Bs[128 * 64];
  const int z = blockIdx.z;
  const unsigned short* W = (z == 0) ? Wq : (z == 1) ? Wk : Wv;
  const int t0 = blockIdx.x * 128, e0 = blockIdx.y * 128;
  const int tid = threadIdx.x;
  const int wv = tid >> 6, lane = tid & 63;
  const int r = lane & 15, q = lane >> 4;
  const int wr = (wv >> 1) * 64, wc = (wv & 1) * 64;
  f32x4 acc[4][4];
#pragma unroll
  for (int i = 0; i < 4; ++i)
#pragma unroll
    for (int j = 0; j < 4; ++j) acc[i][j] = (f32x4){0.f, 0.f, 0.f, 0.f};
  const int srow = tid >> 3, scol = (tid & 7) * 8;
  for (int k0 = 0; k0 < DIM_; k0 += 64) {
#pragma unroll
    for (int j = 0; j < 4; ++j) {
      const int rr = srow + j * 32;
      *(uint4*)&As[rr * 64 + scol] = *(const uint4*)&x[(size_t)(t0 + rr) * DIM_ + k0 + scol];
      *(uint4*)&Bs[rr * 64 + scol] = *(const uint4*)&W[(size_t)(e0 + rr) * DIM_ + k0 + scol];
    }
    __syncthreads();
#pragma unroll
    for (int kc = 0; kc < 2; ++kc) {
      bf16x8 af[4], bfr[4];
#pragma unroll
      for (int rt = 0; rt < 4; ++rt)
        af[rt] = *(const bf16x8*)&As[(wr + rt * 16 + r) * 64 + kc * 32 + q * 8];
#pragma unroll
      for (int ct = 0; ct < 4; ++ct)
        bfr[ct] = *(const bf16x8*)&Bs[(wc + ct * 16 + r) * 64 + kc * 32 + q * 8];
#pragma unroll
      for (int rt = 0; rt < 4; ++rt)
#pragma unroll
        for (int ct = 0; ct < 4; ++ct)
          acc[rt][ct] = MFMA16(af[rt], bfr[ct], acc[rt][ct]);
    }
    __syncthreads();
  }
  if (z < 2) {
    unsigned short* dst = (z == 0) ? Q : K;
#pragma unroll
    for (int rt = 0; rt < 4; ++rt) {
#pragma unroll
      for (int ct = 0; ct < 4; ++ct) {
        const int e = e0 + wc + ct * 16 + r;
#pragma unroll
        for (int i = 0; i < 4; ++i) {
          const int t = t0 + wr + rt * 16 + q * 4 + i;
          dst[(size_t)t * DIM_ + e] = f2bf(acc[rt][ct][i]);
        }
      }
    }
  } else {
#pragma unroll
    for (int rt = 0; rt < 4; ++rt) {
      const int t = t0 + wr + rt * 16 + q * 4;
      const int b_ = t >> 12, n = t & (N_ - 1);
#pragma unroll
      for (int ct = 0; ct < 4; ++ct) {
        const int e = e0 + wc + ct * 16 + r;
        const int h = e >> 6, dh = e & 63;
        ushort4 pk;
        pk.x = f2bf(acc[rt][ct][0]); pk.y = f2bf(acc[rt][ct][1]);
        pk.z = f2bf(acc[rt][ct][2]); pk.w = f2bf(acc[rt][ct][3]);
        *(ushort4*)&VT[((size_t)((b_ * H_ + h) * DH_ + dh)) * N_ + n] = pk;
      }
    }
  }
}

// ---------------- diag: DIAGC * sum(t*t) per (bh, n), stored bf16 ----------------
__global__ void diag_kernel(const unsigned short* __restrict__ Q,
                            const unsigned short* __restrict__ K,
                            unsigned short* __restrict__ dq, unsigned short* __restrict__ dk) {
  const int i = blockIdx.x * 256 + threadIdx.x;
  const int bh = i >> 12, n = i & (N_ - 1);
  const int b_ = bh >> 3, h = bh & 7;
  const unsigned short* src = ((blockIdx.y == 0) ? Q : K) + (size_t)(b_ * N_ + n) * DIM_ + h * DH_;
  float s = 0.f;
#pragma unroll
  for (int c = 0; c < 16; ++c) {
    const ushort4 u = ((const ushort4*)src)[c];
    const float a = bfu(u.x), b2 = bfu(u.y), cc = bfu(u.z), d = bfu(u.w);
    s += a * a + b2 * b2 + cc * cc + d * d;
  }
  ((blockIdx.y == 0) ? dq : dk)[i] = f2bf(s * DIAGC);
}

// ---------------- kmax/qmax (MFMA): z=0 -> K global max; z=1 -> Q per-row max ----------------
__global__ __launch_bounds__(256) void kmax_mfma(
    const unsigned short* __restrict__ K, const unsigned short* __restrict__ Qb,
    const unsigned short* __restrict__ projp,
    float* __restrict__ kmax, float* __restrict__ rmaxq) {
  const int bh = blockIdx.x, n0 = blockIdx.y * 128;
  const int isq = blockIdx.z;
  const int wv = threadIdx.x >> 6, lane = threadIdx.x & 63;
  const int r = lane & 15, q = lane >> 4;
  const int b_ = bh >> 3, h = bh & 7;
  const unsigned short* src = isq ? Qb : K;
  bf16x8 kb[2][2];
#pragma unroll
  for (int nt = 0; nt < 2; ++nt) {
    const int n = n0 + wv * 32 + nt * 16 + r;
    const unsigned short* krow = src + (size_t)(b_ * N_ + n) * DIM_ + h * DH_;
    kb[nt][0] = *(const bf16x8*)(krow + q * 8);
    kb[nt][1] = *(const bf16x8*)(krow + 32 + q * 8);
  }
  float rmv[2] = {-3e38f, -3e38f};
  for (int mt = 0; mt < 17; ++mt) {
    const unsigned short* prow = projp + (size_t)(mt * 16 + r) * DH_;
    const bf16x8 a0 = *(const bf16x8*)(prow + q * 8);
    const bf16x8 a1 = *(const bf16x8*)(prow + 32 + q * 8);
#pragma unroll
    for (int nt = 0; nt < 2; ++nt) {
      f32x4 acc = (f32x4){0.f, 0.f, 0.f, 0.f};
      acc = MFMA16(a0, kb[nt][0], acc);
      acc = MFMA16(a1, kb[nt][1], acc);
#pragma unroll
      for (int i = 0; i < 4; ++i) {
        const int m = mt * 16 + q * 4 + i;
        if (m < M_) rmv[nt] = fmaxf(rmv[nt], acc[i]);
      }
    }
  }
  if (!isq) {
    float runmax = fmaxf(rmv[0], rmv[1]);
    for (int s2 = 1; s2 < 64; s2 <<= 1) runmax = fmaxf(runmax, __shfl_xor(runmax, s2, 64));
    __shared__ float wm[4];
    if (lane == 0) wm[wv] = runmax;
    __syncthreads();
    if (threadIdx.x == 0) {
      const float m = fmaxf(fmaxf(wm[0], wm[1]), fmaxf(wm[2], wm[3])) * NORMC;
      atomicMaxF(&kmax[bh], m);
    }
  } else {
    // per-n raw max: combine the 4 q-groups (m-coverage) via butterfly over q bits
#pragma unroll
    for (int nt = 0; nt < 2; ++nt) {
      float v = rmv[nt];
      v = fmaxf(v, __shfl_xor(v, 16, 64));
      v = fmaxf(v, __shfl_xor(v, 32, 64));
      if (q == 0) rmaxq[bh * N_ + n0 + wv * 32 + nt * 16 + r] = v;
    }
  }
}

// ---------------- fused: td -> exp -> kp; ctx += kp x VT; ksum ----------------
__global__ __launch_bounds__(256) void ctxfused_mfma(
    const unsigned short* __restrict__ K, const unsigned short* __restrict__ VT,
    const unsigned short* __restrict__ projp, const unsigned short* __restrict__ diag_k,
    const float* __restrict__ kmaxv, float* __restrict__ ksuma,
    float* __restrict__ slab) {
  __shared__ unsigned short kll[64][72];
  __shared__ unsigned short vtl[64][72];
  __shared__ unsigned short kpl[64][72];
  __shared__ float dgl[64];
  const int bh = blockIdx.x, m0 = blockIdx.y * 64, zi = blockIdx.z;
  const int nbase = zi * 512;
  const int tid = threadIdx.x;
  const int wv = tid >> 6, lane = tid & 63;
  const int r = lane & 15, q = lane >> 4;
  const int b_ = bh >> 3, h = bh & 7;
  const float km = kmaxv[bh];
  const unsigned short* prow = projp + (size_t)(m0 + wv * 16 + r) * DH_;
  const bf16x8 p0 = *(const bf16x8*)(prow + q * 8);
  const bf16x8 p1 = *(const bf16x8*)(prow + 32 + q * 8);
  const unsigned short* kbase = K + (size_t)(b_ * N_) * DIM_ + h * DH_;
  const unsigned short* vbase = VT + (size_t)bh * DH_ * N_;
  f32x4 cacc[4];
#pragma unroll
  for (int i = 0; i < 4; ++i) cacc[i] = (f32x4){0.f, 0.f, 0.f, 0.f};
  float ksa[4] = {0.f, 0.f, 0.f, 0.f};
  for (int nc = 0; nc < 8; ++nc) {
    const int n0c = nbase + nc * 64;
#pragma unroll
    for (int j = 0; j < 4; ++j) {
      const int idx = tid + j * 256;
      const int rr = idx >> 4, c4 = (idx & 15) << 2;
      *(ushort4*)&kll[rr][c4] = *(const ushort4*)&kbase[(size_t)(n0c + rr) * DIM_ + c4];
      *(ushort4*)&vtl[rr][c4] = *(const ushort4*)&vbase[(size_t)rr * N_ + n0c + c4];
    }
    if (tid < 16) {
      const ushort4 du = *(const ushort4*)&diag_k[bh * N_ + n0c + tid * 4];
      dgl[tid * 4 + 0] = bfu(du.x); dgl[tid * 4 + 1] = bfu(du.y);
      dgl[tid * 4 + 2] = bfu(du.z); dgl[tid * 4 + 3] = bfu(du.w);
    }
    __syncthreads();
#pragma unroll
    for (int nt = 0; nt < 4; ++nt) {
      const bf16x8 kb0 = *(const bf16x8*)&kll[nt * 16 + r][q * 8];
      const bf16x8 kb1 = *(const bf16x8*)&kll[nt * 16 + r][32 + q * 8];
      f32x4 acc = (f32x4){0.f, 0.f, 0.f, 0.f};
      acc = MFMA16(p0, kb0, acc);
      acc = MFMA16(p1, kb1, acc);
      const float dgk = dgl[nt * 16 + r];
#pragma unroll
      for (int i = 0; i < 4; ++i) {
        const int m = m0 + wv * 16 + q * 4 + i;
        float kp = 0.f;
        if (m < M_) {
          const float arg = fminf(NORMC * acc[i] - dgk - km, 0.f);
          kp = RATIOC * (__expf(arg) + EPSK);
        }
        kpl[wv * 16 + q * 4 + i][nt * 16 + r] = f2bf(kp);
        ksa[i] += kp;
      }
    }
    __syncthreads();
    {
      const bf16x8 a0 = *(const bf16x8*)&kpl[wv * 16 + r][q * 8];
      const bf16x8 a1 = *(const bf16x8*)&kpl[wv * 16 + r][32 + q * 8];
#pragma unroll
      for (int ct = 0; ct < 4; ++ct) {
        const bf16x8 b0 = *(const bf16x8*)&vtl[ct * 16 + r][q * 8];
        const bf16x8 b1 = *(const bf16x8*)&vtl[ct * 16 + r][32 + q * 8];
        cacc[ct] = MFMA16(a0, b0, cacc[ct]);
        cacc[ct] = MFMA16(a1, b1, cacc[ct]);
      }
    }
    __syncthreads();
  }
#pragma unroll
  for (int i = 0; i < 4; ++i)
    for (int s2 = 1; s2 < 16; s2 <<= 1) ksa[i] += __shfl_xor(ksa[i], s2, 64);
  if (r == 0) {
#pragma unroll
    for (int i = 0; i < 4; ++i)
      atomicAdd(&ksuma[bh * MP3_ + m0 + wv * 16 + q * 4 + i], ksa[i]);
  }
  float* sl = slab + (size_t)(bh * NZ_ + zi) * SLABM_ * DH_;
#pragma unroll
  for (int ct = 0; ct < 4; ++ct) {
#pragma unroll
    for (int i = 0; i < 4; ++i) {
      const int m = m0 + wv * 16 + q * 4 + i;
      if (m < SLABM_) sl[(size_t)m * DH_ + ct * 16 + r] = cacc[ct][i];
    }
  }
}

// ---------------- pack: reduce 8 z-slabs [m][d] fp32 -> transpose -> ctxT [d][288] bf16 ----
__global__ __launch_bounds__(256) void pack_kernel(const float* __restrict__ slab,
                                                   unsigned short* __restrict__ ctxT) {
  __shared__ float t[64][65];
  const int bh = blockIdx.x, m0 = blockIdx.y * 64;
  const int tid = threadIdx.x;
  const int mr = tid >> 4, d4 = (tid & 15) * 4;
#pragma unroll
  for (int pass = 0; pass < 4; ++pass) {
    const int ml = pass * 16 + mr;
    const int m = m0 + ml;
    float4 s = {0.f, 0.f, 0.f, 0.f};
    if (m < SLABM_) {
#pragma unroll
      for (int z = 0; z < NZ_; ++z) {
        const float4 v =
            *(const float4*)&slab[((size_t)(bh * NZ_ + z) * SLABM_ + m) * DH_ + d4];
        s.x += v.x; s.y += v.y; s.z += v.z; s.w += v.w;
      }
    }
    t[ml][d4 + 0] = s.x; t[ml][d4 + 1] = s.y; t[ml][d4 + 2] = s.z; t[ml][d4 + 3] = s.w;
  }
  __syncthreads();
  const int mc = tid & 63, dbase = tid >> 6;
  const int mo = m0 + mc;
  if (mo < MP2_) {
#pragma unroll
    for (int j = 0; j < 16; ++j) {
      const int d = dbase + j * 4;
      ctxT[((size_t)bh * DH_ + d) * MP2_ + mo] = f2bf(t[mc][d]);
    }
  }
}

// ---------------- fused QP + out GEMM: single-pass (rmax precomputed), LDS tile ----------------
// rm per n comes from kmax_mfma z=1 (bit-identical MFMA sequence). Single pass:
// per mt {2 MFMA -> exp2 -> cvt_pk -> wave-private LDS write, denom partial}.
// Nothing big stays live -> no spill, no recompute. Phase C reads A-frags from
// the wave's own LDS tile (stride 149 u32: 16 r-rows hit 16 distinct banks).
__global__ __launch_bounds__(256) void qpout_mfma(
    const unsigned short* __restrict__ Qb, const unsigned short* __restrict__ projp,
    const float* __restrict__ rmaxq,
    const unsigned short* __restrict__ diag_q, const float* __restrict__ ksuma,
    const unsigned short* __restrict__ ctxT, unsigned short* __restrict__ attn) {
  __shared__ unsigned int qps[4][16][149];  // per-wave tile, row stride 149 u32 (596 B)
  const int bh = blockIdx.x, n0 = blockIdx.y * 64;
  const int wv = threadIdx.x >> 6, lane = threadIdx.x & 63;
  const int r = lane & 15, q = lane >> 4;
  const int b_ = bh >> 3, h = bh & 7;
  // zero-fill u32 cols 136..143 (bf16 cols 272..287; ctxT is 0 there but avoid NaN*0)
  *(uint2*)&qps[wv][r][136 + q * 2] = make_uint2(0u, 0u);
  bf16x8 qb0, qb1;
  {
    const unsigned short* qrow = Qb + (size_t)(b_ * N_ + n0 + wv * 16 + r) * DIM_ + h * DH_;
    qb0 = *(const bf16x8*)(qrow + q * 8);
    qb1 = *(const bf16x8*)(qrow + 32 + q * 8);
  }
  const float rm = rmaxq[bh * N_ + n0 + wv * 16 + r];
  const float dg = bfu(diag_q[bh * N_ + n0 + wv * 16 + r]);
  const float Cl = LOG2R - dg * LOG2E - rm * KA;
  // single pass: td -> exp+pack -> LDS, denominator partial (rounded qp)
  float part = 0.f;
#pragma unroll
  for (int mt = 0; mt < 17; ++mt) {
    const unsigned short* prow = projp + (size_t)(mt * 16 + r) * DH_;
    const bf16x8 p0 = *(const bf16x8*)(prow + q * 8);
    const bf16x8 p1 = *(const bf16x8*)(prow + 32 + q * 8);
    f32x4 acc = (f32x4){0.f, 0.f, 0.f, 0.f};
    acc = MFMA16(p0, qb0, acc);
    acc = MFMA16(p1, qb1, acc);
    const f32x4 kl = *(const f32x4*)&ksuma[bh * MP3_ + mt * 16 + q * 4];
    unsigned int pkw0, pkw1;
    {
      const float s0 = fminf(acc[0] * KA + Cl, LOG2R);
      const float s1 = fminf(acc[1] * KA + Cl, LOG2R);
      const float e0 = exp2f(s0) + REPS;
      const float e1 = exp2f(s1) + REPS;
      asm("v_cvt_pk_bf16_f32 %0, %1, %2" : "=v"(pkw0) : "v"(e0), "v"(e1));
      union { unsigned int u; float f; } lo, hi;
      lo.u = pkw0 << 16; hi.u = pkw0 & 0xffff0000u;
      part += lo.f * kl[0] + hi.f * kl[1];
    }
    {
      const float s0 = fminf(acc[2] * KA + Cl, LOG2R);
      const float s1 = fminf(acc[3] * KA + Cl, LOG2R);
      const float e0 = exp2f(s0) + REPS;
      const float e1 = exp2f(s1) + REPS;
      asm("v_cvt_pk_bf16_f32 %0, %1, %2" : "=v"(pkw1) : "v"(e0), "v"(e1));
      union { unsigned int u; float f; } lo, hi;
      lo.u = pkw1 << 16; hi.u = pkw1 & 0xffff0000u;
      part += lo.f * kl[2] + hi.f * kl[3];
    }
    // row = n-local (r), bf16 cols m = mt*16 + q*4 .. +3  -> u32 cols mt*8 + q*2
    *(uint2*)&qps[wv][r][mt * 8 + q * 2] = make_uint2(pkw0, pkw1);
  }
  part += __shfl_xor(part, 16, 64);
  part += __shfl_xor(part, 32, 64);
  const float dinv = 1.f / fmaxf(part, 1e-30f);
  // Phase C: out = qp . ctxT (K = 288); A-frags from wave-private LDS tile
  f32x4 oacc[4];
#pragma unroll
  for (int i = 0; i < 4; ++i) oacc[i] = (f32x4){0.f, 0.f, 0.f, 0.f};
  const unsigned short* cbase = ctxT + (size_t)bh * DH_ * MP2_;
#pragma unroll
  for (int kc = 0; kc < 9; ++kc) {
    const bf16x8 af = *(const bf16x8*)&qps[wv][r][kc * 16 + q * 4];
#pragma unroll
    for (int dt = 0; dt < 4; ++dt) {
      const bf16x8 bfr = *(const bf16x8*)&cbase[(size_t)(dt * 16 + r) * MP2_ + kc * 32 + q * 8];
      oacc[dt] = MFMA16(af, bfr, oacc[dt]);
    }
  }
  // dinv lives at lane with r = n-local; output rows n-local = q*4+i
  float dv[4];
#pragma unroll
  for (int i = 0; i < 4; ++i)
    dv[i] = __shfl(dinv, (lane & 48) | (q * 4 + i), 64);
#pragma unroll
  for (int dt = 0; dt < 4; ++dt) {
    const int d = dt * 16 + r;
#pragma unroll
    for (int i = 0; i < 4; ++i) {
      const int nn = wv * 16 + q * 4 + i;
      attn[(size_t)(b_ * N_ + n0 + nn) * DIM_ + h * DH_ + d] = f2bf(oacc[dt][i] * dv[i]);
    }
  }
}

// ---------------- final: 128x128 LDS-staged MFMA GEMM + residual (fp32 I/O) ----------------
__global__ __launch_bounds__(256) void final_mfma(
    const unsigned short* __restrict__ attn, const unsigned short* __restrict__ Wo,
    const float* __restrict__ bo, const float* __restrict__ x,
    float* __restrict__ out) {
  __shared__ unsigned short As[128 * 64];
  __shared__ unsigned short Bs[128 * 64];
  const int t0 = blockIdx.x * 128, e0 = blockIdx.y * 128;
  const int tid = threadIdx.x;
  const int wv = tid >> 6, lane = tid & 63;
  const int r = lane & 15, q = lane >> 4;
  const int wr = (wv >> 1) * 64, wc = (wv & 1) * 64;
  f32x4 acc[4][4];
#pragma unroll
  for (int i = 0; i < 4; ++i)
#pragma unroll
    for (int j = 0; j < 4; ++j) acc[i][j] = (f32x4){0.f, 0.f, 0.f, 0.f};
  const int srow = tid >> 3, scol = (tid & 7) * 8;
  for (int k0 = 0; k0 < DIM_; k0 += 64) {
#pragma unroll
    for (int j = 0; j < 4; ++j) {
      const int rr = srow + j * 32;
      *(uint4*)&As[rr * 64 + scol] = *(const uint4*)&attn[(size_t)(t0 + rr) * DIM_ + k0 + scol];
      *(uint4*)&Bs[rr * 64 + scol] = *(const uint4*)&Wo[(size_t)(e0 + rr) * DIM_ + k0 + scol];
    }
    __syncthreads();
#pragma unroll
    for (int kc = 0; kc < 2; ++kc) {
      bf16x8 af[4], bfr[4];
#pragma unroll
      for (int rt = 0; rt < 4; ++rt)
        af[rt] = *(const bf16x8*)&As[(wr + rt * 16 + r) * 64 + kc * 32 + q * 8];
#pragma unroll
      for (int ct = 0; ct < 4; ++ct)
        bfr[ct] = *(const bf16x8*)&Bs[(wc + ct * 16 + r) * 64 + kc * 32 + q * 8];
#pragma unroll
      for (int rt = 0; rt < 4; ++rt)
#pragma unroll
        for (int ct = 0; ct < 4; ++ct)
          acc[rt][ct] = MFMA16(af[rt], bfr[ct], acc[rt][ct]);
    }
    __syncthreads();
  }
#pragma unroll
  for (int rt = 0; rt < 4; ++rt) {
#pragma unroll
    for (int ct = 0; ct < 4; ++ct) {
      const int c = e0 + wc + ct * 16 + r;
      const float bov = bo[c];
#pragma unroll
      for (int i = 0; i < 4; ++i) {
        const int t = t0 + wr + rt * 16 + q * 4 + i;
        out[(size_t)t * DIM_ + c] = acc[rt][ct][i] + bov + x[(size_t)t * DIM_ + c];
      }
    }
  }
}

extern "C" void kernel_launch(void* const* d_in, const int* in_sizes, int n_in,
                              void* d_out, int out_size, void* d_ws, size_t ws_size,
                              hipStream_t stream) {
  const float* x = (const float*)d_in[0];
  const float* Wq = (const float*)d_in[1];
  const float* Wk = (const float*)d_in[2];
  const float* Wv = (const float*)d_in[3];
  const float* Wo = (const float*)d_in[4];
  const float* bo = (const float*)d_in[5];
  const float* proj = (const float*)d_in[6];
  char* ws = (char*)d_ws;
  unsigned short* projp = (unsigned short*)(ws + PROJP_B);
  float* kmax = (float*)(ws + KMAX_B);
  float* ksuma = (float*)(ws + KSUMA_B);
  float* ctxa = (float*)(ws + CTXA_B);
  unsigned short* ctxT = (unsigned short*)(ws + CTXT_B);
  unsigned short* diag_q = (unsigned short*)(ws + DIAGQ_B);
  unsigned short* diag_k = (unsigned short*)(ws + DIAGK_B);
  unsigned short* xbf = (unsigned short*)(ws + XBF_B);
  unsigned short* wqb = (unsigned short*)(ws + WQ_B);
  unsigned short* wkb = (unsigned short*)(ws + WK_B);
  unsigned short* wvb = (unsigned short*)(ws + WV_B);
  unsigned short* wob = (unsigned short*)(ws + WO_B);
  unsigned short* Q = (unsigned short*)(ws + Q_B);
  unsigned short* K = (unsigned short*)(ws + K_B);
  unsigned short* VT = (unsigned short*)(ws + VT_B);
  float* rmaxq = (float*)(ws + RMAXQ_B);
  unsigned short* attn = K;  // K dead after ctxfused_mfma
  float* out = (float*)d_out;

  cvt_kernel<<<1024, 256, 0, stream>>>(x, xbf, 8388608);
  cvt_kernel<<<128, 256, 0, stream>>>(Wq, wqb, 262144);
  cvt_kernel<<<128, 256, 0, stream>>>(Wk, wkb, 262144);
  cvt_kernel<<<128, 256, 0, stream>>>(Wv, wvb, 262144);
  cvt_kernel<<<128, 256, 0, stream>>>(Wo, wob, 262144);
  setup_kernel<<<80, 256, 0, stream>>>(proj, projp, kmax, ksuma);
  qkv_mfma<<<dim3(NT_ / 128, DIM_ / 128, 3), 256, 0, stream>>>(xbf, wqb, wkb, wvb, Q, K, VT);
  diag_kernel<<<dim3(512, 2), 256, 0, stream>>>(Q, K, diag_q, diag_k);
  kmax_mfma<<<dim3(BH_, 32, 2), 256, 0, stream>>>(K, Q, projp, kmax, rmaxq);
  ctxfused_mfma<<<dim3(BH_, 5, NZ_), 256, 0, stream>>>(K, VT, projp, diag_k, kmax, ksuma, ctxa);
  pack_kernel<<<dim3(BH_, 5), 256, 0, stream>>>(ctxa, ctxT);
  qpout_mfma<<<dim3(BH_, 64), 256, 0, stream>>>(Q, projp, rmaxq, diag_q, ksuma, ctxT, attn);
  final_mfma<<<dim3(NT_ / 128, DIM_ / 128), 256, 0, stream>>>(attn, wob, bo, x, out);
}

// Round 5
// 315.058 us; speedup vs baseline: 1.1277x; 1.0665x over previous
//
#include <hip/hip_runtime.h>

#define N_ 4096
#define DIM_ 512
#define H_ 8
#define DH_ 64
#define M_ 266
#define MP_ 272      // ksum/qp live range padded to 272 (17 tiles of 16)
#define MP2_ 288     // out-GEMM K padded to 9 chunks of 32
#define MP3_ 320     // ksuma / projp m padded to 5 chunks of 64
#define SLABM_ 280   // ctx partial-slab m extent (>= M_=266, trimmed to fit overlay)
#define NZ_ 8        // n-split for ctxfused
#define NT_ 16384
#define BH_ 32

#define NORMC 0.3535533905932738f   // 64^-0.25
#define RATIOC 0.06131393394849658f // 266^-0.5
#define EPSK 1e-4f
#define DIAGC 0.0625f               // 0.5 * normalizer^2
// folded exp2 constants: qp = exp2(min(raw*KA + Cl, LOG2R)) + REPS
#define KA 0.51006971f              // NORMC * log2(e)
#define LOG2R -4.0276408f           // log2(RATIOC)
#define LOG2E 1.4426950408889634f
#define REPS 6.131393e-6f           // RATIOC * EPSK

// ---- ws layout (byte offsets), total ~71.5 MB ----
// ctx slabs (18,350,080 B) overlay xbf+wqb+wkb+wvb, dead after qkv_mfma.
#define PROJP_B 0ul            // 40960
#define KMAX_B  40960ul        // 128
#define KSUMA_B 41088ul        // 40960
#define WO_B    82048ul        // 524288
#define CTXT_B  606336ul       // 1179648
#define DIAGQ_B 1785984ul      // 262144
#define DIAGK_B 2048128ul      // 262144
#define XBF_B   2310272ul      // 16777216
#define WQ_B    19087488ul     // 524288
#define WK_B    19611776ul     // 524288
#define WV_B    20136064ul     // 524288
#define CTXA_B  2310272ul      // == XBF_B, 32*8*280*64*4 = 18350080 (ends at Q_B)
#define Q_B     20660352ul     // 16777216
#define K_B     37437568ul     // 16777216
#define VT_B    54214784ul     // 16777216
#define RMAXQ_B 70992000ul     // 524288 (32*4096 f32) -> end 71,516,288

typedef __bf16 bf16x8 __attribute__((ext_vector_type(8)));
typedef float f32x4 __attribute__((ext_vector_type(4)));
#define MFMA16(a, b, c) __builtin_amdgcn_mfma_f32_16x16x32_bf16((a), (b), (c), 0, 0, 0)

__device__ __forceinline__ float bfu(unsigned short u) {
  union { unsigned int i; float f; } x; x.i = ((unsigned int)u) << 16; return x.f;
}
__device__ __forceinline__ unsigned short f2bf(float f) {
  union { float f; unsigned int i; } u; u.f = f;
  unsigned int r = u.i + 0x7fffu + ((u.i >> 16) & 1u);
  return (unsigned short)(r >> 16);
}
__device__ __forceinline__ void atomicMaxF(float* addr, float val) {
  int* ai = (int*)addr;
  while (true) {
    float cur = __int_as_float(*(volatile int*)ai);
    if (val <= cur) break;
    int old = atomicCAS(ai, __float_as_int(cur), __float_as_int(val));
    if (old == __float_as_int(cur)) break;
  }
}

// ---------------- fp32 -> bf16 conversion ----------------
__global__ void cvt_kernel(const float* __restrict__ src, unsigned short* __restrict__ dst, int n) {
  int i = (blockIdx.x * 256 + threadIdx.x) * 4;
  const int stride = gridDim.x * 1024;
  for (; i < n; i += stride) {
    const float4 v = *(const float4*)(src + i);
    ushort4 u;
    u.x = f2bf(v.x); u.y = f2bf(v.y); u.z = f2bf(v.z); u.w = f2bf(v.w);
    *(ushort4*)(dst + i) = u;
  }
}

// ---------------- setup: proj cvt+pad(320), kmax init, ksuma zero ----------------
__global__ void setup_kernel(const float* __restrict__ proj,
                             unsigned short* __restrict__ projp,
                             float* __restrict__ kmax,
                             float* __restrict__ ksuma) {
  const int i = blockIdx.x * 256 + threadIdx.x;
  const int stride = gridDim.x * 256;
  for (int j = i; j < MP3_ * DH_; j += stride)
    projp[j] = (j < M_ * DH_) ? f2bf(proj[j]) : (unsigned short)0;
  for (int j = i; j < BH_; j += stride) kmax[j] = -3e38f;
  for (int j = i; j < BH_ * MP3_; j += stride) ksuma[j] = 0.f;
}

// ---------------- QKV projection: 128x128 LDS-staged MFMA GEMM ----------------
__global__ __launch_bounds__(256) void qkv_mfma(
    const unsigned short* __restrict__ x, const unsigned short* __restrict__ Wq,
    const unsigned short* __restrict__ Wk, const unsigned short* __restrict__ Wv,
    unsigned short* __restrict__ Q, unsigned short* __restrict__ K,
    unsigned short* __restrict__ VT) {
  __shared__ unsigned short As[128 * 64];
  __shared__ unsigned short Bs[128 * 64];
  const int z = blockIdx.z;
  const unsigned short* W = (z == 0) ? Wq : (z == 1) ? Wk : Wv;
  const int t0 = blockIdx.x * 128, e0 = blockIdx.y * 128;
  const int tid = threadIdx.x;
  const int wv = tid >> 6, lane = tid & 63;
  const int r = lane & 15, q = lane >> 4;
  const int wr = (wv >> 1) * 64, wc = (wv & 1) * 64;
  f32x4 acc[4][4];
#pragma unroll
  for (int i = 0; i < 4; ++i)
#pragma unroll
    for (int j = 0; j < 4; ++j) acc[i][j] = (f32x4){0.f, 0.f, 0.f, 0.f};
  const int srow = tid >> 3, scol = (tid & 7) * 8;
  for (int k0 = 0; k0 < DIM_; k0 += 64) {
#pragma unroll
    for (int j = 0; j < 4; ++j) {
      const int rr = srow + j * 32;
      *(uint4*)&As[rr * 64 + scol] = *(const uint4*)&x[(size_t)(t0 + rr) * DIM_ + k0 + scol];
      *(uint4*)&Bs[rr * 64 + scol] = *(const uint4*)&W[(size_t)(e0 + rr) * DIM_ + k0 + scol];
    }
    __syncthreads();
#pragma unroll
    for (int kc = 0; kc < 2; ++kc) {
      bf16x8 af[4], bfr[4];
#pragma unroll
      for (int rt = 0; rt < 4; ++rt)
        af[rt] = *(const bf16x8*)&As[(wr + rt * 16 + r) * 64 + kc * 32 + q * 8];
#pragma unroll
      for (int ct = 0; ct < 4; ++ct)
        bfr[ct] = *(const bf16x8*)&Bs[(wc + ct * 16 + r) * 64 + kc * 32 + q * 8];
#pragma unroll
      for (int rt = 0; rt < 4; ++rt)
#pragma unroll
        for (int ct = 0; ct < 4; ++ct)
          acc[rt][ct] = MFMA16(af[rt], bfr[ct], acc[rt][ct]);
    }
    __syncthreads();
  }
  if (z < 2) {
    unsigned short* dst = (z == 0) ? Q : K;
#pragma unroll
    for (int rt = 0; rt < 4; ++rt) {
#pragma unroll
      for (int ct = 0; ct < 4; ++ct) {
        const int e = e0 + wc + ct * 16 + r;
#pragma unroll
        for (int i = 0; i < 4; ++i) {
          const int t = t0 + wr + rt * 16 + q * 4 + i;
          dst[(size_t)t * DIM_ + e] = f2bf(acc[rt][ct][i]);
        }
      }
    }
  } else {
#pragma unroll
    for (int rt = 0; rt < 4; ++rt) {
      const int t = t0 + wr + rt * 16 + q * 4;
      const int b_ = t >> 12, n = t & (N_ - 1);
#pragma unroll
      for (int ct = 0; ct < 4; ++ct) {
        const int e = e0 + wc + ct * 16 + r;
        const int h = e >> 6, dh = e & 63;
        ushort4 pk;
        pk.x = f2bf(acc[rt][ct][0]); pk.y = f2bf(acc[rt][ct][1]);
        pk.z = f2bf(acc[rt][ct][2]); pk.w = f2bf(acc[rt][ct][3]);
        *(ushort4*)&VT[((size_t)((b_ * H_ + h) * DH_ + dh)) * N_ + n] = pk;
      }
    }
  }
}

// ---------------- diag: DIAGC * sum(t*t) per (bh, n), stored bf16 ----------------
__global__ void diag_kernel(const unsigned short* __restrict__ Q,
                            const unsigned short* __restrict__ K,
                            unsigned short* __restrict__ dq, unsigned short* __restrict__ dk) {
  const int i = blockIdx.x * 256 + threadIdx.x;
  const int bh = i >> 12, n = i & (N_ - 1);
  const int b_ = bh >> 3, h = bh & 7;
  const unsigned short* src = ((blockIdx.y == 0) ? Q : K) + (size_t)(b_ * N_ + n) * DIM_ + h * DH_;
  float s = 0.f;
#pragma unroll
  for (int c = 0; c < 16; ++c) {
    const ushort4 u = ((const ushort4*)src)[c];
    const float a = bfu(u.x), b2 = bfu(u.y), cc = bfu(u.z), d = bfu(u.w);
    s += a * a + b2 * b2 + cc * cc + d * d;
  }
  ((blockIdx.y == 0) ? dq : dk)[i] = f2bf(s * DIAGC);
}

// ---------------- kmax/qmax (MFMA, merged): K global max + Q per-row max ----------------
// proj staged once in LDS ([72]-padded stride: 2-way bank alias = free); each proj
// fragment feeds 16 independent MFMAs (4 K-strips + 4 Q-strips) -> latency amortized.
// MFMA order (p0 then p1 accumulate) is bit-identical to qpout phase A.
__global__ __launch_bounds__(256) void kmax_mfma(
    const unsigned short* __restrict__ K, const unsigned short* __restrict__ Qb,
    const unsigned short* __restrict__ projp,
    float* __restrict__ kmax, float* __restrict__ rmaxq) {
  __shared__ unsigned short sP[MP_][72];
  __shared__ float wm[4];
  const int bh = blockIdx.x, n0 = blockIdx.y * 256;
  const int tid = threadIdx.x;
  const int wv = tid >> 6, lane = tid & 63;
  const int r = lane & 15, q = lane >> 4;
  const int b_ = bh >> 3, h = bh & 7;
  // stage proj rows 0..271 (coalesced 16B chunks)
  for (int c = tid; c < MP_ * 4; c += 256) {
    const int row = c >> 2, cb = (c & 3) * 8;
    *(uint4*)&sP[row][cb] = *(const uint4*)&projp[row * DH_ + cb];
  }
  // load 4 K-strips + 4 Q-strips: rows nbase + st*16 + r
  bf16x8 kb[4][2], qb[4][2];
  const int nbase = n0 + wv * 64;
#pragma unroll
  for (int st = 0; st < 4; ++st) {
    const size_t off = (size_t)(b_ * N_ + nbase + st * 16 + r) * DIM_ + h * DH_;
    kb[st][0] = *(const bf16x8*)(K + off + q * 8);
    kb[st][1] = *(const bf16x8*)(K + off + 32 + q * 8);
    qb[st][0] = *(const bf16x8*)(Qb + off + q * 8);
    qb[st][1] = *(const bf16x8*)(Qb + off + 32 + q * 8);
  }
  __syncthreads();
  float km = -3e38f;
  float qm[4] = {-3e38f, -3e38f, -3e38f, -3e38f};
  for (int mt = 0; mt < 17; ++mt) {
    const bf16x8 p0 = *(const bf16x8*)&sP[mt * 16 + r][q * 8];
    const bf16x8 p1 = *(const bf16x8*)&sP[mt * 16 + r][32 + q * 8];
#pragma unroll
    for (int st = 0; st < 4; ++st) {
      f32x4 ka = (f32x4){0.f, 0.f, 0.f, 0.f};
      ka = MFMA16(p0, kb[st][0], ka);
      ka = MFMA16(p1, kb[st][1], ka);
      f32x4 qa = (f32x4){0.f, 0.f, 0.f, 0.f};
      qa = MFMA16(p0, qb[st][0], qa);
      qa = MFMA16(p1, qb[st][1], qa);
#pragma unroll
      for (int i = 0; i < 4; ++i) {
        const int m = mt * 16 + q * 4 + i;
        if (m < M_) {
          km = fmaxf(km, ka[i]);
          qm[st] = fmaxf(qm[st], qa[i]);
        }
      }
    }
  }
  // Q: per-row raw max -- combine the 4 q-groups (m coverage) per row
#pragma unroll
  for (int st = 0; st < 4; ++st) {
    float v = qm[st];
    v = fmaxf(v, __shfl_xor(v, 16, 64));
    v = fmaxf(v, __shfl_xor(v, 32, 64));
    if (q == 0) rmaxq[bh * N_ + nbase + st * 16 + r] = v;
  }
  // K: block max -> atomic
  for (int s2 = 1; s2 < 64; s2 <<= 1) km = fmaxf(km, __shfl_xor(km, s2, 64));
  if (lane == 0) wm[wv] = km;
  __syncthreads();
  if (tid == 0) {
    const float m = fmaxf(fmaxf(wm[0], wm[1]), fmaxf(wm[2], wm[3])) * NORMC;
    atomicMaxF(&kmax[bh], m);
  }
}

// ---------------- fused: td -> exp -> kp; ctx += kp x VT; ksum ----------------
__global__ __launch_bounds__(256) void ctxfused_mfma(
    const unsigned short* __restrict__ K, const unsigned short* __restrict__ VT,
    const unsigned short* __restrict__ projp, const unsigned short* __restrict__ diag_k,
    const float* __restrict__ kmaxv, float* __restrict__ ksuma,
    float* __restrict__ slab) {
  __shared__ unsigned short kll[64][72];
  __shared__ unsigned short vtl[64][72];
  __shared__ unsigned short kpl[64][72];
  __shared__ float dgl[64];
  const int bh = blockIdx.x, m0 = blockIdx.y * 64, zi = blockIdx.z;
  const int nbase = zi * 512;
  const int tid = threadIdx.x;
  const int wv = tid >> 6, lane = tid & 63;
  const int r = lane & 15, q = lane >> 4;
  const int b_ = bh >> 3, h = bh & 7;
  const float km = kmaxv[bh];
  const unsigned short* prow = projp + (size_t)(m0 + wv * 16 + r) * DH_;
  const bf16x8 p0 = *(const bf16x8*)(prow + q * 8);
  const bf16x8 p1 = *(const bf16x8*)(prow + 32 + q * 8);
  const unsigned short* kbase = K + (size_t)(b_ * N_) * DIM_ + h * DH_;
  const unsigned short* vbase = VT + (size_t)bh * DH_ * N_;
  f32x4 cacc[4];
#pragma unroll
  for (int i = 0; i < 4; ++i) cacc[i] = (f32x4){0.f, 0.f, 0.f, 0.f};
  float ksa[4] = {0.f, 0.f, 0.f, 0.f};
  for (int nc = 0; nc < 8; ++nc) {
    const int n0c = nbase + nc * 64;
#pragma unroll
    for (int j = 0; j < 4; ++j) {
      const int idx = tid + j * 256;
      const int rr = idx >> 4, c4 = (idx & 15) << 2;
      *(ushort4*)&kll[rr][c4] = *(const ushort4*)&kbase[(size_t)(n0c + rr) * DIM_ + c4];
      *(ushort4*)&vtl[rr][c4] = *(const ushort4*)&vbase[(size_t)rr * N_ + n0c + c4];
    }
    if (tid < 16) {
      const ushort4 du = *(const ushort4*)&diag_k[bh * N_ + n0c + tid * 4];
      dgl[tid * 4 + 0] = bfu(du.x); dgl[tid * 4 + 1] = bfu(du.y);
      dgl[tid * 4 + 2] = bfu(du.z); dgl[tid * 4 + 3] = bfu(du.w);
    }
    __syncthreads();
#pragma unroll
    for (int nt = 0; nt < 4; ++nt) {
      const bf16x8 kb0 = *(const bf16x8*)&kll[nt * 16 + r][q * 8];
      const bf16x8 kb1 = *(const bf16x8*)&kll[nt * 16 + r][32 + q * 8];
      f32x4 acc = (f32x4){0.f, 0.f, 0.f, 0.f};
      acc = MFMA16(p0, kb0, acc);
      acc = MFMA16(p1, kb1, acc);
      const float dgk = dgl[nt * 16 + r];
#pragma unroll
      for (int i = 0; i < 4; ++i) {
        const int m = m0 + wv * 16 + q * 4 + i;
        float kp = 0.f;
        if (m < M_) {
          const float arg = fminf(NORMC * acc[i] - dgk - km, 0.f);
          kp = RATIOC * (__expf(arg) + EPSK);
        }
        kpl[wv * 16 + q * 4 + i][nt * 16 + r] = f2bf(kp);
        ksa[i] += kp;
      }
    }
    __syncthreads();
    {
      const bf16x8 a0 = *(const bf16x8*)&kpl[wv * 16 + r][q * 8];
      const bf16x8 a1 = *(const bf16x8*)&kpl[wv * 16 + r][32 + q * 8];
#pragma unroll
      for (int ct = 0; ct < 4; ++ct) {
        const bf16x8 b0 = *(const bf16x8*)&vtl[ct * 16 + r][q * 8];
        const bf16x8 b1 = *(const bf16x8*)&vtl[ct * 16 + r][32 + q * 8];
        cacc[ct] = MFMA16(a0, b0, cacc[ct]);
        cacc[ct] = MFMA16(a1, b1, cacc[ct]);
      }
    }
    __syncthreads();
  }
#pragma unroll
  for (int i = 0; i < 4; ++i)
    for (int s2 = 1; s2 < 16; s2 <<= 1) ksa[i] += __shfl_xor(ksa[i], s2, 64);
  if (r == 0) {
#pragma unroll
    for (int i = 0; i < 4; ++i)
      atomicAdd(&ksuma[bh * MP3_ + m0 + wv * 16 + q * 4 + i], ksa[i]);
  }
  float* sl = slab + (size_t)(bh * NZ_ + zi) * SLABM_ * DH_;
#pragma unroll
  for (int ct = 0; ct < 4; ++ct) {
#pragma unroll
    for (int i = 0; i < 4; ++i) {
      const int m = m0 + wv * 16 + q * 4 + i;
      if (m < SLABM_) sl[(size_t)m * DH_ + ct * 16 + r] = cacc[ct][i];
    }
  }
}

// ---------------- pack: reduce 8 z-slabs [m][d] fp32 -> transpose -> ctxT [d][288] bf16 ----
__global__ __launch_bounds__(256) void pack_kernel(const float* __restrict__ slab,
                                                   unsigned short* __restrict__ ctxT) {
  __shared__ float t[64][65];
  const int bh = blockIdx.x, m0 = blockIdx.y * 64;
  const int tid = threadIdx.x;
  const int mr = tid >> 4, d4 = (tid & 15) * 4;
#pragma unroll
  for (int pass = 0; pass < 4; ++pass) {
    const int ml = pass * 16 + mr;
    const int m = m0 + ml;
    float4 s = {0.f, 0.f, 0.f, 0.f};
    if (m < SLABM_) {
#pragma unroll
      for (int z = 0; z < NZ_; ++z) {
        const float4 v =
            *(const float4*)&slab[((size_t)(bh * NZ_ + z) * SLABM_ + m) * DH_ + d4];
        s.x += v.x; s.y += v.y; s.z += v.z; s.w += v.w;
      }
    }
    t[ml][d4 + 0] = s.x; t[ml][d4 + 1] = s.y; t[ml][d4 + 2] = s.z; t[ml][d4 + 3] = s.w;
  }
  __syncthreads();
  const int mc = tid & 63, dbase = tid >> 6;
  const int mo = m0 + mc;
  if (mo < MP2_) {
#pragma unroll
    for (int j = 0; j < 16; ++j) {
      const int d = dbase + j * 4;
      ctxT[((size_t)bh * DH_ + d) * MP2_ + mo] = f2bf(t[mc][d]);
    }
  }
}

// ---------------- fused QP + out GEMM: single-pass (rmax precomputed), LDS tile ----------------
__global__ __launch_bounds__(256) void qpout_mfma(
    const unsigned short* __restrict__ Qb, const unsigned short* __restrict__ projp,
    const float* __restrict__ rmaxq,
    const unsigned short* __restrict__ diag_q, const float* __restrict__ ksuma,
    const unsigned short* __restrict__ ctxT, unsigned short* __restrict__ attn) {
  __shared__ unsigned int qps[4][16][149];  // per-wave tile, row stride 149 u32 (596 B)
  const int bh = blockIdx.x, n0 = blockIdx.y * 64;
  const int wv = threadIdx.x >> 6, lane = threadIdx.x & 63;
  const int r = lane & 15, q = lane >> 4;
  const int b_ = bh >> 3, h = bh & 7;
  // zero-fill u32 cols 136..143 (bf16 cols 272..287; ctxT is 0 there but avoid NaN*0)
  *(uint2*)&qps[wv][r][136 + q * 2] = make_uint2(0u, 0u);
  bf16x8 qb0, qb1;
  {
    const unsigned short* qrow = Qb + (size_t)(b_ * N_ + n0 + wv * 16 + r) * DIM_ + h * DH_;
    qb0 = *(const bf16x8*)(qrow + q * 8);
    qb1 = *(const bf16x8*)(qrow + 32 + q * 8);
  }
  const float rm = rmaxq[bh * N_ + n0 + wv * 16 + r];
  const float dg = bfu(diag_q[bh * N_ + n0 + wv * 16 + r]);
  const float Cl = LOG2R - dg * LOG2E - rm * KA;
  // single pass: td -> exp+pack -> LDS, denominator partial (rounded qp)
  float part = 0.f;
#pragma unroll
  for (int mt = 0; mt < 17; ++mt) {
    const unsigned short* prow = projp + (size_t)(mt * 16 + r) * DH_;
    const bf16x8 p0 = *(const bf16x8*)(prow + q * 8);
    const bf16x8 p1 = *(const bf16x8*)(prow + 32 + q * 8);
    f32x4 acc = (f32x4){0.f, 0.f, 0.f, 0.f};
    acc = MFMA16(p0, qb0, acc);
    acc = MFMA16(p1, qb1, acc);
    const f32x4 kl = *(const f32x4*)&ksuma[bh * MP3_ + mt * 16 + q * 4];
    unsigned int pkw0, pkw1;
    {
      const float s0 = fminf(acc[0] * KA + Cl, LOG2R);
      const float s1 = fminf(acc[1] * KA + Cl, LOG2R);
      const float e0 = exp2f(s0) + REPS;
      const float e1 = exp2f(s1) + REPS;
      asm("v_cvt_pk_bf16_f32 %0, %1, %2" : "=v"(pkw0) : "v"(e0), "v"(e1));
      union { unsigned int u; float f; } lo, hi;
      lo.u = pkw0 << 16; hi.u = pkw0 & 0xffff0000u;
      part += lo.f * kl[0] + hi.f * kl[1];
    }
    {
      const float s0 = fminf(acc[2] * KA + Cl, LOG2R);
      const float s1 = fminf(acc[3] * KA + Cl, LOG2R);
      const float e0 = exp2f(s0) + REPS;
      const float e1 = exp2f(s1) + REPS;
      asm("v_cvt_pk_bf16_f32 %0, %1, %2" : "=v"(pkw1) : "v"(e0), "v"(e1));
      union { unsigned int u; float f; } lo, hi;
      lo.u = pkw1 << 16; hi.u = pkw1 & 0xffff0000u;
      part += lo.f * kl[2] + hi.f * kl[3];
    }
    // row = n-local (r), bf16 cols m = mt*16 + q*4 .. +3  -> u32 cols mt*8 + q*2
    *(uint2*)&qps[wv][r][mt * 8 + q * 2] = make_uint2(pkw0, pkw1);
  }
  part += __shfl_xor(part, 16, 64);
  part += __shfl_xor(part, 32, 64);
  const float dinv = 1.f / fmaxf(part, 1e-30f);
  // Phase C: out = qp . ctxT (K = 288); A-frags from wave-private LDS tile
  f32x4 oacc[4];
#pragma unroll
  for (int i = 0; i < 4; ++i) oacc[i] = (f32x4){0.f, 0.f, 0.f, 0.f};
  const unsigned short* cbase = ctxT + (size_t)bh * DH_ * MP2_;
#pragma unroll
  for (int kc = 0; kc < 9; ++kc) {
    const bf16x8 af = *(const bf16x8*)&qps[wv][r][kc * 16 + q * 4];
#pragma unroll
    for (int dt = 0; dt < 4; ++dt) {
      const bf16x8 bfr = *(const bf16x8*)&cbase[(size_t)(dt * 16 + r) * MP2_ + kc * 32 + q * 8];
      oacc[dt] = MFMA16(af, bfr, oacc[dt]);
    }
  }
  // dinv lives at lane with r = n-local; output rows n-local = q*4+i
  float dv[4];
#pragma unroll
  for (int i = 0; i < 4; ++i)
    dv[i] = __shfl(dinv, (lane & 48) | (q * 4 + i), 64);
#pragma unroll
  for (int dt = 0; dt < 4; ++dt) {
    const int d = dt * 16 + r;
#pragma unroll
    for (int i = 0; i < 4; ++i) {
      const int nn = wv * 16 + q * 4 + i;
      attn[(size_t)(b_ * N_ + n0 + nn) * DIM_ + h * DH_ + d] = f2bf(oacc[dt][i] * dv[i]);
    }
  }
}

// ---------------- final: 128x128 LDS-staged MFMA GEMM + residual (fp32 I/O) ----------------
__global__ __launch_bounds__(256) void final_mfma(
    const unsigned short* __restrict__ attn, const unsigned short* __restrict__ Wo,
    const float* __restrict__ bo, const float* __restrict__ x,
    float* __restrict__ out) {
  __shared__ unsigned short As[128 * 64];
  __shared__ unsigned short Bs[128 * 64];
  const int t0 = blockIdx.x * 128, e0 = blockIdx.y * 128;
  const int tid = threadIdx.x;
  const int wv = tid >> 6, lane = tid & 63;
  const int r = lane & 15, q = lane >> 4;
  const int wr = (wv >> 1) * 64, wc = (wv & 1) * 64;
  f32x4 acc[4][4];
#pragma unroll
  for (int i = 0; i < 4; ++i)
#pragma unroll
    for (int j = 0; j < 4; ++j) acc[i][j] = (f32x4){0.f, 0.f, 0.f, 0.f};
  const int srow = tid >> 3, scol = (tid & 7) * 8;
  for (int k0 = 0; k0 < DIM_; k0 += 64) {
#pragma unroll
    for (int j = 0; j < 4; ++j) {
      const int rr = srow + j * 32;
      *(uint4*)&As[rr * 64 + scol] = *(const uint4*)&attn[(size_t)(t0 + rr) * DIM_ + k0 + scol];
      *(uint4*)&Bs[rr * 64 + scol] = *(const uint4*)&Wo[(size_t)(e0 + rr) * DIM_ + k0 + scol];
    }
    __syncthreads();
#pragma unroll
    for (int kc = 0; kc < 2; ++kc) {
      bf16x8 af[4], bfr[4];
#pragma unroll
      for (int rt = 0; rt < 4; ++rt)
        af[rt] = *(const bf16x8*)&As[(wr + rt * 16 + r) * 64 + kc * 32 + q * 8];
#pragma unroll
      for (int ct = 0; ct < 4; ++ct)
        bfr[ct] = *(const bf16x8*)&Bs[(wc + ct * 16 + r) * 64 + kc * 32 + q * 8];
#pragma unroll
      for (int rt = 0; rt < 4; ++rt)
#pragma unroll
        for (int ct = 0; ct < 4; ++ct)
          acc[rt][ct] = MFMA16(af[rt], bfr[ct], acc[rt][ct]);
    }
    __syncthreads();
  }
#pragma unroll
  for (int rt = 0; rt < 4; ++rt) {
#pragma unroll
    for (int ct = 0; ct < 4; ++ct) {
      const int c = e0 + wc + ct * 16 + r;
      const float bov = bo[c];
#pragma unroll
      for (int i = 0; i < 4; ++i) {
        const int t = t0 + wr + rt * 16 + q * 4 + i;
        out[(size_t)t * DIM_ + c] = acc[rt][ct][i] + bov + x[(size_t)t * DIM_ + c];
      }
    }
  }
}

extern "C" void kernel_launch(void* const* d_in, const int* in_sizes, int n_in,
                              void* d_out, int out_size, void* d_ws, size_t ws_size,
                              hipStream_t stream) {
  const float* x = (const float*)d_in[0];
  const float* Wq = (const float*)d_in[1];
  const float* Wk = (const float*)d_in[2];
  const float* Wv = (const float*)d_in[3];
  const float* Wo = (const float*)d_in[4];
  const float* bo = (const float*)d_in[5];
  const float* proj = (const float*)d_in[6];
  char* ws = (char*)d_ws;
  unsigned short* projp = (unsigned short*)(ws + PROJP_B);
  float* kmax = (float*)(ws + KMAX_B);
  float* ksuma = (float*)(ws + KSUMA_B);
  float* ctxa = (float*)(ws + CTXA_B);
  unsigned short* ctxT = (unsigned short*)(ws + CTXT_B);
  unsigned short* diag_q = (unsigned short*)(ws + DIAGQ_B);
  unsigned short* diag_k = (unsigned short*)(ws + DIAGK_B);
  unsigned short* xbf = (unsigned short*)(ws + XBF_B);
  unsigned short* wqb = (unsigned short*)(ws + WQ_B);
  unsigned short* wkb = (unsigned short*)(ws + WK_B);
  unsigned short* wvb = (unsigned short*)(ws + WV_B);
  unsigned short* wob = (unsigned short*)(ws + WO_B);
  unsigned short* Q = (unsigned short*)(ws + Q_B);
  unsigned short* K = (unsigned short*)(ws + K_B);
  unsigned short* VT = (unsigned short*)(ws + VT_B);
  float* rmaxq = (float*)(ws + RMAXQ_B);
  unsigned short* attn = K;  // K dead after ctxfused_mfma
  float* out = (float*)d_out;

  cvt_kernel<<<1024, 256, 0, stream>>>(x, xbf, 8388608);
  cvt_kernel<<<128, 256, 0, stream>>>(Wq, wqb, 262144);
  cvt_kernel<<<128, 256, 0, stream>>>(Wk, wkb, 262144);
  cvt_kernel<<<128, 256, 0, stream>>>(Wv, wvb, 262144);
  cvt_kernel<<<128, 256, 0, stream>>>(Wo, wob, 262144);
  setup_kernel<<<80, 256, 0, stream>>>(proj, projp, kmax, ksuma);
  qkv_mfma<<<dim3(NT_ / 128, DIM_ / 128, 3), 256, 0, stream>>>(xbf, wqb, wkb, wvb, Q, K, VT);
  diag_kernel<<<dim3(512, 2), 256, 0, stream>>>(Q, K, diag_q, diag_k);
  kmax_mfma<<<dim3(BH_, N_ / 256), 256, 0, stream>>>(K, Q, projp, kmax, rmaxq);
  ctxfused_mfma<<<dim3(BH_, 5, NZ_), 256, 0, stream>>>(K, VT, projp, diag_k, kmax, ksuma, ctxa);
  pack_kernel<<<dim3(BH_, 5), 256, 0, stream>>>(ctxa, ctxT);
  qpout_mfma<<<dim3(BH_, 64), 256, 0, stream>>>(Q, projp, rmaxq, diag_q, ksuma, ctxT, attn);
  final_mfma<<<dim3(NT_ / 128, DIM_ / 128), 256, 0, stream>>>(attn, wob, bo, x, out);
}

// Round 6
// 294.340 us; speedup vs baseline: 1.2071x; 1.0704x over previous
//
#include <hip/hip_runtime.h>

#define N_ 4096
#define DIM_ 512
#define H_ 8
#define DH_ 64
#define M_ 266
#define MP_ 272      // ksum/qp live range padded to 272 (17 tiles of 16)
#define MP2_ 288     // out-GEMM K padded to 9 chunks of 32
#define MP3_ 320     // ksuma / projp m padded to 5 chunks of 64
#define SLABM_ 280   // ctx partial-slab m extent (>= M_=266, trimmed to fit overlay)
#define NZ_ 8        // n-split for ctxfused
#define NT_ 16384
#define BH_ 32

#define NORMC 0.3535533905932738f   // 64^-0.25
#define RATIOC 0.06131393394849658f // 266^-0.5
#define EPSK 1e-4f
#define DIAGC 0.0625f               // 0.5 * normalizer^2
// folded exp2 constants: qp = exp2(min(raw*KA + Cl, LOG2R)) + REPS
#define KA 0.51006971f              // NORMC * log2(e)
#define LOG2R -4.0276408f           // log2(RATIOC)
#define LOG2E 1.4426950408889634f
#define REPS 6.131393e-6f           // RATIOC * EPSK

// ---- ws layout (byte offsets), total ~71.5 MB ----
// ctx slabs (18,350,080 B) overlay xbf+wqb+wkb+wvb, dead after qkv_mfma.
#define PROJP_B 0ul            // 40960
#define KMAX_B  40960ul        // 128
#define KSUMA_B 41088ul        // 40960
#define WO_B    82048ul        // 524288
#define CTXT_B  606336ul       // 1179648
#define DIAGQ_B 1785984ul      // 262144
#define DIAGK_B 2048128ul      // 262144
#define XBF_B   2310272ul      // 16777216
#define WQ_B    19087488ul     // 524288
#define WK_B    19611776ul     // 524288
#define WV_B    20136064ul     // 524288
#define CTXA_B  2310272ul      // == XBF_B, 32*8*280*64*4 = 18350080 (ends at Q_B)
#define Q_B     20660352ul     // 16777216
#define K_B     37437568ul     // 16777216
#define VT_B    54214784ul     // 16777216
#define RMAXQ_B 70992000ul     // 524288 (32*4096 f32) -> end 71,516,288

typedef __bf16 bf16x8 __attribute__((ext_vector_type(8)));
typedef float f32x4 __attribute__((ext_vector_type(4)));
#define MFMA16(a, b, c) __builtin_amdgcn_mfma_f32_16x16x32_bf16((a), (b), (c), 0, 0, 0)

__device__ __forceinline__ float bfu(unsigned short u) {
  union { unsigned int i; float f; } x; x.i = ((unsigned int)u) << 16; return x.f;
}
__device__ __forceinline__ unsigned short f2bf(float f) {
  union { float f; unsigned int i; } u; u.f = f;
  unsigned int r = u.i + 0x7fffu + ((u.i >> 16) & 1u);
  return (unsigned short)(r >> 16);
}
__device__ __forceinline__ void atomicMaxF(float* addr, float val) {
  int* ai = (int*)addr;
  while (true) {
    float cur = __int_as_float(*(volatile int*)ai);
    if (val <= cur) break;
    int old = atomicCAS(ai, __float_as_int(cur), __float_as_int(val));
    if (old == __float_as_int(cur)) break;
  }
}

// ---------------- fp32 -> bf16 conversion ----------------
__global__ void cvt_kernel(const float* __restrict__ src, unsigned short* __restrict__ dst, int n) {
  int i = (blockIdx.x * 256 + threadIdx.x) * 4;
  const int stride = gridDim.x * 1024;
  for (; i < n; i += stride) {
    const float4 v = *(const float4*)(src + i);
    ushort4 u;
    u.x = f2bf(v.x); u.y = f2bf(v.y); u.z = f2bf(v.z); u.w = f2bf(v.w);
    *(ushort4*)(dst + i) = u;
  }
}

// ---------------- setup: proj cvt+pad(320), kmax init, ksuma zero ----------------
__global__ void setup_kernel(const float* __restrict__ proj,
                             unsigned short* __restrict__ projp,
                             float* __restrict__ kmax,
                             float* __restrict__ ksuma) {
  const int i = blockIdx.x * 256 + threadIdx.x;
  const int stride = gridDim.x * 256;
  for (int j = i; j < MP3_ * DH_; j += stride)
    projp[j] = (j < M_ * DH_) ? f2bf(proj[j]) : (unsigned short)0;
  for (int j = i; j < BH_; j += stride) kmax[j] = -3e38f;
  for (int j = i; j < BH_ * MP3_; j += stride) ksuma[j] = 0.f;
}

// ---------------- QKV projection: 128x128 LDS-staged MFMA GEMM ----------------
__global__ __launch_bounds__(256) void qkv_mfma(
    const unsigned short* __restrict__ x, const unsigned short* __restrict__ Wq,
    const unsigned short* __restrict__ Wk, const unsigned short* __restrict__ Wv,
    unsigned short* __restrict__ Q, unsigned short* __restrict__ K,
    unsigned short* __restrict__ VT) {
  __shared__ unsigned short As[128 * 64];
  __shared__ unsigned short Bs[128 * 64];
  const int z = blockIdx.z;
  const unsigned short* W = (z == 0) ? Wq : (z == 1) ? Wk : Wv;
  const int t0 = blockIdx.x * 128, e0 = blockIdx.y * 128;
  const int tid = threadIdx.x;
  const int wv = tid >> 6, lane = tid & 63;
  const int r = lane & 15, q = lane >> 4;
  const int wr = (wv >> 1) * 64, wc = (wv & 1) * 64;
  f32x4 acc[4][4];
#pragma unroll
  for (int i = 0; i < 4; ++i)
#pragma unroll
    for (int j = 0; j < 4; ++j) acc[i][j] = (f32x4){0.f, 0.f, 0.f, 0.f};
  const int srow = tid >> 3, scol = (tid & 7) * 8;
  for (int k0 = 0; k0 < DIM_; k0 += 64) {
#pragma unroll
    for (int j = 0; j < 4; ++j) {
      const int rr = srow + j * 32;
      *(uint4*)&As[rr * 64 + scol] = *(const uint4*)&x[(size_t)(t0 + rr) * DIM_ + k0 + scol];
      *(uint4*)&Bs[rr * 64 + scol] = *(const uint4*)&W[(size_t)(e0 + rr) * DIM_ + k0 + scol];
    }
    __syncthreads();
#pragma unroll
    for (int kc = 0; kc < 2; ++kc) {
      bf16x8 af[4], bfr[4];
#pragma unroll
      for (int rt = 0; rt < 4; ++rt)
        af[rt] = *(const bf16x8*)&As[(wr + rt * 16 + r) * 64 + kc * 32 + q * 8];
#pragma unroll
      for (int ct = 0; ct < 4; ++ct)
        bfr[ct] = *(const bf16x8*)&Bs[(wc + ct * 16 + r) * 64 + kc * 32 + q * 8];
#pragma unroll
      for (int rt = 0; rt < 4; ++rt)
#pragma unroll
        for (int ct = 0; ct < 4; ++ct)
          acc[rt][ct] = MFMA16(af[rt], bfr[ct], acc[rt][ct]);
    }
    __syncthreads();
  }
  if (z < 2) {
    unsigned short* dst = (z == 0) ? Q : K;
#pragma unroll
    for (int rt = 0; rt < 4; ++rt) {
#pragma unroll
      for (int ct = 0; ct < 4; ++ct) {
        const int e = e0 + wc + ct * 16 + r;
#pragma unroll
        for (int i = 0; i < 4; ++i) {
          const int t = t0 + wr + rt * 16 + q * 4 + i;
          dst[(size_t)t * DIM_ + e] = f2bf(acc[rt][ct][i]);
        }
      }
    }
  } else {
#pragma unroll
    for (int rt = 0; rt < 4; ++rt) {
      const int t = t0 + wr + rt * 16 + q * 4;
      const int b_ = t >> 12, n = t & (N_ - 1);
#pragma unroll
      for (int ct = 0; ct < 4; ++ct) {
        const int e = e0 + wc + ct * 16 + r;
        const int h = e >> 6, dh = e & 63;
        ushort4 pk;
        pk.x = f2bf(acc[rt][ct][0]); pk.y = f2bf(acc[rt][ct][1]);
        pk.z = f2bf(acc[rt][ct][2]); pk.w = f2bf(acc[rt][ct][3]);
        *(ushort4*)&VT[((size_t)((b_ * H_ + h) * DH_ + dh)) * N_ + n] = pk;
      }
    }
  }
}

// ---------------- diag: DIAGC * sum(t*t) per (bh, n), stored bf16 ----------------
__global__ void diag_kernel(const unsigned short* __restrict__ Q,
                            const unsigned short* __restrict__ K,
                            unsigned short* __restrict__ dq, unsigned short* __restrict__ dk) {
  const int i = blockIdx.x * 256 + threadIdx.x;
  const int bh = i >> 12, n = i & (N_ - 1);
  const int b_ = bh >> 3, h = bh & 7;
  const unsigned short* src = ((blockIdx.y == 0) ? Q : K) + (size_t)(b_ * N_ + n) * DIM_ + h * DH_;
  float s = 0.f;
#pragma unroll
  for (int c = 0; c < 16; ++c) {
    const ushort4 u = ((const ushort4*)src)[c];
    const float a = bfu(u.x), b2 = bfu(u.y), cc = bfu(u.z), d = bfu(u.w);
    s += a * a + b2 * b2 + cc * cc + d * d;
  }
  ((blockIdx.y == 0) ? dq : dk)[i] = f2bf(s * DIAGC);
}

// ---------------- kmax/qmax (MFMA, merged): K global max + Q per-row max ----------------
__global__ __launch_bounds__(256) void kmax_mfma(
    const unsigned short* __restrict__ K, const unsigned short* __restrict__ Qb,
    const unsigned short* __restrict__ projp,
    float* __restrict__ kmax, float* __restrict__ rmaxq) {
  __shared__ unsigned short sP[MP_][72];
  __shared__ float wm[4];
  const int bh = blockIdx.x, n0 = blockIdx.y * 256;
  const int tid = threadIdx.x;
  const int wv = tid >> 6, lane = tid & 63;
  const int r = lane & 15, q = lane >> 4;
  const int b_ = bh >> 3, h = bh & 7;
  // stage proj rows 0..271 (coalesced 16B chunks)
  for (int c = tid; c < MP_ * 4; c += 256) {
    const int row = c >> 2, cb = (c & 3) * 8;
    *(uint4*)&sP[row][cb] = *(const uint4*)&projp[row * DH_ + cb];
  }
  // load 4 K-strips + 4 Q-strips: rows nbase + st*16 + r
  bf16x8 kb[4][2], qb[4][2];
  const int nbase = n0 + wv * 64;
#pragma unroll
  for (int st = 0; st < 4; ++st) {
    const size_t off = (size_t)(b_ * N_ + nbase + st * 16 + r) * DIM_ + h * DH_;
    kb[st][0] = *(const bf16x8*)(K + off + q * 8);
    kb[st][1] = *(const bf16x8*)(K + off + 32 + q * 8);
    qb[st][0] = *(const bf16x8*)(Qb + off + q * 8);
    qb[st][1] = *(const bf16x8*)(Qb + off + 32 + q * 8);
  }
  __syncthreads();
  float km = -3e38f;
  float qm[4] = {-3e38f, -3e38f, -3e38f, -3e38f};
  for (int mt = 0; mt < 17; ++mt) {
    const bf16x8 p0 = *(const bf16x8*)&sP[mt * 16 + r][q * 8];
    const bf16x8 p1 = *(const bf16x8*)&sP[mt * 16 + r][32 + q * 8];
#pragma unroll
    for (int st = 0; st < 4; ++st) {
      f32x4 ka = (f32x4){0.f, 0.f, 0.f, 0.f};
      ka = MFMA16(p0, kb[st][0], ka);
      ka = MFMA16(p1, kb[st][1], ka);
      f32x4 qa = (f32x4){0.f, 0.f, 0.f, 0.f};
      qa = MFMA16(p0, qb[st][0], qa);
      qa = MFMA16(p1, qb[st][1], qa);
#pragma unroll
      for (int i = 0; i < 4; ++i) {
        const int m = mt * 16 + q * 4 + i;
        if (m < M_) {
          km = fmaxf(km, ka[i]);
          qm[st] = fmaxf(qm[st], qa[i]);
        }
      }
    }
  }
  // Q: per-row raw max -- combine the 4 q-groups (m coverage) per row
#pragma unroll
  for (int st = 0; st < 4; ++st) {
    float v = qm[st];
    v = fmaxf(v, __shfl_xor(v, 16, 64));
    v = fmaxf(v, __shfl_xor(v, 32, 64));
    if (q == 0) rmaxq[bh * N_ + nbase + st * 16 + r] = v;
  }
  // K: block max -> atomic
  for (int s2 = 1; s2 < 64; s2 <<= 1) km = fmaxf(km, __shfl_xor(km, s2, 64));
  if (lane == 0) wm[wv] = km;
  __syncthreads();
  if (tid == 0) {
    const float m = fmaxf(fmaxf(wm[0], wm[1]), fmaxf(wm[2], wm[3])) * NORMC;
    atomicMaxF(&kmax[bh], m);
  }
}

// ---------------- fused: td -> exp -> kp; ctx += kp x VT; ksum ----------------
__global__ __launch_bounds__(256) void ctxfused_mfma(
    const unsigned short* __restrict__ K, const unsigned short* __restrict__ VT,
    const unsigned short* __restrict__ projp, const unsigned short* __restrict__ diag_k,
    const float* __restrict__ kmaxv, float* __restrict__ ksuma,
    float* __restrict__ slab) {
  __shared__ unsigned short kll[64][72];
  __shared__ unsigned short vtl[64][72];
  __shared__ unsigned short kpl[64][72];
  __shared__ float dgl[64];
  const int bh = blockIdx.x, m0 = blockIdx.y * 64, zi = blockIdx.z;
  const int nbase = zi * 512;
  const int tid = threadIdx.x;
  const int wv = tid >> 6, lane = tid & 63;
  const int r = lane & 15, q = lane >> 4;
  const int b_ = bh >> 3, h = bh & 7;
  const float km = kmaxv[bh];
  const unsigned short* prow = projp + (size_t)(m0 + wv * 16 + r) * DH_;
  const bf16x8 p0 = *(const bf16x8*)(prow + q * 8);
  const bf16x8 p1 = *(const bf16x8*)(prow + 32 + q * 8);
  const unsigned short* kbase = K + (size_t)(b_ * N_) * DIM_ + h * DH_;
  const unsigned short* vbase = VT + (size_t)bh * DH_ * N_;
  f32x4 cacc[4];
#pragma unroll
  for (int i = 0; i < 4; ++i) cacc[i] = (f32x4){0.f, 0.f, 0.f, 0.f};
  float ksa[4] = {0.f, 0.f, 0.f, 0.f};
  for (int nc = 0; nc < 8; ++nc) {
    const int n0c = nbase + nc * 64;
#pragma unroll
    for (int j = 0; j < 4; ++j) {
      const int idx = tid + j * 256;
      const int rr = idx >> 4, c4 = (idx & 15) << 2;
      *(ushort4*)&kll[rr][c4] = *(const ushort4*)&kbase[(size_t)(n0c + rr) * DIM_ + c4];
      *(ushort4*)&vtl[rr][c4] = *(const ushort4*)&vbase[(size_t)rr * N_ + n0c + c4];
    }
    if (tid < 16) {
      const ushort4 du = *(const ushort4*)&diag_k[bh * N_ + n0c + tid * 4];
      dgl[tid * 4 + 0] = bfu(du.x); dgl[tid * 4 + 1] = bfu(du.y);
      dgl[tid * 4 + 2] = bfu(du.z); dgl[tid * 4 + 3] = bfu(du.w);
    }
    __syncthreads();
#pragma unroll
    for (int nt = 0; nt < 4; ++nt) {
      const bf16x8 kb0 = *(const bf16x8*)&kll[nt * 16 + r][q * 8];
      const bf16x8 kb1 = *(const bf16x8*)&kll[nt * 16 + r][32 + q * 8];
      f32x4 acc = (f32x4){0.f, 0.f, 0.f, 0.f};
      acc = MFMA16(p0, kb0, acc);
      acc = MFMA16(p1, kb1, acc);
      const float dgk = dgl[nt * 16 + r];
#pragma unroll
      for (int i = 0; i < 4; ++i) {
        const int m = m0 + wv * 16 + q * 4 + i;
        float kp = 0.f;
        if (m < M_) {
          const float arg = fminf(NORMC * acc[i] - dgk - km, 0.f);
          kp = RATIOC * (__expf(arg) + EPSK);
        }
        kpl[wv * 16 + q * 4 + i][nt * 16 + r] = f2bf(kp);
        ksa[i] += kp;
      }
    }
    __syncthreads();
    {
      const bf16x8 a0 = *(const bf16x8*)&kpl[wv * 16 + r][q * 8];
      const bf16x8 a1 = *(const bf16x8*)&kpl[wv * 16 + r][32 + q * 8];
#pragma unroll
      for (int ct = 0; ct < 4; ++ct) {
        const bf16x8 b0 = *(const bf16x8*)&vtl[ct * 16 + r][q * 8];
        const bf16x8 b1 = *(const bf16x8*)&vtl[ct * 16 + r][32 + q * 8];
        cacc[ct] = MFMA16(a0, b0, cacc[ct]);
        cacc[ct] = MFMA16(a1, b1, cacc[ct]);
      }
    }
    __syncthreads();
  }
#pragma unroll
  for (int i = 0; i < 4; ++i)
    for (int s2 = 1; s2 < 16; s2 <<= 1) ksa[i] += __shfl_xor(ksa[i], s2, 64);
  if (r == 0) {
#pragma unroll
    for (int i = 0; i < 4; ++i)
      atomicAdd(&ksuma[bh * MP3_ + m0 + wv * 16 + q * 4 + i], ksa[i]);
  }
  float* sl = slab + (size_t)(bh * NZ_ + zi) * SLABM_ * DH_;
#pragma unroll
  for (int ct = 0; ct < 4; ++ct) {
#pragma unroll
    for (int i = 0; i < 4; ++i) {
      const int m = m0 + wv * 16 + q * 4 + i;
      if (m < SLABM_) sl[(size_t)m * DH_ + ct * 16 + r] = cacc[ct][i];
    }
  }
}

// ---------------- pack: reduce 8 z-slabs [m][d] fp32 -> transpose -> ctxT [d][288] bf16 ----
__global__ __launch_bounds__(256) void pack_kernel(const float* __restrict__ slab,
                                                   unsigned short* __restrict__ ctxT) {
  __shared__ float t[64][65];
  const int bh = blockIdx.x, m0 = blockIdx.y * 64;
  const int tid = threadIdx.x;
  const int mr = tid >> 4, d4 = (tid & 15) * 4;
#pragma unroll
  for (int pass = 0; pass < 4; ++pass) {
    const int ml = pass * 16 + mr;
    const int m = m0 + ml;
    float4 s = {0.f, 0.f, 0.f, 0.f};
    if (m < SLABM_) {
#pragma unroll
      for (int z = 0; z < NZ_; ++z) {
        const float4 v =
            *(const float4*)&slab[((size_t)(bh * NZ_ + z) * SLABM_ + m) * DH_ + d4];
        s.x += v.x; s.y += v.y; s.z += v.z; s.w += v.w;
      }
    }
    t[ml][d4 + 0] = s.x; t[ml][d4 + 1] = s.y; t[ml][d4 + 2] = s.z; t[ml][d4 + 3] = s.w;
  }
  __syncthreads();
  const int mc = tid & 63, dbase = tid >> 6;
  const int mo = m0 + mc;
  if (mo < MP2_) {
#pragma unroll
    for (int j = 0; j < 16; ++j) {
      const int d = dbase + j * 4;
      ctxT[((size_t)bh * DH_ + d) * MP2_ + mo] = f2bf(t[mc][d]);
    }
  }
}

// ---------------- fused QP + out GEMM: LDS-staged proj (time-shared with qp tile) ----------------
// LDS union: phase B reads proj from sP (staged once/block, [72]-stride = free 2-way);
// packed qp lives in REGISTERS (pk0/pk1[17], fully unrolled); after a barrier the
// same LDS becomes the qps tile (reg dump), then phase C reads A-frags from it.
// Removes all 34 per-wave L2 proj loads from the phase-B critical path.
__global__ __launch_bounds__(256) void qpout_mfma(
    const unsigned short* __restrict__ Qb, const unsigned short* __restrict__ projp,
    const float* __restrict__ rmaxq,
    const unsigned short* __restrict__ diag_q, const float* __restrict__ ksuma,
    const unsigned short* __restrict__ ctxT, unsigned short* __restrict__ attn) {
  __shared__ union SM {
    unsigned short sP[MP_][72];      // 39168 B  (phase B)
    unsigned int qps[4][16][149];    // 38144 B  (phase C; per-wave tile, stride 149 u32)
  } sm;
  const int bh = blockIdx.x, n0 = blockIdx.y * 64;
  const int tid = threadIdx.x;
  const int wv = tid >> 6, lane = tid & 63;
  const int r = lane & 15, q = lane >> 4;
  const int b_ = bh >> 3, h = bh & 7;
  // stage proj rows 0..271 into sP (coalesced 16B chunks)
  for (int c = tid; c < MP_ * 4; c += 256) {
    const int row = c >> 2, cb = (c & 3) * 8;
    *(uint4*)&sm.sP[row][cb] = *(const uint4*)&projp[row * DH_ + cb];
  }
  bf16x8 qb0, qb1;
  {
    const unsigned short* qrow = Qb + (size_t)(b_ * N_ + n0 + wv * 16 + r) * DIM_ + h * DH_;
    qb0 = *(const bf16x8*)(qrow + q * 8);
    qb1 = *(const bf16x8*)(qrow + 32 + q * 8);
  }
  const float rm = rmaxq[bh * N_ + n0 + wv * 16 + r];
  const float dg = bfu(diag_q[bh * N_ + n0 + wv * 16 + r]);
  const float Cl = LOG2R - dg * LOG2E - rm * KA;
  __syncthreads();
  // phase B: td -> exp+pack -> registers; denominator partial (rounded qp)
  unsigned int pk0[17], pk1[17];
  float part = 0.f;
#pragma unroll
  for (int mt = 0; mt < 17; ++mt) {
    const bf16x8 p0 = *(const bf16x8*)&sm.sP[mt * 16 + r][q * 8];
    const bf16x8 p1 = *(const bf16x8*)&sm.sP[mt * 16 + r][32 + q * 8];
    f32x4 acc = (f32x4){0.f, 0.f, 0.f, 0.f};
    acc = MFMA16(p0, qb0, acc);
    acc = MFMA16(p1, qb1, acc);
    const f32x4 kl = *(const f32x4*)&ksuma[bh * MP3_ + mt * 16 + q * 4];
    {
      const float s0 = fminf(acc[0] * KA + Cl, LOG2R);
      const float s1 = fminf(acc[1] * KA + Cl, LOG2R);
      const float e0 = exp2f(s0) + REPS;
      const float e1 = exp2f(s1) + REPS;
      unsigned int pkk;
      asm("v_cvt_pk_bf16_f32 %0, %1, %2" : "=v"(pkk) : "v"(e0), "v"(e1));
      pk0[mt] = pkk;
      union { unsigned int u; float f; } lo, hi;
      lo.u = pkk << 16; hi.u = pkk & 0xffff0000u;
      part += lo.f * kl[0] + hi.f * kl[1];
    }
    {
      const float s0 = fminf(acc[2] * KA + Cl, LOG2R);
      const float s1 = fminf(acc[3] * KA + Cl, LOG2R);
      const float e0 = exp2f(s0) + REPS;
      const float e1 = exp2f(s1) + REPS;
      unsigned int pkk;
      asm("v_cvt_pk_bf16_f32 %0, %1, %2" : "=v"(pkk) : "v"(e0), "v"(e1));
      pk1[mt] = pkk;
      union { unsigned int u; float f; } lo, hi;
      lo.u = pkk << 16; hi.u = pkk & 0xffff0000u;
      part += lo.f * kl[2] + hi.f * kl[3];
    }
  }
  __syncthreads();  // all waves done reading sP; LDS becomes qps
  // dump packed qp regs -> wave-private qps tile (row r, u32 cols mt*8 + q*2)
#pragma unroll
  for (int mt = 0; mt < 17; ++mt)
    *(uint2*)&sm.qps[wv][r][mt * 8 + q * 2] = make_uint2(pk0[mt], pk1[mt]);
  // zero pad u32 cols 136..143 (bf16 cols 272..287)
  *(uint2*)&sm.qps[wv][r][136 + q * 2] = make_uint2(0u, 0u);
  part += __shfl_xor(part, 16, 64);
  part += __shfl_xor(part, 32, 64);
  const float dinv = 1.f / fmaxf(part, 1e-30f);
  // Phase C: out = qp . ctxT (K = 288); A-frags from wave-private LDS tile
  f32x4 oacc[4];
#pragma unroll
  for (int i = 0; i < 4; ++i) oacc[i] = (f32x4){0.f, 0.f, 0.f, 0.f};
  const unsigned short* cbase = ctxT + (size_t)bh * DH_ * MP2_;
#pragma unroll
  for (int kc = 0; kc < 9; ++kc) {
    const bf16x8 af = *(const bf16x8*)&sm.qps[wv][r][kc * 16 + q * 4];
#pragma unroll
    for (int dt = 0; dt < 4; ++dt) {
      const bf16x8 bfr = *(const bf16x8*)&cbase[(size_t)(dt * 16 + r) * MP2_ + kc * 32 + q * 8];
      oacc[dt] = MFMA16(af, bfr, oacc[dt]);
    }
  }
  // dinv lives at lane with r = n-local; output rows n-local = q*4+i
  float dv[4];
#pragma unroll
  for (int i = 0; i < 4; ++i)
    dv[i] = __shfl(dinv, (lane & 48) | (q * 4 + i), 64);
#pragma unroll
  for (int dt = 0; dt < 4; ++dt) {
    const int d = dt * 16 + r;
#pragma unroll
    for (int i = 0; i < 4; ++i) {
      const int nn = wv * 16 + q * 4 + i;
      attn[(size_t)(b_ * N_ + n0 + nn) * DIM_ + h * DH_ + d] = f2bf(oacc[dt][i] * dv[i]);
    }
  }
}

// ---------------- final: 128x128 LDS-staged MFMA GEMM + residual (fp32 I/O) ----------------
__global__ __launch_bounds__(256) void final_mfma(
    const unsigned short* __restrict__ attn, const unsigned short* __restrict__ Wo,
    const float* __restrict__ bo, const float* __restrict__ x,
    float* __restrict__ out) {
  __shared__ unsigned short As[128 * 64];
  __shared__ unsigned short Bs[128 * 64];
  const int t0 = blockIdx.x * 128, e0 = blockIdx.y * 128;
  const int tid = threadIdx.x;
  const int wv = tid >> 6, lane = tid & 63;
  const int r = lane & 15, q = lane >> 4;
  const int wr = (wv >> 1) * 64, wc = (wv & 1) * 64;
  f32x4 acc[4][4];
#pragma unroll
  for (int i = 0; i < 4; ++i)
#pragma unroll
    for (int j = 0; j < 4; ++j) acc[i][j] = (f32x4){0.f, 0.f, 0.f, 0.f};
  const int srow = tid >> 3, scol = (tid & 7) * 8;
  for (int k0 = 0; k0 < DIM_; k0 += 64) {
#pragma unroll
    for (int j = 0; j < 4; ++j) {
      const int rr = srow + j * 32;
      *(uint4*)&As[rr * 64 + scol] = *(const uint4*)&attn[(size_t)(t0 + rr) * DIM_ + k0 + scol];
      *(uint4*)&Bs[rr * 64 + scol] = *(const uint4*)&Wo[(size_t)(e0 + rr) * DIM_ + k0 + scol];
    }
    __syncthreads();
#pragma unroll
    for (int kc = 0; kc < 2; ++kc) {
      bf16x8 af[4], bfr[4];
#pragma unroll
      for (int rt = 0; rt < 4; ++rt)
        af[rt] = *(const bf16x8*)&As[(wr + rt * 16 + r) * 64 + kc * 32 + q * 8];
#pragma unroll
      for (int ct = 0; ct < 4; ++ct)
        bfr[ct] = *(const bf16x8*)&Bs[(wc + ct * 16 + r) * 64 + kc * 32 + q * 8];
#pragma unroll
      for (int rt = 0; rt < 4; ++rt)
#pragma unroll
        for (int ct = 0; ct < 4; ++ct)
          acc[rt][ct] = MFMA16(af[rt], bfr[ct], acc[rt][ct]);
    }
    __syncthreads();
  }
#pragma unroll
  for (int rt = 0; rt < 4; ++rt) {
#pragma unroll
    for (int ct = 0; ct < 4; ++ct) {
      const int c = e0 + wc + ct * 16 + r;
      const float bov = bo[c];
#pragma unroll
      for (int i = 0; i < 4; ++i) {
        const int t = t0 + wr + rt * 16 + q * 4 + i;
        out[(size_t)t * DIM_ + c] = acc[rt][ct][i] + bov + x[(size_t)t * DIM_ + c];
      }
    }
  }
}

extern "C" void kernel_launch(void* const* d_in, const int* in_sizes, int n_in,
                              void* d_out, int out_size, void* d_ws, size_t ws_size,
                              hipStream_t stream) {
  const float* x = (const float*)d_in[0];
  const float* Wq = (const float*)d_in[1];
  const float* Wk = (const float*)d_in[2];
  const float* Wv = (const float*)d_in[3];
  const float* Wo = (const float*)d_in[4];
  const float* bo = (const float*)d_in[5];
  const float* proj = (const float*)d_in[6];
  char* ws = (char*)d_ws;
  unsigned short* projp = (unsigned short*)(ws + PROJP_B);
  float* kmax = (float*)(ws + KMAX_B);
  float* ksuma = (float*)(ws + KSUMA_B);
  float* ctxa = (float*)(ws + CTXA_B);
  unsigned short* ctxT = (unsigned short*)(ws + CTXT_B);
  unsigned short* diag_q = (unsigned short*)(ws + DIAGQ_B);
  unsigned short* diag_k = (unsigned short*)(ws + DIAGK_B);
  unsigned short* xbf = (unsigned short*)(ws + XBF_B);
  unsigned short* wqb = (unsigned short*)(ws + WQ_B);
  unsigned short* wkb = (unsigned short*)(ws + WK_B);
  unsigned short* wvb = (unsigned short*)(ws + WV_B);
  unsigned short* wob = (unsigned short*)(ws + WO_B);
  unsigned short* Q = (unsigned short*)(ws + Q_B);
  unsigned short* K = (unsigned short*)(ws + K_B);
  unsigned short* VT = (unsigned short*)(ws + VT_B);
  float* rmaxq = (float*)(ws + RMAXQ_B);
  unsigned short* attn = K;  // K dead after ctxfused_mfma
  float* out = (float*)d_out;

  cvt_kernel<<<1024, 256, 0, stream>>>(x, xbf, 8388608);
  cvt_kernel<<<128, 256, 0, stream>>>(Wq, wqb, 262144);
  cvt_kernel<<<128, 256, 0, stream>>>(Wk, wkb, 262144);
  cvt_kernel<<<128, 256, 0, stream>>>(Wv, wvb, 262144);
  cvt_kernel<<<128, 256, 0, stream>>>(Wo, wob, 262144);
  setup_kernel<<<80, 256, 0, stream>>>(proj, projp, kmax, ksuma);
  qkv_mfma<<<dim3(NT_ / 128, DIM_ / 128, 3), 256, 0, stream>>>(xbf, wqb, wkb, wvb, Q, K, VT);
  diag_kernel<<<dim3(512, 2), 256, 0, stream>>>(Q, K, diag_q, diag_k);
  kmax_mfma<<<dim3(BH_, N_ / 256), 256, 0, stream>>>(K, Q, projp, kmax, rmaxq);
  ctxfused_mfma<<<dim3(BH_, 5, NZ_), 256, 0, stream>>>(K, VT, projp, diag_k, kmax, ksuma, ctxa);
  pack_kernel<<<dim3(BH_, 5), 256, 0, stream>>>(ctxa, ctxT);
  qpout_mfma<<<dim3(BH_, 64), 256, 0, stream>>>(Q, projp, rmaxq, diag_q, ksuma, ctxT, attn);
  final_mfma<<<dim3(NT_ / 128, DIM_ / 128), 256, 0, stream>>>(attn, wob, bo, x, out);
}

// Round 7
// 292.632 us; speedup vs baseline: 1.2141x; 1.0058x over previous
//
#include <hip/hip_runtime.h>

#define N_ 4096
#define DIM_ 512
#define H_ 8
#define DH_ 64
#define M_ 266
#define MP_ 272      // ksum/qp live range padded to 272 (17 tiles of 16)
#define MP2_ 288     // out-GEMM K padded to 9 chunks of 32
#define MP3_ 320     // ksuma / projp m padded to 5 chunks of 64
#define SLABM_ 280   // ctx partial-slab m extent (>= M_=266, trimmed to fit overlay)
#define NZ_ 8        // n-split for ctxfused
#define NT_ 16384
#define BH_ 32

#define NORMC 0.3535533905932738f   // 64^-0.25
#define RATIOC 0.06131393394849658f // 266^-0.5
#define EPSK 1e-4f
#define DIAGC 0.0625f               // 0.5 * normalizer^2
// folded exp2 constants: qp = exp2(min(raw*KA + Cl, LOG2R)) + REPS
#define KA 0.51006971f              // NORMC * log2(e)
#define LOG2R -4.0276408f           // log2(RATIOC)
#define LOG2E 1.4426950408889634f
#define REPS 6.131393e-6f           // RATIOC * EPSK

// ---- ws layout (byte offsets), total ~71.5 MB ----
// ctx slabs (18,350,080 B) overlay xbf+wqb+wkb+wvb, dead after qkv_mfma.
#define PROJP_B 0ul            // 40960
#define KMAX_B  40960ul        // 128
#define KSUMA_B 41088ul        // 40960
#define WO_B    82048ul        // 524288
#define CTXT_B  606336ul       // 1179648
#define DIAGQ_B 1785984ul      // 262144
#define DIAGK_B 2048128ul      // 262144
#define XBF_B   2310272ul      // 16777216
#define WQ_B    19087488ul     // 524288
#define WK_B    19611776ul     // 524288
#define WV_B    20136064ul     // 524288
#define CTXA_B  2310272ul      // == XBF_B, 32*8*280*64*4 = 18350080 (ends at Q_B)
#define Q_B     20660352ul     // 16777216
#define K_B     37437568ul     // 16777216
#define VT_B    54214784ul     // 16777216
#define RMAXQ_B 70992000ul     // 524288 (32*4096 f32) -> end 71,516,288

typedef __bf16 bf16x8 __attribute__((ext_vector_type(8)));
typedef float f32x4 __attribute__((ext_vector_type(4)));
#define MFMA16(a, b, c) __builtin_amdgcn_mfma_f32_16x16x32_bf16((a), (b), (c), 0, 0, 0)

// async global->LDS, 16B per lane; LDS dest = wave-uniform base + lane*16
typedef __attribute__((address_space(1))) const unsigned int* gas_t;
typedef __attribute__((address_space(3))) unsigned int* las_t;
__device__ __forceinline__ void gload16(const void* g, void* l) {
  __builtin_amdgcn_global_load_lds((gas_t)g, (las_t)l, 16, 0, 0);
}

__device__ __forceinline__ float bfu(unsigned short u) {
  union { unsigned int i; float f; } x; x.i = ((unsigned int)u) << 16; return x.f;
}
__device__ __forceinline__ unsigned short f2bf(float f) {
  union { float f; unsigned int i; } u; u.f = f;
  unsigned int r = u.i + 0x7fffu + ((u.i >> 16) & 1u);
  return (unsigned short)(r >> 16);
}
__device__ __forceinline__ void atomicMaxF(float* addr, float val) {
  int* ai = (int*)addr;
  while (true) {
    float cur = __int_as_float(*(volatile int*)ai);
    if (val <= cur) break;
    int old = atomicCAS(ai, __float_as_int(cur), __float_as_int(val));
    if (old == __float_as_int(cur)) break;
  }
}

// ---------------- fp32 -> bf16 conversion ----------------
__global__ void cvt_kernel(const float* __restrict__ src, unsigned short* __restrict__ dst, int n) {
  int i = (blockIdx.x * 256 + threadIdx.x) * 4;
  const int stride = gridDim.x * 1024;
  for (; i < n; i += stride) {
    const float4 v = *(const float4*)(src + i);
    ushort4 u;
    u.x = f2bf(v.x); u.y = f2bf(v.y); u.z = f2bf(v.z); u.w = f2bf(v.w);
    *(ushort4*)(dst + i) = u;
  }
}

// ---------------- setup: proj cvt+pad(320), kmax init, ksuma zero ----------------
__global__ void setup_kernel(const float* __restrict__ proj,
                             unsigned short* __restrict__ projp,
                             float* __restrict__ kmax,
                             float* __restrict__ ksuma) {
  const int i = blockIdx.x * 256 + threadIdx.x;
  const int stride = gridDim.x * 256;
  for (int j = i; j < MP3_ * DH_; j += stride)
    projp[j] = (j < M_ * DH_) ? f2bf(proj[j]) : (unsigned short)0;
  for (int j = i; j < BH_; j += stride) kmax[j] = -3e38f;
  for (int j = i; j < BH_ * MP3_; j += stride) ksuma[j] = 0.f;
}

// ---------------- QKV projection: 128x128 MFMA GEMM, global_load_lds staging ----------------
__global__ __launch_bounds__(256) void qkv_mfma(
    const unsigned short* __restrict__ x, const unsigned short* __restrict__ Wq,
    const unsigned short* __restrict__ Wk, const unsigned short* __restrict__ Wv,
    unsigned short* __restrict__ Q, unsigned short* __restrict__ K,
    unsigned short* __restrict__ VT) {
  __shared__ unsigned short As[128 * 64];
  __shared__ unsigned short Bs[128 * 64];
  const int z = blockIdx.z;
  const unsigned short* W = (z == 0) ? Wq : (z == 1) ? Wk : Wv;
  const int t0 = blockIdx.x * 128, e0 = blockIdx.y * 128;
  const int tid = threadIdx.x;
  const int wv = tid >> 6, lane = tid & 63;
  const int r = lane & 15, q = lane >> 4;
  const int wr = (wv >> 1) * 64, wc = (wv & 1) * 64;
  f32x4 acc[4][4];
#pragma unroll
  for (int i = 0; i < 4; ++i)
#pragma unroll
    for (int j = 0; j < 4; ++j) acc[i][j] = (f32x4){0.f, 0.f, 0.f, 0.f};
  // async staging: wave wv covers rows wv*32 + j*8 + (lane>>3), col (lane&7)*8
  const int lrow = lane >> 3, lcol = (lane & 7) * 8;
  for (int k0 = 0; k0 < DIM_; k0 += 64) {
#pragma unroll
    for (int j = 0; j < 4; ++j) {
      const int rr = wv * 32 + j * 8;
      gload16(&x[(size_t)(t0 + rr + lrow) * DIM_ + k0 + lcol], &As[rr * 64]);
      gload16(&W[(size_t)(e0 + rr + lrow) * DIM_ + k0 + lcol], &Bs[rr * 64]);
    }
    __syncthreads();
#pragma unroll
    for (int kc = 0; kc < 2; ++kc) {
      bf16x8 af[4], bfr[4];
#pragma unroll
      for (int rt = 0; rt < 4; ++rt)
        af[rt] = *(const bf16x8*)&As[(wr + rt * 16 + r) * 64 + kc * 32 + q * 8];
#pragma unroll
      for (int ct = 0; ct < 4; ++ct)
        bfr[ct] = *(const bf16x8*)&Bs[(wc + ct * 16 + r) * 64 + kc * 32 + q * 8];
#pragma unroll
      for (int rt = 0; rt < 4; ++rt)
#pragma unroll
        for (int ct = 0; ct < 4; ++ct)
          acc[rt][ct] = MFMA16(af[rt], bfr[ct], acc[rt][ct]);
    }
    __syncthreads();
  }
  if (z < 2) {
    unsigned short* dst = (z == 0) ? Q : K;
#pragma unroll
    for (int rt = 0; rt < 4; ++rt) {
#pragma unroll
      for (int ct = 0; ct < 4; ++ct) {
        const int e = e0 + wc + ct * 16 + r;
#pragma unroll
        for (int i = 0; i < 4; ++i) {
          const int t = t0 + wr + rt * 16 + q * 4 + i;
          dst[(size_t)t * DIM_ + e] = f2bf(acc[rt][ct][i]);
        }
      }
    }
  } else {
#pragma unroll
    for (int rt = 0; rt < 4; ++rt) {
      const int t = t0 + wr + rt * 16 + q * 4;
      const int b_ = t >> 12, n = t & (N_ - 1);
#pragma unroll
      for (int ct = 0; ct < 4; ++ct) {
        const int e = e0 + wc + ct * 16 + r;
        const int h = e >> 6, dh = e & 63;
        ushort4 pk;
        pk.x = f2bf(acc[rt][ct][0]); pk.y = f2bf(acc[rt][ct][1]);
        pk.z = f2bf(acc[rt][ct][2]); pk.w = f2bf(acc[rt][ct][3]);
        *(ushort4*)&VT[((size_t)((b_ * H_ + h) * DH_ + dh)) * N_ + n] = pk;
      }
    }
  }
}

// ---------------- diag: DIAGC * sum(t*t) per (bh, n), stored bf16 ----------------
__global__ void diag_kernel(const unsigned short* __restrict__ Q,
                            const unsigned short* __restrict__ K,
                            unsigned short* __restrict__ dq, unsigned short* __restrict__ dk) {
  const int i = blockIdx.x * 256 + threadIdx.x;
  const int bh = i >> 12, n = i & (N_ - 1);
  const int b_ = bh >> 3, h = bh & 7;
  const unsigned short* src = ((blockIdx.y == 0) ? Q : K) + (size_t)(b_ * N_ + n) * DIM_ + h * DH_;
  float s = 0.f;
#pragma unroll
  for (int c = 0; c < 16; ++c) {
    const ushort4 u = ((const ushort4*)src)[c];
    const float a = bfu(u.x), b2 = bfu(u.y), cc = bfu(u.z), d = bfu(u.w);
    s += a * a + b2 * b2 + cc * cc + d * d;
  }
  ((blockIdx.y == 0) ? dq : dk)[i] = f2bf(s * DIAGC);
}

// ---------------- kmax/qmax (MFMA, merged): K global max + Q per-row max ----------------
__global__ __launch_bounds__(256) void kmax_mfma(
    const unsigned short* __restrict__ K, const unsigned short* __restrict__ Qb,
    const unsigned short* __restrict__ projp,
    float* __restrict__ kmax, float* __restrict__ rmaxq) {
  __shared__ unsigned short sP[MP_][72];
  __shared__ float wm[4];
  const int bh = blockIdx.x, n0 = blockIdx.y * 256;
  const int tid = threadIdx.x;
  const int wv = tid >> 6, lane = tid & 63;
  const int r = lane & 15, q = lane >> 4;
  const int b_ = bh >> 3, h = bh & 7;
  // stage proj rows 0..271 (coalesced 16B chunks)
  for (int c = tid; c < MP_ * 4; c += 256) {
    const int row = c >> 2, cb = (c & 3) * 8;
    *(uint4*)&sP[row][cb] = *(const uint4*)&projp[row * DH_ + cb];
  }
  // load 4 K-strips + 4 Q-strips: rows nbase + st*16 + r
  bf16x8 kb[4][2], qb[4][2];
  const int nbase = n0 + wv * 64;
#pragma unroll
  for (int st = 0; st < 4; ++st) {
    const size_t off = (size_t)(b_ * N_ + nbase + st * 16 + r) * DIM_ + h * DH_;
    kb[st][0] = *(const bf16x8*)(K + off + q * 8);
    kb[st][1] = *(const bf16x8*)(K + off + 32 + q * 8);
    qb[st][0] = *(const bf16x8*)(Qb + off + q * 8);
    qb[st][1] = *(const bf16x8*)(Qb + off + 32 + q * 8);
  }
  __syncthreads();
  float km = -3e38f;
  float qm[4] = {-3e38f, -3e38f, -3e38f, -3e38f};
  for (int mt = 0; mt < 17; ++mt) {
    const bf16x8 p0 = *(const bf16x8*)&sP[mt * 16 + r][q * 8];
    const bf16x8 p1 = *(const bf16x8*)&sP[mt * 16 + r][32 + q * 8];
#pragma unroll
    for (int st = 0; st < 4; ++st) {
      f32x4 ka = (f32x4){0.f, 0.f, 0.f, 0.f};
      ka = MFMA16(p0, kb[st][0], ka);
      ka = MFMA16(p1, kb[st][1], ka);
      f32x4 qa = (f32x4){0.f, 0.f, 0.f, 0.f};
      qa = MFMA16(p0, qb[st][0], qa);
      qa = MFMA16(p1, qb[st][1], qa);
#pragma unroll
      for (int i = 0; i < 4; ++i) {
        const int m = mt * 16 + q * 4 + i;
        if (m < M_) {
          km = fmaxf(km, ka[i]);
          qm[st] = fmaxf(qm[st], qa[i]);
        }
      }
    }
  }
  // Q: per-row raw max -- combine the 4 q-groups (m coverage) per row
#pragma unroll
  for (int st = 0; st < 4; ++st) {
    float v = qm[st];
    v = fmaxf(v, __shfl_xor(v, 16, 64));
    v = fmaxf(v, __shfl_xor(v, 32, 64));
    if (q == 0) rmaxq[bh * N_ + nbase + st * 16 + r] = v;
  }
  // K: block max -> atomic
  for (int s2 = 1; s2 < 64; s2 <<= 1) km = fmaxf(km, __shfl_xor(km, s2, 64));
  if (lane == 0) wm[wv] = km;
  __syncthreads();
  if (tid == 0) {
    const float m = fmaxf(fmaxf(wm[0], wm[1]), fmaxf(wm[2], wm[3])) * NORMC;
    atomicMaxF(&kmax[bh], m);
  }
}

// ---------------- fused: td -> exp -> kp; ctx += kp x VT; ksum ----------------
__global__ __launch_bounds__(256) void ctxfused_mfma(
    const unsigned short* __restrict__ K, const unsigned short* __restrict__ VT,
    const unsigned short* __restrict__ projp, const unsigned short* __restrict__ diag_k,
    const float* __restrict__ kmaxv, float* __restrict__ ksuma,
    float* __restrict__ slab) {
  __shared__ unsigned short kll[64][72];
  __shared__ unsigned short vtl[64][72];
  __shared__ unsigned short kpl[64][72];
  __shared__ float dgl[64];
  const int bh = blockIdx.x, m0 = blockIdx.y * 64, zi = blockIdx.z;
  const int nbase = zi * 512;
  const int tid = threadIdx.x;
  const int wv = tid >> 6, lane = tid & 63;
  const int r = lane & 15, q = lane >> 4;
  const int b_ = bh >> 3, h = bh & 7;
  const float km = kmaxv[bh];
  const unsigned short* prow = projp + (size_t)(m0 + wv * 16 + r) * DH_;
  const bf16x8 p0 = *(const bf16x8*)(prow + q * 8);
  const bf16x8 p1 = *(const bf16x8*)(prow + 32 + q * 8);
  const unsigned short* kbase = K + (size_t)(b_ * N_) * DIM_ + h * DH_;
  const unsigned short* vbase = VT + (size_t)bh * DH_ * N_;
  f32x4 cacc[4];
#pragma unroll
  for (int i = 0; i < 4; ++i) cacc[i] = (f32x4){0.f, 0.f, 0.f, 0.f};
  float ksa[4] = {0.f, 0.f, 0.f, 0.f};
  for (int nc = 0; nc < 8; ++nc) {
    const int n0c = nbase + nc * 64;
#pragma unroll
    for (int j = 0; j < 4; ++j) {
      const int idx = tid + j * 256;
      const int rr = idx >> 4, c4 = (idx & 15) << 2;
      *(ushort4*)&kll[rr][c4] = *(const ushort4*)&kbase[(size_t)(n0c + rr) * DIM_ + c4];
      *(ushort4*)&vtl[rr][c4] = *(const ushort4*)&vbase[(size_t)rr * N_ + n0c + c4];
    }
    if (tid < 16) {
      const ushort4 du = *(const ushort4*)&diag_k[bh * N_ + n0c + tid * 4];
      dgl[tid * 4 + 0] = bfu(du.x); dgl[tid * 4 + 1] = bfu(du.y);
      dgl[tid * 4 + 2] = bfu(du.z); dgl[tid * 4 + 3] = bfu(du.w);
    }
    __syncthreads();
#pragma unroll
    for (int nt = 0; nt < 4; ++nt) {
      const bf16x8 kb0 = *(const bf16x8*)&kll[nt * 16 + r][q * 8];
      const bf16x8 kb1 = *(const bf16x8*)&kll[nt * 16 + r][32 + q * 8];
      f32x4 acc = (f32x4){0.f, 0.f, 0.f, 0.f};
      acc = MFMA16(p0, kb0, acc);
      acc = MFMA16(p1, kb1, acc);
      const float dgk = dgl[nt * 16 + r];
#pragma unroll
      for (int i = 0; i < 4; ++i) {
        const int m = m0 + wv * 16 + q * 4 + i;
        float kp = 0.f;
        if (m < M_) {
          const float arg = fminf(NORMC * acc[i] - dgk - km, 0.f);
          kp = RATIOC * (__expf(arg) + EPSK);
        }
        kpl[wv * 16 + q * 4 + i][nt * 16 + r] = f2bf(kp);
        ksa[i] += kp;
      }
    }
    __syncthreads();
    {
      const bf16x8 a0 = *(const bf16x8*)&kpl[wv * 16 + r][q * 8];
      const bf16x8 a1 = *(const bf16x8*)&kpl[wv * 16 + r][32 + q * 8];
#pragma unroll
      for (int ct = 0; ct < 4; ++ct) {
        const bf16x8 b0 = *(const bf16x8*)&vtl[ct * 16 + r][q * 8];
        const bf16x8 b1 = *(const bf16x8*)&vtl[ct * 16 + r][32 + q * 8];
        cacc[ct] = MFMA16(a0, b0, cacc[ct]);
        cacc[ct] = MFMA16(a1, b1, cacc[ct]);
      }
    }
    __syncthreads();
  }
#pragma unroll
  for (int i = 0; i < 4; ++i)
    for (int s2 = 1; s2 < 16; s2 <<= 1) ksa[i] += __shfl_xor(ksa[i], s2, 64);
  if (r == 0) {
#pragma unroll
    for (int i = 0; i < 4; ++i)
      atomicAdd(&ksuma[bh * MP3_ + m0 + wv * 16 + q * 4 + i], ksa[i]);
  }
  float* sl = slab + (size_t)(bh * NZ_ + zi) * SLABM_ * DH_;
#pragma unroll
  for (int ct = 0; ct < 4; ++ct) {
#pragma unroll
    for (int i = 0; i < 4; ++i) {
      const int m = m0 + wv * 16 + q * 4 + i;
      if (m < SLABM_) sl[(size_t)m * DH_ + ct * 16 + r] = cacc[ct][i];
    }
  }
}

// ---------------- pack: reduce 8 z-slabs [m][d] fp32 -> transpose -> ctxT [d][288] bf16 ----
__global__ __launch_bounds__(256) void pack_kernel(const float* __restrict__ slab,
                                                   unsigned short* __restrict__ ctxT) {
  __shared__ float t[64][65];
  const int bh = blockIdx.x, m0 = blockIdx.y * 64;
  const int tid = threadIdx.x;
  const int mr = tid >> 4, d4 = (tid & 15) * 4;
#pragma unroll
  for (int pass = 0; pass < 4; ++pass) {
    const int ml = pass * 16 + mr;
    const int m = m0 + ml;
    float4 s = {0.f, 0.f, 0.f, 0.f};
    if (m < SLABM_) {
#pragma unroll
      for (int z = 0; z < NZ_; ++z) {
        const float4 v =
            *(const float4*)&slab[((size_t)(bh * NZ_ + z) * SLABM_ + m) * DH_ + d4];
        s.x += v.x; s.y += v.y; s.z += v.z; s.w += v.w;
      }
    }
    t[ml][d4 + 0] = s.x; t[ml][d4 + 1] = s.y; t[ml][d4 + 2] = s.z; t[ml][d4 + 3] = s.w;
  }
  __syncthreads();
  const int mc = tid & 63, dbase = tid >> 6;
  const int mo = m0 + mc;
  if (mo < MP2_) {
#pragma unroll
    for (int j = 0; j < 16; ++j) {
      const int d = dbase + j * 4;
      ctxT[((size_t)bh * DH_ + d) * MP2_ + mo] = f2bf(t[mc][d]);
    }
  }
}

// ---------------- fused QP + out GEMM: LDS-staged proj (time-shared with qp tile) ----------------
__global__ __launch_bounds__(256) void qpout_mfma(
    const unsigned short* __restrict__ Qb, const unsigned short* __restrict__ projp,
    const float* __restrict__ rmaxq,
    const unsigned short* __restrict__ diag_q, const float* __restrict__ ksuma,
    const unsigned short* __restrict__ ctxT, unsigned short* __restrict__ attn) {
  __shared__ union SM {
    unsigned short sP[MP_][72];      // 39168 B  (phase B)
    unsigned int qps[4][16][149];    // 38144 B  (phase C; per-wave tile, stride 149 u32)
  } sm;
  const int bh = blockIdx.x, n0 = blockIdx.y * 64;
  const int tid = threadIdx.x;
  const int wv = tid >> 6, lane = tid & 63;
  const int r = lane & 15, q = lane >> 4;
  const int b_ = bh >> 3, h = bh & 7;
  // stage proj rows 0..271 into sP (coalesced 16B chunks)
  for (int c = tid; c < MP_ * 4; c += 256) {
    const int row = c >> 2, cb = (c & 3) * 8;
    *(uint4*)&sm.sP[row][cb] = *(const uint4*)&projp[row * DH_ + cb];
  }
  bf16x8 qb0, qb1;
  {
    const unsigned short* qrow = Qb + (size_t)(b_ * N_ + n0 + wv * 16 + r) * DIM_ + h * DH_;
    qb0 = *(const bf16x8*)(qrow + q * 8);
    qb1 = *(const bf16x8*)(qrow + 32 + q * 8);
  }
  const float rm = rmaxq[bh * N_ + n0 + wv * 16 + r];
  const float dg = bfu(diag_q[bh * N_ + n0 + wv * 16 + r]);
  const float Cl = LOG2R - dg * LOG2E - rm * KA;
  __syncthreads();
  // phase B: td -> exp+pack -> registers; denominator partial (rounded qp)
  unsigned int pk0[17], pk1[17];
  float part = 0.f;
#pragma unroll
  for (int mt = 0; mt < 17; ++mt) {
    const bf16x8 p0 = *(const bf16x8*)&sm.sP[mt * 16 + r][q * 8];
    const bf16x8 p1 = *(const bf16x8*)&sm.sP[mt * 16 + r][32 + q * 8];
    f32x4 acc = (f32x4){0.f, 0.f, 0.f, 0.f};
    acc = MFMA16(p0, qb0, acc);
    acc = MFMA16(p1, qb1, acc);
    const f32x4 kl = *(const f32x4*)&ksuma[bh * MP3_ + mt * 16 + q * 4];
    {
      const float s0 = fminf(acc[0] * KA + Cl, LOG2R);
      const float s1 = fminf(acc[1] * KA + Cl, LOG2R);
      const float e0 = exp2f(s0) + REPS;
      const float e1 = exp2f(s1) + REPS;
      unsigned int pkk;
      asm("v_cvt_pk_bf16_f32 %0, %1, %2" : "=v"(pkk) : "v"(e0), "v"(e1));
      pk0[mt] = pkk;
      union { unsigned int u; float f; } lo, hi;
      lo.u = pkk << 16; hi.u = pkk & 0xffff0000u;
      part += lo.f * kl[0] + hi.f * kl[1];
    }
    {
      const float s0 = fminf(acc[2] * KA + Cl, LOG2R);
      const float s1 = fminf(acc[3] * KA + Cl, LOG2R);
      const float e0 = exp2f(s0) + REPS;
      const float e1 = exp2f(s1) + REPS;
      unsigned int pkk;
      asm("v_cvt_pk_bf16_f32 %0, %1, %2" : "=v"(pkk) : "v"(e0), "v"(e1));
      pk1[mt] = pkk;
      union { unsigned int u; float f; } lo, hi;
      lo.u = pkk << 16; hi.u = pkk & 0xffff0000u;
      part += lo.f * kl[2] + hi.f * kl[3];
    }
  }
  __syncthreads();  // all waves done reading sP; LDS becomes qps
  // dump packed qp regs -> wave-private qps tile (row r, u32 cols mt*8 + q*2)
#pragma unroll
  for (int mt = 0; mt < 17; ++mt)
    *(uint2*)&sm.qps[wv][r][mt * 8 + q * 2] = make_uint2(pk0[mt], pk1[mt]);
  // zero pad u32 cols 136..143 (bf16 cols 272..287)
  *(uint2*)&sm.qps[wv][r][136 + q * 2] = make_uint2(0u, 0u);
  part += __shfl_xor(part, 16, 64);
  part += __shfl_xor(part, 32, 64);
  const float dinv = 1.f / fmaxf(part, 1e-30f);
  // Phase C: out = qp . ctxT (K = 288); A-frags from wave-private LDS tile
  f32x4 oacc[4];
#pragma unroll
  for (int i = 0; i < 4; ++i) oacc[i] = (f32x4){0.f, 0.f, 0.f, 0.f};
  const unsigned short* cbase = ctxT + (size_t)bh * DH_ * MP2_;
#pragma unroll
  for (int kc = 0; kc < 9; ++kc) {
    const bf16x8 af = *(const bf16x8*)&sm.qps[wv][r][kc * 16 + q * 4];
#pragma unroll
    for (int dt = 0; dt < 4; ++dt) {
      const bf16x8 bfr = *(const bf16x8*)&cbase[(size_t)(dt * 16 + r) * MP2_ + kc * 32 + q * 8];
      oacc[dt] = MFMA16(af, bfr, oacc[dt]);
    }
  }
  // dinv lives at lane with r = n-local; output rows n-local = q*4+i
  float dv[4];
#pragma unroll
  for (int i = 0; i < 4; ++i)
    dv[i] = __shfl(dinv, (lane & 48) | (q * 4 + i), 64);
#pragma unroll
  for (int dt = 0; dt < 4; ++dt) {
    const int d = dt * 16 + r;
#pragma unroll
    for (int i = 0; i < 4; ++i) {
      const int nn = wv * 16 + q * 4 + i;
      attn[(size_t)(b_ * N_ + n0 + nn) * DIM_ + h * DH_ + d] = f2bf(oacc[dt][i] * dv[i]);
    }
  }
}

// ---------------- final: 128x128 MFMA GEMM + residual, global_load_lds staging ----------------
__global__ __launch_bounds__(256) void final_mfma(
    const unsigned short* __restrict__ attn, const unsigned short* __restrict__ Wo,
    const float* __restrict__ bo, const float* __restrict__ x,
    float* __restrict__ out) {
  __shared__ unsigned short As[128 * 64];
  __shared__ unsigned short Bs[128 * 64];
  const int t0 = blockIdx.x * 128, e0 = blockIdx.y * 128;
  const int tid = threadIdx.x;
  const int wv = tid >> 6, lane = tid & 63;
  const int r = lane & 15, q = lane >> 4;
  const int wr = (wv >> 1) * 64, wc = (wv & 1) * 64;
  f32x4 acc[4][4];
#pragma unroll
  for (int i = 0; i < 4; ++i)
#pragma unroll
    for (int j = 0; j < 4; ++j) acc[i][j] = (f32x4){0.f, 0.f, 0.f, 0.f};
  const int lrow = lane >> 3, lcol = (lane & 7) * 8;
  for (int k0 = 0; k0 < DIM_; k0 += 64) {
#pragma unroll
    for (int j = 0; j < 4; ++j) {
      const int rr = wv * 32 + j * 8;
      gload16(&attn[(size_t)(t0 + rr + lrow) * DIM_ + k0 + lcol], &As[rr * 64]);
      gload16(&Wo[(size_t)(e0 + rr + lrow) * DIM_ + k0 + lcol], &Bs[rr * 64]);
    }
    __syncthreads();
#pragma unroll
    for (int kc = 0; kc < 2; ++kc) {
      bf16x8 af[4], bfr[4];
#pragma unroll
      for (int rt = 0; rt < 4; ++rt)
        af[rt] = *(const bf16x8*)&As[(wr + rt * 16 + r) * 64 + kc * 32 + q * 8];
#pragma unroll
      for (int ct = 0; ct < 4; ++ct)
        bfr[ct] = *(const bf16x8*)&Bs[(wc + ct * 16 + r) * 64 + kc * 32 + q * 8];
#pragma unroll
      for (int rt = 0; rt < 4; ++rt)
#pragma unroll
        for (int ct = 0; ct < 4; ++ct)
          acc[rt][ct] = MFMA16(af[rt], bfr[ct], acc[rt][ct]);
    }
    __syncthreads();
  }
#pragma unroll
  for (int rt = 0; rt < 4; ++rt) {
#pragma unroll
    for (int ct = 0; ct < 4; ++ct) {
      const int c = e0 + wc + ct * 16 + r;
      const float bov = bo[c];
#pragma unroll
      for (int i = 0; i < 4; ++i) {
        const int t = t0 + wr + rt * 16 + q * 4 + i;
        out[(size_t)t * DIM_ + c] = acc[rt][ct][i] + bov + x[(size_t)t * DIM_ + c];
      }
    }
  }
}

extern "C" void kernel_launch(void* const* d_in, const int* in_sizes, int n_in,
                              void* d_out, int out_size, void* d_ws, size_t ws_size,
                              hipStream_t stream) {
  const float* x = (const float*)d_in[0];
  const float* Wq = (const float*)d_in[1];
  const float* Wk = (const float*)d_in[2];
  const float* Wv = (const float*)d_in[3];
  const float* Wo = (const float*)d_in[4];
  const float* bo = (const float*)d_in[5];
  const float* proj = (const float*)d_in[6];
  char* ws = (char*)d_ws;
  unsigned short* projp = (unsigned short*)(ws + PROJP_B);
  float* kmax = (float*)(ws + KMAX_B);
  float* ksuma = (float*)(ws + KSUMA_B);
  float* ctxa = (float*)(ws + CTXA_B);
  unsigned short* ctxT = (unsigned short*)(ws + CTXT_B);
  unsigned short* diag_q = (unsigned short*)(ws + DIAGQ_B);
  unsigned short* diag_k = (unsigned short*)(ws + DIAGK_B);
  unsigned short* xbf = (unsigned short*)(ws + XBF_B);
  unsigned short* wqb = (unsigned short*)(ws + WQ_B);
  unsigned short* wkb = (unsigned short*)(ws + WK_B);
  unsigned short* wvb = (unsigned short*)(ws + WV_B);
  unsigned short* wob = (unsigned short*)(ws + WO_B);
  unsigned short* Q = (unsigned short*)(ws + Q_B);
  unsigned short* K = (unsigned short*)(ws + K_B);
  unsigned short* VT = (unsigned short*)(ws + VT_B);
  float* rmaxq = (float*)(ws + RMAXQ_B);
  unsigned short* attn = K;  // K dead after ctxfused_mfma
  float* out = (float*)d_out;

  cvt_kernel<<<1024, 256, 0, stream>>>(x, xbf, 8388608);
  cvt_kernel<<<128, 256, 0, stream>>>(Wq, wqb, 262144);
  cvt_kernel<<<128, 256, 0, stream>>>(Wk, wkb, 262144);
  cvt_kernel<<<128, 256, 0, stream>>>(Wv, wvb, 262144);
  cvt_kernel<<<128, 256, 0, stream>>>(Wo, wob, 262144);
  setup_kernel<<<80, 256, 0, stream>>>(proj, projp, kmax, ksuma);
  qkv_mfma<<<dim3(NT_ / 128, DIM_ / 128, 3), 256, 0, stream>>>(xbf, wqb, wkb, wvb, Q, K, VT);
  diag_kernel<<<dim3(512, 2), 256, 0, stream>>>(Q, K, diag_q, diag_k);
  kmax_mfma<<<dim3(BH_, N_ / 256), 256, 0, stream>>>(K, Q, projp, kmax, rmaxq);
  ctxfused_mfma<<<dim3(BH_, 5, NZ_), 256, 0, stream>>>(K, VT, projp, diag_k, kmax, ksuma, ctxa);
  pack_kernel<<<dim3(BH_, 5), 256, 0, stream>>>(ctxa, ctxT);
  qpout_mfma<<<dim3(BH_, 64), 256, 0, stream>>>(Q, projp, rmaxq, diag_q, ksuma, ctxT, attn);
  final_mfma<<<dim3(NT_ / 128, DIM_ / 128), 256, 0, stream>>>(attn, wob, bo, x, out);
}

// Round 8
// 284.163 us; speedup vs baseline: 1.2503x; 1.0298x over previous
//
#include <hip/hip_runtime.h>

#define N_ 4096
#define DIM_ 512
#define H_ 8
#define DH_ 64
#define M_ 266
#define MP_ 272      // ksum/qp live range padded to 272 (17 tiles of 16)
#define MP2_ 288     // out-GEMM K padded to 9 chunks of 32
#define MP3_ 320     // ksuma / projp m padded to 5 chunks of 64
#define SLABM_ 280   // ctx partial-slab m extent (>= M_=266, trimmed to fit overlay)
#define NZ_ 8        // n-split for ctxfused
#define NT_ 16384
#define BH_ 32

#define NORMC 0.3535533905932738f   // 64^-0.25
#define RATIOC 0.06131393394849658f // 266^-0.5
#define EPSK 1e-4f
#define DIAGC 0.0625f               // 0.5 * normalizer^2
// folded exp2 constants: qp = exp2(min(raw*KA + Cl, LOG2R)) + REPS
#define KA 0.51006971f              // NORMC * log2(e)
#define LOG2R -4.0276408f           // log2(RATIOC)
#define LOG2E 1.4426950408889634f
#define REPS 6.131393e-6f           // RATIOC * EPSK

// ---- ws layout (byte offsets), total ~71.5 MB ----
// ctx slabs (18,350,080 B) overlay xbf+wqb+wkb+wvb, dead after qkv_mfma.
#define PROJP_B 0ul            // 40960
#define KMAX_B  40960ul        // 128
#define KSUMA_B 41088ul        // 40960
#define WO_B    82048ul        // 524288
#define CTXT_B  606336ul       // 1179648
#define DIAGQ_B 1785984ul      // 262144
#define DIAGK_B 2048128ul      // 262144
#define XBF_B   2310272ul      // 16777216
#define WQ_B    19087488ul     // 524288
#define WK_B    19611776ul     // 524288
#define WV_B    20136064ul     // 524288
#define CTXA_B  2310272ul      // == XBF_B, 32*8*280*64*4 = 18350080 (ends at Q_B)
#define Q_B     20660352ul     // 16777216
#define K_B     37437568ul     // 16777216
#define VT_B    54214784ul     // 16777216
#define RMAXQ_B 70992000ul     // 524288 (32*4096 f32) -> end 71,516,288

typedef __bf16 bf16x8 __attribute__((ext_vector_type(8)));
typedef float f32x4 __attribute__((ext_vector_type(4)));
#define MFMA16(a, b, c) __builtin_amdgcn_mfma_f32_16x16x32_bf16((a), (b), (c), 0, 0, 0)

// async global->LDS, 16B per lane; LDS dest = wave-uniform base + lane*16
typedef __attribute__((address_space(1))) const unsigned int* gas_t;
typedef __attribute__((address_space(3))) unsigned int* las_t;
__device__ __forceinline__ void gload16(const void* g, void* l) {
  __builtin_amdgcn_global_load_lds((gas_t)g, (las_t)l, 16, 0, 0);
}

__device__ __forceinline__ float bfu(unsigned short u) {
  union { unsigned int i; float f; } x; x.i = ((unsigned int)u) << 16; return x.f;
}
__device__ __forceinline__ unsigned short f2bf(float f) {
  union { float f; unsigned int i; } u; u.f = f;
  unsigned int r = u.i + 0x7fffu + ((u.i >> 16) & 1u);
  return (unsigned short)(r >> 16);
}
__device__ __forceinline__ void atomicMaxF(float* addr, float val) {
  int* ai = (int*)addr;
  while (true) {
    float cur = __int_as_float(*(volatile int*)ai);
    if (val <= cur) break;
    int old = atomicCAS(ai, __float_as_int(cur), __float_as_int(val));
    if (old == __float_as_int(cur)) break;
  }
}

// ---------------- prep: all fp32->bf16 conversions + proj pad + inits (1 launch) ----------------
__global__ void prep_kernel(const float* __restrict__ x, const float* __restrict__ Wq,
                            const float* __restrict__ Wk, const float* __restrict__ Wv,
                            const float* __restrict__ Wo, const float* __restrict__ proj,
                            unsigned short* __restrict__ xbf, unsigned short* __restrict__ wqb,
                            unsigned short* __restrict__ wkb, unsigned short* __restrict__ wvb,
                            unsigned short* __restrict__ wob,
                            unsigned short* __restrict__ projp,
                            float* __restrict__ kmax, float* __restrict__ ksuma) {
  const int t0 = blockIdx.x * 256 + threadIdx.x;
  const int stride = gridDim.x * 256;
  for (int i = t0; i < 8388608 / 4; i += stride) {
    const float4 v = ((const float4*)x)[i];
    ushort4 u;
    u.x = f2bf(v.x); u.y = f2bf(v.y); u.z = f2bf(v.z); u.w = f2bf(v.w);
    ((ushort4*)xbf)[i] = u;
  }
  const float* wsrc[4] = {Wq, Wk, Wv, Wo};
  unsigned short* wdst[4] = {wqb, wkb, wvb, wob};
#pragma unroll
  for (int w = 0; w < 4; ++w) {
    for (int i = t0; i < 262144 / 4; i += stride) {
      const float4 v = ((const float4*)wsrc[w])[i];
      ushort4 u;
      u.x = f2bf(v.x); u.y = f2bf(v.y); u.z = f2bf(v.z); u.w = f2bf(v.w);
      ((ushort4*)wdst[w])[i] = u;
    }
  }
  for (int j = t0; j < MP3_ * DH_; j += stride)
    projp[j] = (j < M_ * DH_) ? f2bf(proj[j]) : (unsigned short)0;
  for (int j = t0; j < BH_; j += stride) kmax[j] = -3e38f;
  for (int j = t0; j < BH_ * MP3_; j += stride) ksuma[j] = 0.f;
}

// ---------------- QKV projection: 128x128 MFMA GEMM, dbuf global_load_lds (2-phase) ----------------
__global__ __launch_bounds__(256) void qkv_mfma(
    const unsigned short* __restrict__ x, const unsigned short* __restrict__ Wq,
    const unsigned short* __restrict__ Wk, const unsigned short* __restrict__ Wv,
    unsigned short* __restrict__ Q, unsigned short* __restrict__ K,
    unsigned short* __restrict__ VT) {
  __shared__ unsigned short As[2][128 * 64];
  __shared__ unsigned short Bs[2][128 * 64];
  const int z = blockIdx.z;
  const unsigned short* W = (z == 0) ? Wq : (z == 1) ? Wk : Wv;
  const int t0 = blockIdx.x * 128, e0 = blockIdx.y * 128;
  const int tid = threadIdx.x;
  const int wv = tid >> 6, lane = tid & 63;
  const int r = lane & 15, q = lane >> 4;
  const int wr = (wv >> 1) * 64, wc = (wv & 1) * 64;
  f32x4 acc[4][4];
#pragma unroll
  for (int i = 0; i < 4; ++i)
#pragma unroll
    for (int j = 0; j < 4; ++j) acc[i][j] = (f32x4){0.f, 0.f, 0.f, 0.f};
  // staging: wave wv covers rows wv*32 + j*8 + (lane>>3), col (lane&7)*8
  const int lrow = lane >> 3, lcol = (lane & 7) * 8;
#define QKV_STAGE(buf, k0)                                                          \
  {                                                                                 \
    _Pragma("unroll") for (int j = 0; j < 4; ++j) {                                 \
      const int rr = wv * 32 + j * 8;                                               \
      gload16(&x[(size_t)(t0 + rr + lrow) * DIM_ + (k0) + lcol], &As[buf][rr * 64]);\
      gload16(&W[(size_t)(e0 + rr + lrow) * DIM_ + (k0) + lcol], &Bs[buf][rr * 64]);\
    }                                                                               \
  }
#define QKV_COMPUTE(buf)                                                            \
  {                                                                                 \
    _Pragma("unroll") for (int kc = 0; kc < 2; ++kc) {                              \
      bf16x8 af[4], bfr[4];                                                         \
      _Pragma("unroll") for (int rt = 0; rt < 4; ++rt)                              \
        af[rt] = *(const bf16x8*)&As[buf][(wr + rt * 16 + r) * 64 + kc * 32 + q * 8];\
      _Pragma("unroll") for (int ct = 0; ct < 4; ++ct)                              \
        bfr[ct] = *(const bf16x8*)&Bs[buf][(wc + ct * 16 + r) * 64 + kc * 32 + q * 8];\
      _Pragma("unroll") for (int rt = 0; rt < 4; ++rt)                              \
        _Pragma("unroll") for (int ct = 0; ct < 4; ++ct)                            \
          acc[rt][ct] = MFMA16(af[rt], bfr[ct], acc[rt][ct]);                       \
    }                                                                               \
  }
  QKV_STAGE(0, 0);
  __syncthreads();
  int cur = 0;
#pragma unroll
  for (int k0 = 64; k0 < DIM_; k0 += 64) {
    QKV_STAGE(cur ^ 1, k0);   // issue next tile BEFORE computing current
    QKV_COMPUTE(cur);
    __syncthreads();          // waves done reading cur; implicit vmcnt(0) -> next buf ready
    cur ^= 1;
  }
  QKV_COMPUTE(cur);
  if (z < 2) {
    unsigned short* dst = (z == 0) ? Q : K;
#pragma unroll
    for (int rt = 0; rt < 4; ++rt) {
#pragma unroll
      for (int ct = 0; ct < 4; ++ct) {
        const int e = e0 + wc + ct * 16 + r;
#pragma unroll
        for (int i = 0; i < 4; ++i) {
          const int t = t0 + wr + rt * 16 + q * 4 + i;
          dst[(size_t)t * DIM_ + e] = f2bf(acc[rt][ct][i]);
        }
      }
    }
  } else {
#pragma unroll
    for (int rt = 0; rt < 4; ++rt) {
      const int t = t0 + wr + rt * 16 + q * 4;
      const int b_ = t >> 12, n = t & (N_ - 1);
#pragma unroll
      for (int ct = 0; ct < 4; ++ct) {
        const int e = e0 + wc + ct * 16 + r;
        const int h = e >> 6, dh = e & 63;
        ushort4 pk;
        pk.x = f2bf(acc[rt][ct][0]); pk.y = f2bf(acc[rt][ct][1]);
        pk.z = f2bf(acc[rt][ct][2]); pk.w = f2bf(acc[rt][ct][3]);
        *(ushort4*)&VT[((size_t)((b_ * H_ + h) * DH_ + dh)) * N_ + n] = pk;
      }
    }
  }
}

// ---------------- diag: DIAGC * sum(t*t) per (bh, n), stored bf16 ----------------
__global__ void diag_kernel(const unsigned short* __restrict__ Q,
                            const unsigned short* __restrict__ K,
                            unsigned short* __restrict__ dq, unsigned short* __restrict__ dk) {
  const int i = blockIdx.x * 256 + threadIdx.x;
  const int bh = i >> 12, n = i & (N_ - 1);
  const int b_ = bh >> 3, h = bh & 7;
  const unsigned short* src = ((blockIdx.y == 0) ? Q : K) + (size_t)(b_ * N_ + n) * DIM_ + h * DH_;
  float s = 0.f;
#pragma unroll
  for (int c = 0; c < 16; ++c) {
    const ushort4 u = ((const ushort4*)src)[c];
    const float a = bfu(u.x), b2 = bfu(u.y), cc = bfu(u.z), d = bfu(u.w);
    s += a * a + b2 * b2 + cc * cc + d * d;
  }
  ((blockIdx.y == 0) ? dq : dk)[i] = f2bf(s * DIAGC);
}

// ---------------- kmax/qmax (MFMA, merged): K global max + Q per-row max ----------------
__global__ __launch_bounds__(256) void kmax_mfma(
    const unsigned short* __restrict__ K, const unsigned short* __restrict__ Qb,
    const unsigned short* __restrict__ projp,
    float* __restrict__ kmax, float* __restrict__ rmaxq) {
  __shared__ unsigned short sP[MP_][72];
  __shared__ float wm[4];
  const int bh = blockIdx.x, n0 = blockIdx.y * 256;
  const int tid = threadIdx.x;
  const int wv = tid >> 6, lane = tid & 63;
  const int r = lane & 15, q = lane >> 4;
  const int b_ = bh >> 3, h = bh & 7;
  // stage proj rows 0..271 (coalesced 16B chunks)
  for (int c = tid; c < MP_ * 4; c += 256) {
    const int row = c >> 2, cb = (c & 3) * 8;
    *(uint4*)&sP[row][cb] = *(const uint4*)&projp[row * DH_ + cb];
  }
  // load 4 K-strips + 4 Q-strips: rows nbase + st*16 + r
  bf16x8 kb[4][2], qb[4][2];
  const int nbase = n0 + wv * 64;
#pragma unroll
  for (int st = 0; st < 4; ++st) {
    const size_t off = (size_t)(b_ * N_ + nbase + st * 16 + r) * DIM_ + h * DH_;
    kb[st][0] = *(const bf16x8*)(K + off + q * 8);
    kb[st][1] = *(const bf16x8*)(K + off + 32 + q * 8);
    qb[st][0] = *(const bf16x8*)(Qb + off + q * 8);
    qb[st][1] = *(const bf16x8*)(Qb + off + 32 + q * 8);
  }
  __syncthreads();
  float km = -3e38f;
  float qm[4] = {-3e38f, -3e38f, -3e38f, -3e38f};
  for (int mt = 0; mt < 17; ++mt) {
    const bf16x8 p0 = *(const bf16x8*)&sP[mt * 16 + r][q * 8];
    const bf16x8 p1 = *(const bf16x8*)&sP[mt * 16 + r][32 + q * 8];
#pragma unroll
    for (int st = 0; st < 4; ++st) {
      f32x4 ka = (f32x4){0.f, 0.f, 0.f, 0.f};
      ka = MFMA16(p0, kb[st][0], ka);
      ka = MFMA16(p1, kb[st][1], ka);
      f32x4 qa = (f32x4){0.f, 0.f, 0.f, 0.f};
      qa = MFMA16(p0, qb[st][0], qa);
      qa = MFMA16(p1, qb[st][1], qa);
#pragma unroll
      for (int i = 0; i < 4; ++i) {
        const int m = mt * 16 + q * 4 + i;
        if (m < M_) {
          km = fmaxf(km, ka[i]);
          qm[st] = fmaxf(qm[st], qa[i]);
        }
      }
    }
  }
  // Q: per-row raw max -- combine the 4 q-groups (m coverage) per row
#pragma unroll
  for (int st = 0; st < 4; ++st) {
    float v = qm[st];
    v = fmaxf(v, __shfl_xor(v, 16, 64));
    v = fmaxf(v, __shfl_xor(v, 32, 64));
    if (q == 0) rmaxq[bh * N_ + nbase + st * 16 + r] = v;
  }
  // K: block max -> atomic
  for (int s2 = 1; s2 < 64; s2 <<= 1) km = fmaxf(km, __shfl_xor(km, s2, 64));
  if (lane == 0) wm[wv] = km;
  __syncthreads();
  if (tid == 0) {
    const float m = fmaxf(fmaxf(wm[0], wm[1]), fmaxf(wm[2], wm[3])) * NORMC;
    atomicMaxF(&kmax[bh], m);
  }
}

// ---------------- fused: td -> exp -> kp; ctx += kp x VT; ksum ----------------
__global__ __launch_bounds__(256) void ctxfused_mfma(
    const unsigned short* __restrict__ K, const unsigned short* __restrict__ VT,
    const unsigned short* __restrict__ projp, const unsigned short* __restrict__ diag_k,
    const float* __restrict__ kmaxv, float* __restrict__ ksuma,
    float* __restrict__ slab) {
  __shared__ unsigned short kll[64][72];
  __shared__ unsigned short vtl[64][72];
  __shared__ unsigned short kpl[64][72];
  __shared__ float dgl[64];
  const int bh = blockIdx.x, m0 = blockIdx.y * 64, zi = blockIdx.z;
  const int nbase = zi * 512;
  const int tid = threadIdx.x;
  const int wv = tid >> 6, lane = tid & 63;
  const int r = lane & 15, q = lane >> 4;
  const int b_ = bh >> 3, h = bh & 7;
  const float km = kmaxv[bh];
  const unsigned short* prow = projp + (size_t)(m0 + wv * 16 + r) * DH_;
  const bf16x8 p0 = *(const bf16x8*)(prow + q * 8);
  const bf16x8 p1 = *(const bf16x8*)(prow + 32 + q * 8);
  const unsigned short* kbase = K + (size_t)(b_ * N_) * DIM_ + h * DH_;
  const unsigned short* vbase = VT + (size_t)bh * DH_ * N_;
  f32x4 cacc[4];
#pragma unroll
  for (int i = 0; i < 4; ++i) cacc[i] = (f32x4){0.f, 0.f, 0.f, 0.f};
  float ksa[4] = {0.f, 0.f, 0.f, 0.f};
  for (int nc = 0; nc < 8; ++nc) {
    const int n0c = nbase + nc * 64;
#pragma unroll
    for (int j = 0; j < 4; ++j) {
      const int idx = tid + j * 256;
      const int rr = idx >> 4, c4 = (idx & 15) << 2;
      *(ushort4*)&kll[rr][c4] = *(const ushort4*)&kbase[(size_t)(n0c + rr) * DIM_ + c4];
      *(ushort4*)&vtl[rr][c4] = *(const ushort4*)&vbase[(size_t)rr * N_ + n0c + c4];
    }
    if (tid < 16) {
      const ushort4 du = *(const ushort4*)&diag_k[bh * N_ + n0c + tid * 4];
      dgl[tid * 4 + 0] = bfu(du.x); dgl[tid * 4 + 1] = bfu(du.y);
      dgl[tid * 4 + 2] = bfu(du.z); dgl[tid * 4 + 3] = bfu(du.w);
    }
    __syncthreads();
#pragma unroll
    for (int nt = 0; nt < 4; ++nt) {
      const bf16x8 kb0 = *(const bf16x8*)&kll[nt * 16 + r][q * 8];
      const bf16x8 kb1 = *(const bf16x8*)&kll[nt * 16 + r][32 + q * 8];
      f32x4 acc = (f32x4){0.f, 0.f, 0.f, 0.f};
      acc = MFMA16(p0, kb0, acc);
      acc = MFMA16(p1, kb1, acc);
      const float dgk = dgl[nt * 16 + r];
#pragma unroll
      for (int i = 0; i < 4; ++i) {
        const int m = m0 + wv * 16 + q * 4 + i;
        float kp = 0.f;
        if (m < M_) {
          const float arg = fminf(NORMC * acc[i] - dgk - km, 0.f);
          kp = RATIOC * (__expf(arg) + EPSK);
        }
        kpl[wv * 16 + q * 4 + i][nt * 16 + r] = f2bf(kp);
        ksa[i] += kp;
      }
    }
    __syncthreads();
    {
      const bf16x8 a0 = *(const bf16x8*)&kpl[wv * 16 + r][q * 8];
      const bf16x8 a1 = *(const bf16x8*)&kpl[wv * 16 + r][32 + q * 8];
#pragma unroll
      for (int ct = 0; ct < 4; ++ct) {
        const bf16x8 b0 = *(const bf16x8*)&vtl[ct * 16 + r][q * 8];
        const bf16x8 b1 = *(const bf16x8*)&vtl[ct * 16 + r][32 + q * 8];
        cacc[ct] = MFMA16(a0, b0, cacc[ct]);
        cacc[ct] = MFMA16(a1, b1, cacc[ct]);
      }
    }
    __syncthreads();
  }
#pragma unroll
  for (int i = 0; i < 4; ++i)
    for (int s2 = 1; s2 < 16; s2 <<= 1) ksa[i] += __shfl_xor(ksa[i], s2, 64);
  if (r == 0) {
#pragma unroll
    for (int i = 0; i < 4; ++i)
      atomicAdd(&ksuma[bh * MP3_ + m0 + wv * 16 + q * 4 + i], ksa[i]);
  }
  float* sl = slab + (size_t)(bh * NZ_ + zi) * SLABM_ * DH_;
#pragma unroll
  for (int ct = 0; ct < 4; ++ct) {
#pragma unroll
    for (int i = 0; i < 4; ++i) {
      const int m = m0 + wv * 16 + q * 4 + i;
      if (m < SLABM_) sl[(size_t)m * DH_ + ct * 16 + r] = cacc[ct][i];
    }
  }
}

// ---------------- pack: reduce 8 z-slabs [m][d] fp32 -> transpose -> ctxT [d][288] bf16 ----
__global__ __launch_bounds__(256) void pack_kernel(const float* __restrict__ slab,
                                                   unsigned short* __restrict__ ctxT) {
  __shared__ float t[64][65];
  const int bh = blockIdx.x, m0 = blockIdx.y * 64;
  const int tid = threadIdx.x;
  const int mr = tid >> 4, d4 = (tid & 15) * 4;
#pragma unroll
  for (int pass = 0; pass < 4; ++pass) {
    const int ml = pass * 16 + mr;
    const int m = m0 + ml;
    float4 s = {0.f, 0.f, 0.f, 0.f};
    if (m < SLABM_) {
#pragma unroll
      for (int z = 0; z < NZ_; ++z) {
        const float4 v =
            *(const float4*)&slab[((size_t)(bh * NZ_ + z) * SLABM_ + m) * DH_ + d4];
        s.x += v.x; s.y += v.y; s.z += v.z; s.w += v.w;
      }
    }
    t[ml][d4 + 0] = s.x; t[ml][d4 + 1] = s.y; t[ml][d4 + 2] = s.z; t[ml][d4 + 3] = s.w;
  }
  __syncthreads();
  const int mc = tid & 63, dbase = tid >> 6;
  const int mo = m0 + mc;
  if (mo < MP2_) {
#pragma unroll
    for (int j = 0; j < 16; ++j) {
      const int d = dbase + j * 4;
      ctxT[((size_t)bh * DH_ + d) * MP2_ + mo] = f2bf(t[mc][d]);
    }
  }
}

// ---------------- fused QP + out GEMM: LDS-staged proj (time-shared with qp tile) ----------------
__global__ __launch_bounds__(256) void qpout_mfma(
    const unsigned short* __restrict__ Qb, const unsigned short* __restrict__ projp,
    const float* __restrict__ rmaxq,
    const unsigned short* __restrict__ diag_q, const float* __restrict__ ksuma,
    const unsigned short* __restrict__ ctxT, unsigned short* __restrict__ attn) {
  __shared__ union SM {
    unsigned short sP[MP_][72];      // 39168 B  (phase B)
    unsigned int qps[4][16][149];    // 38144 B  (phase C; per-wave tile, stride 149 u32)
  } sm;
  const int bh = blockIdx.x, n0 = blockIdx.y * 64;
  const int tid = threadIdx.x;
  const int wv = tid >> 6, lane = tid & 63;
  const int r = lane & 15, q = lane >> 4;
  const int b_ = bh >> 3, h = bh & 7;
  // stage proj rows 0..271 into sP (coalesced 16B chunks)
  for (int c = tid; c < MP_ * 4; c += 256) {
    const int row = c >> 2, cb = (c & 3) * 8;
    *(uint4*)&sm.sP[row][cb] = *(const uint4*)&projp[row * DH_ + cb];
  }
  bf16x8 qb0, qb1;
  {
    const unsigned short* qrow = Qb + (size_t)(b_ * N_ + n0 + wv * 16 + r) * DIM_ + h * DH_;
    qb0 = *(const bf16x8*)(qrow + q * 8);
    qb1 = *(const bf16x8*)(qrow + 32 + q * 8);
  }
  const float rm = rmaxq[bh * N_ + n0 + wv * 16 + r];
  const float dg = bfu(diag_q[bh * N_ + n0 + wv * 16 + r]);
  const float Cl = LOG2R - dg * LOG2E - rm * KA;
  __syncthreads();
  // phase B: td -> exp+pack -> registers; denominator partial (rounded qp)
  unsigned int pk0[17], pk1[17];
  float part = 0.f;
#pragma unroll
  for (int mt = 0; mt < 17; ++mt) {
    const bf16x8 p0 = *(const bf16x8*)&sm.sP[mt * 16 + r][q * 8];
    const bf16x8 p1 = *(const bf16x8*)&sm.sP[mt * 16 + r][32 + q * 8];
    f32x4 acc = (f32x4){0.f, 0.f, 0.f, 0.f};
    acc = MFMA16(p0, qb0, acc);
    acc = MFMA16(p1, qb1, acc);
    const f32x4 kl = *(const f32x4*)&ksuma[bh * MP3_ + mt * 16 + q * 4];
    {
      const float s0 = fminf(acc[0] * KA + Cl, LOG2R);
      const float s1 = fminf(acc[1] * KA + Cl, LOG2R);
      const float e0 = exp2f(s0) + REPS;
      const float e1 = exp2f(s1) + REPS;
      unsigned int pkk;
      asm("v_cvt_pk_bf16_f32 %0, %1, %2" : "=v"(pkk) : "v"(e0), "v"(e1));
      pk0[mt] = pkk;
      union { unsigned int u; float f; } lo, hi;
      lo.u = pkk << 16; hi.u = pkk & 0xffff0000u;
      part += lo.f * kl[0] + hi.f * kl[1];
    }
    {
      const float s0 = fminf(acc[2] * KA + Cl, LOG2R);
      const float s1 = fminf(acc[3] * KA + Cl, LOG2R);
      const float e0 = exp2f(s0) + REPS;
      const float e1 = exp2f(s1) + REPS;
      unsigned int pkk;
      asm("v_cvt_pk_bf16_f32 %0, %1, %2" : "=v"(pkk) : "v"(e0), "v"(e1));
      pk1[mt] = pkk;
      union { unsigned int u; float f; } lo, hi;
      lo.u = pkk << 16; hi.u = pkk & 0xffff0000u;
      part += lo.f * kl[2] + hi.f * kl[3];
    }
  }
  __syncthreads();  // all waves done reading sP; LDS becomes qps
  // dump packed qp regs -> wave-private qps tile (row r, u32 cols mt*8 + q*2)
#pragma unroll
  for (int mt = 0; mt < 17; ++mt)
    *(uint2*)&sm.qps[wv][r][mt * 8 + q * 2] = make_uint2(pk0[mt], pk1[mt]);
  // zero pad u32 cols 136..143 (bf16 cols 272..287)
  *(uint2*)&sm.qps[wv][r][136 + q * 2] = make_uint2(0u, 0u);
  part += __shfl_xor(part, 16, 64);
  part += __shfl_xor(part, 32, 64);
  const float dinv = 1.f / fmaxf(part, 1e-30f);
  // Phase C: out = qp . ctxT (K = 288); A-frags from wave-private LDS tile
  f32x4 oacc[4];
#pragma unroll
  for (int i = 0; i < 4; ++i) oacc[i] = (f32x4){0.f, 0.f, 0.f, 0.f};
  const unsigned short* cbase = ctxT + (size_t)bh * DH_ * MP2_;
#pragma unroll
  for (int kc = 0; kc < 9; ++kc) {
    const bf16x8 af = *(const bf16x8*)&sm.qps[wv][r][kc * 16 + q * 4];
#pragma unroll
    for (int dt = 0; dt < 4; ++dt) {
      const bf16x8 bfr = *(const bf16x8*)&cbase[(size_t)(dt * 16 + r) * MP2_ + kc * 32 + q * 8];
      oacc[dt] = MFMA16(af, bfr, oacc[dt]);
    }
  }
  // dinv lives at lane with r = n-local; output rows n-local = q*4+i
  float dv[4];
#pragma unroll
  for (int i = 0; i < 4; ++i)
    dv[i] = __shfl(dinv, (lane & 48) | (q * 4 + i), 64);
#pragma unroll
  for (int dt = 0; dt < 4; ++dt) {
    const int d = dt * 16 + r;
#pragma unroll
    for (int i = 0; i < 4; ++i) {
      const int nn = wv * 16 + q * 4 + i;
      attn[(size_t)(b_ * N_ + n0 + nn) * DIM_ + h * DH_ + d] = f2bf(oacc[dt][i] * dv[i]);
    }
  }
}

// ---------------- final: 128x128 MFMA GEMM + residual, dbuf global_load_lds (2-phase) ----------------
__global__ __launch_bounds__(256) void final_mfma(
    const unsigned short* __restrict__ attn, const unsigned short* __restrict__ Wo,
    const float* __restrict__ bo, const float* __restrict__ x,
    float* __restrict__ out) {
  __shared__ unsigned short As[2][128 * 64];
  __shared__ unsigned short Bs[2][128 * 64];
  const int t0 = blockIdx.x * 128, e0 = blockIdx.y * 128;
  const int tid = threadIdx.x;
  const int wv = tid >> 6, lane = tid & 63;
  const int r = lane & 15, q = lane >> 4;
  const int wr = (wv >> 1) * 64, wc = (wv & 1) * 64;
  f32x4 acc[4][4];
#pragma unroll
  for (int i = 0; i < 4; ++i)
#pragma unroll
    for (int j = 0; j < 4; ++j) acc[i][j] = (f32x4){0.f, 0.f, 0.f, 0.f};
  const int lrow = lane >> 3, lcol = (lane & 7) * 8;
#define FIN_STAGE(buf, k0)                                                              \
  {                                                                                     \
    _Pragma("unroll") for (int j = 0; j < 4; ++j) {                                     \
      const int rr = wv * 32 + j * 8;                                                   \
      gload16(&attn[(size_t)(t0 + rr + lrow) * DIM_ + (k0) + lcol], &As[buf][rr * 64]); \
      gload16(&Wo[(size_t)(e0 + rr + lrow) * DIM_ + (k0) + lcol], &Bs[buf][rr * 64]);   \
    }                                                                                   \
  }
#define FIN_COMPUTE(buf)                                                                \
  {                                                                                     \
    _Pragma("unroll") for (int kc = 0; kc < 2; ++kc) {                                  \
      bf16x8 af[4], bfr[4];                                                             \
      _Pragma("unroll") for (int rt = 0; rt < 4; ++rt)                                  \
        af[rt] = *(const bf16x8*)&As[buf][(wr + rt * 16 + r) * 64 + kc * 32 + q * 8];   \
      _Pragma("unroll") for (int ct = 0; ct < 4; ++ct)                                  \
        bfr[ct] = *(const bf16x8*)&Bs[buf][(wc + ct * 16 + r) * 64 + kc * 32 + q * 8];  \
      _Pragma("unroll") for (int rt = 0; rt < 4; ++rt)                                  \
        _Pragma("unroll") for (int ct = 0; ct < 4; ++ct)                                \
          acc[rt][ct] = MFMA16(af[rt], bfr[ct], acc[rt][ct]);                           \
    }                                                                                   \
  }
  FIN_STAGE(0, 0);
  __syncthreads();
  int cur = 0;
#pragma unroll
  for (int k0 = 64; k0 < DIM_; k0 += 64) {
    FIN_STAGE(cur ^ 1, k0);
    FIN_COMPUTE(cur);
    __syncthreads();
    cur ^= 1;
  }
  FIN_COMPUTE(cur);
#pragma unroll
  for (int rt = 0; rt < 4; ++rt) {
#pragma unroll
    for (int ct = 0; ct < 4; ++ct) {
      const int c = e0 + wc + ct * 16 + r;
      const float bov = bo[c];
#pragma unroll
      for (int i = 0; i < 4; ++i) {
        const int t = t0 + wr + rt * 16 + q * 4 + i;
        out[(size_t)t * DIM_ + c] = acc[rt][ct][i] + bov + x[(size_t)t * DIM_ + c];
      }
    }
  }
}

extern "C" void kernel_launch(void* const* d_in, const int* in_sizes, int n_in,
                              void* d_out, int out_size, void* d_ws, size_t ws_size,
                              hipStream_t stream) {
  const float* x = (const float*)d_in[0];
  const float* Wq = (const float*)d_in[1];
  const float* Wk = (const float*)d_in[2];
  const float* Wv = (const float*)d_in[3];
  const float* Wo = (const float*)d_in[4];
  const float* bo = (const float*)d_in[5];
  const float* proj = (const float*)d_in[6];
  char* ws = (char*)d_ws;
  unsigned short* projp = (unsigned short*)(ws + PROJP_B);
  float* kmax = (float*)(ws + KMAX_B);
  float* ksuma = (float*)(ws + KSUMA_B);
  float* ctxa = (float*)(ws + CTXA_B);
  unsigned short* ctxT = (unsigned short*)(ws + CTXT_B);
  unsigned short* diag_q = (unsigned short*)(ws + DIAGQ_B);
  unsigned short* diag_k = (unsigned short*)(ws + DIAGK_B);
  unsigned short* xbf = (unsigned short*)(ws + XBF_B);
  unsigned short* wqb = (unsigned short*)(ws + WQ_B);
  unsigned short* wkb = (unsigned short*)(ws + WK_B);
  unsigned short* wvb = (unsigned short*)(ws + WV_B);
  unsigned short* wob = (unsigned short*)(ws + WO_B);
  unsigned short* Q = (unsigned short*)(ws + Q_B);
  unsigned short* K = (unsigned short*)(ws + K_B);
  unsigned short* VT = (unsigned short*)(ws + VT_B);
  float* rmaxq = (float*)(ws + RMAXQ_B);
  unsigned short* attn = K;  // K dead after ctxfused_mfma
  float* out = (float*)d_out;

  prep_kernel<<<1024, 256, 0, stream>>>(x, Wq, Wk, Wv, Wo, proj,
                                        xbf, wqb, wkb, wvb, wob, projp, kmax, ksuma);
  qkv_mfma<<<dim3(NT_ / 128, DIM_ / 128, 3), 256, 0, stream>>>(xbf, wqb, wkb, wvb, Q, K, VT);
  diag_kernel<<<dim3(512, 2), 256, 0, stream>>>(Q, K, diag_q, diag_k);
  kmax_mfma<<<dim3(BH_, N_ / 256), 256, 0, stream>>>(K, Q, projp, kmax, rmaxq);
  ctxfused_mfma<<<dim3(BH_, 5, NZ_), 256, 0, stream>>>(K, VT, projp, diag_k, kmax, ksuma, ctxa);
  pack_kernel<<<dim3(BH_, 5), 256, 0, stream>>>(ctxa, ctxT);
  qpout_mfma<<<dim3(BH_, 64), 256, 0, stream>>>(Q, projp, rmaxq, diag_q, ksuma, ctxT, attn);
  final_mfma<<<dim3(NT_ / 128, DIM_ / 128), 256, 0, stream>>>(attn, wob, bo, x, out);
}

// Round 10
// 275.300 us; speedup vs baseline: 1.2905x; 1.0322x over previous
//
#include <hip/hip_runtime.h>

#define N_ 4096
#define DIM_ 512
#define H_ 8
#define DH_ 64
#define M_ 266
#define MP_ 272      // ksum/qp live range padded to 272 (17 tiles of 16)
#define MP2_ 288     // out-GEMM K padded to 9 chunks of 32
#define MP3_ 320     // ksuma / projp m padded to 5 chunks of 64
#define SLABM_ 280   // ctx partial-slab m extent (>= M_=266, trimmed to fit overlay)
#define NZ_ 8        // n-split for ctxfused
#define NT_ 16384
#define BH_ 32

#define NORMC 0.3535533905932738f   // 64^-0.25
#define RATIOC 0.06131393394849658f // 266^-0.5
#define EPSK 1e-4f
#define DIAGC 0.0625f               // 0.5 * normalizer^2
// folded exp2 constants: qp = exp2(min(raw*KA + Cl, LOG2R)) + REPS
#define KA 0.51006971f              // NORMC * log2(e)
#define LOG2R -4.0276408f           // log2(RATIOC)
#define LOG2E 1.4426950408889634f
#define REPS 6.131393e-6f           // RATIOC * EPSK

// ---- ws layout (byte offsets), total ~71.5 MB ----
// ctx slabs (18,350,080 B) overlay xbf+wqb+wkb+wvb, dead after qkv_mfma.
#define PROJP_B 0ul            // 40960
#define KMAX_B  40960ul        // 128
#define KSUMA_B 41088ul        // 40960
#define WO_B    82048ul        // 524288
#define CTXT_B  606336ul       // 1179648
#define DIAGQ_B 1785984ul      // 262144
#define DIAGK_B 2048128ul      // 262144
#define XBF_B   2310272ul      // 16777216
#define WQ_B    19087488ul     // 524288
#define WK_B    19611776ul     // 524288
#define WV_B    20136064ul     // 524288
#define CTXA_B  2310272ul      // == XBF_B, 32*8*280*64*4 = 18350080 (ends at Q_B)
#define Q_B     20660352ul     // 16777216
#define K_B     37437568ul     // 16777216
#define VT_B    54214784ul     // 16777216
#define RMAXQ_B 70992000ul     // 524288 (32*4096 f32) -> end 71,516,288

typedef __bf16 bf16x8 __attribute__((ext_vector_type(8)));
typedef float f32x4 __attribute__((ext_vector_type(4)));
#define MFMA16(a, b, c) __builtin_amdgcn_mfma_f32_16x16x32_bf16((a), (b), (c), 0, 0, 0)

// async global->LDS, 16B per lane; LDS dest = wave-uniform base + lane*16
typedef __attribute__((address_space(1))) const unsigned int* gas_t;
typedef __attribute__((address_space(3))) unsigned int* las_t;
__device__ __forceinline__ void gload16(const void* g, void* l) {
  __builtin_amdgcn_global_load_lds((gas_t)g, (las_t)l, 16, 0, 0);
}

__device__ __forceinline__ float bfu(unsigned short u) {
  union { unsigned int i; float f; } x; x.i = ((unsigned int)u) << 16; return x.f;
}
__device__ __forceinline__ unsigned short f2bf(float f) {
  union { float f; unsigned int i; } u; u.f = f;
  unsigned int r = u.i + 0x7fffu + ((u.i >> 16) & 1u);
  return (unsigned short)(r >> 16);
}
__device__ __forceinline__ void atomicMaxF(float* addr, float val) {
  int* ai = (int*)addr;
  while (true) {
    float cur = __int_as_float(*(volatile int*)ai);
    if (val <= cur) break;
    int old = atomicCAS(ai, __float_as_int(cur), __float_as_int(val));
    if (old == __float_as_int(cur)) break;
  }
}

// ---------------- prep: all fp32->bf16 conversions + proj pad + inits (1 launch) ----------------
__global__ void prep_kernel(const float* __restrict__ x, const float* __restrict__ Wq,
                            const float* __restrict__ Wk, const float* __restrict__ Wv,
                            const float* __restrict__ Wo, const float* __restrict__ proj,
                            unsigned short* __restrict__ xbf, unsigned short* __restrict__ wqb,
                            unsigned short* __restrict__ wkb, unsigned short* __restrict__ wvb,
                            unsigned short* __restrict__ wob,
                            unsigned short* __restrict__ projp,
                            float* __restrict__ kmax, float* __restrict__ ksuma) {
  const int t0 = blockIdx.x * 256 + threadIdx.x;
  const int stride = gridDim.x * 256;
  for (int i = t0; i < 8388608 / 4; i += stride) {
    const float4 v = ((const float4*)x)[i];
    ushort4 u;
    u.x = f2bf(v.x); u.y = f2bf(v.y); u.z = f2bf(v.z); u.w = f2bf(v.w);
    ((ushort4*)xbf)[i] = u;
  }
  const float* wsrc[4] = {Wq, Wk, Wv, Wo};
  unsigned short* wdst[4] = {wqb, wkb, wvb, wob};
#pragma unroll
  for (int w = 0; w < 4; ++w) {
    for (int i = t0; i < 262144 / 4; i += stride) {
      const float4 v = ((const float4*)wsrc[w])[i];
      ushort4 u;
      u.x = f2bf(v.x); u.y = f2bf(v.y); u.z = f2bf(v.z); u.w = f2bf(v.w);
      ((ushort4*)wdst[w])[i] = u;
    }
  }
  for (int j = t0; j < MP3_ * DH_; j += stride)
    projp[j] = (j < M_ * DH_) ? f2bf(proj[j]) : (unsigned short)0;
  for (int j = t0; j < BH_; j += stride) kmax[j] = -3e38f;
  for (int j = t0; j < BH_ * MP3_; j += stride) ksuma[j] = 0.f;
}

// ---------------- QKV projection: 128x128 MFMA GEMM, global_load_lds staging ----------------
// Single-buffer staging (r7 structure: 4 blocks/CU beats dbuf's 2). Q/K epilogue
// routed through the dead LDS tile -> coalesced uint4 stores (was 64 scattered 2B).
__global__ __launch_bounds__(256) void qkv_mfma(
    const unsigned short* __restrict__ x, const unsigned short* __restrict__ Wq,
    const unsigned short* __restrict__ Wk, const unsigned short* __restrict__ Wv,
    unsigned short* __restrict__ Q, unsigned short* __restrict__ K,
    unsigned short* __restrict__ VT) {
  __shared__ __align__(16) unsigned short S[128 * 136];  // staging: As=S[0..8191], Bs=S[8192..16383]; epilogue: T[128][136]
  unsigned short* As = S;
  unsigned short* Bs = S + 8192;
  const int z = blockIdx.z;
  const unsigned short* W = (z == 0) ? Wq : (z == 1) ? Wk : Wv;
  const int t0 = blockIdx.x * 128, e0 = blockIdx.y * 128;
  const int tid = threadIdx.x;
  const int wv = tid >> 6, lane = tid & 63;
  const int r = lane & 15, q = lane >> 4;
  const int wr = (wv >> 1) * 64, wc = (wv & 1) * 64;
  f32x4 acc[4][4];
#pragma unroll
  for (int i = 0; i < 4; ++i)
#pragma unroll
    for (int j = 0; j < 4; ++j) acc[i][j] = (f32x4){0.f, 0.f, 0.f, 0.f};
  // staging: wave wv covers rows wv*32 + j*8 + (lane>>3), col (lane&7)*8
  const int lrow = lane >> 3, lcol = (lane & 7) * 8;
  for (int k0 = 0; k0 < DIM_; k0 += 64) {
#pragma unroll
    for (int j = 0; j < 4; ++j) {
      const int rr = wv * 32 + j * 8;
      gload16(&x[(size_t)(t0 + rr + lrow) * DIM_ + k0 + lcol], &As[rr * 64]);
      gload16(&W[(size_t)(e0 + rr + lrow) * DIM_ + k0 + lcol], &Bs[rr * 64]);
    }
    __syncthreads();
#pragma unroll
    for (int kc = 0; kc < 2; ++kc) {
      bf16x8 af[4], bfr[4];
#pragma unroll
      for (int rt = 0; rt < 4; ++rt)
        af[rt] = *(const bf16x8*)&As[(wr + rt * 16 + r) * 64 + kc * 32 + q * 8];
#pragma unroll
      for (int ct = 0; ct < 4; ++ct)
        bfr[ct] = *(const bf16x8*)&Bs[(wc + ct * 16 + r) * 64 + kc * 32 + q * 8];
#pragma unroll
      for (int rt = 0; rt < 4; ++rt)
#pragma unroll
        for (int ct = 0; ct < 4; ++ct)
          acc[rt][ct] = MFMA16(af[rt], bfr[ct], acc[rt][ct]);
    }
    __syncthreads();
  }
  if (z < 2) {
    unsigned short* dst = (z == 0) ? Q : K;
    // transpose via LDS: T[t_local][e_local], row stride 136 (272B, 16B-aligned rows)
#pragma unroll
    for (int rt = 0; rt < 4; ++rt)
#pragma unroll
      for (int ct = 0; ct < 4; ++ct)
#pragma unroll
        for (int i = 0; i < 4; ++i)
          S[(wr + rt * 16 + q * 4 + i) * 136 + wc + ct * 16 + r] = f2bf(acc[rt][ct][i]);
    __syncthreads();
    const int row = tid >> 1, cb = (tid & 1) * 64;
#pragma unroll
    for (int j = 0; j < 8; ++j)
      *(uint4*)&dst[(size_t)(t0 + row) * DIM_ + e0 + cb + j * 8] =
          *(const uint4*)&S[row * 136 + cb + j * 8];
  } else {
#pragma unroll
    for (int rt = 0; rt < 4; ++rt) {
      const int t = t0 + wr + rt * 16 + q * 4;
      const int b_ = t >> 12, n = t & (N_ - 1);
#pragma unroll
      for (int ct = 0; ct < 4; ++ct) {
        const int e = e0 + wc + ct * 16 + r;
        const int h = e >> 6, dh = e & 63;
        ushort4 pk;
        pk.x = f2bf(acc[rt][ct][0]); pk.y = f2bf(acc[rt][ct][1]);
        pk.z = f2bf(acc[rt][ct][2]); pk.w = f2bf(acc[rt][ct][3]);
        *(ushort4*)&VT[((size_t)((b_ * H_ + h) * DH_ + dh)) * N_ + n] = pk;
      }
    }
  }
}

// ---------------- kmax/qmax (MFMA, merged) + diag: K global max, Q per-row max, diag_q/k ----------------
__global__ __launch_bounds__(256) void kmax_mfma(
    const unsigned short* __restrict__ K, const unsigned short* __restrict__ Qb,
    const unsigned short* __restrict__ projp,
    float* __restrict__ kmax, float* __restrict__ rmaxq,
    unsigned short* __restrict__ dq, unsigned short* __restrict__ dk) {
  __shared__ unsigned short sP[MP_][72];
  __shared__ float wm[4];
  const int bh = blockIdx.x, n0 = blockIdx.y * 256;
  const int tid = threadIdx.x;
  const int wv = tid >> 6, lane = tid & 63;
  const int r = lane & 15, q = lane >> 4;
  const int b_ = bh >> 3, h = bh & 7;
  // stage proj rows 0..271 (coalesced 16B chunks)
  for (int c = tid; c < MP_ * 4; c += 256) {
    const int row = c >> 2, cb = (c & 3) * 8;
    *(uint4*)&sP[row][cb] = *(const uint4*)&projp[row * DH_ + cb];
  }
  // load 4 K-strips + 4 Q-strips: rows nbase + st*16 + r
  bf16x8 kb[4][2], qb[4][2];
  const int nbase = n0 + wv * 64;
#pragma unroll
  for (int st = 0; st < 4; ++st) {
    const size_t off = (size_t)(b_ * N_ + nbase + st * 16 + r) * DIM_ + h * DH_;
    kb[st][0] = *(const bf16x8*)(K + off + q * 8);
    kb[st][1] = *(const bf16x8*)(K + off + 32 + q * 8);
    qb[st][0] = *(const bf16x8*)(Qb + off + q * 8);
    qb[st][1] = *(const bf16x8*)(Qb + off + 32 + q * 8);
  }
  // diag (merged): each lane holds 16 of the row's 64 values; q-butterfly completes the sum
#pragma unroll
  for (int st = 0; st < 4; ++st) {
    float sk = 0.f, sq = 0.f;
#pragma unroll
    for (int p = 0; p < 2; ++p)
#pragma unroll
      for (int e = 0; e < 8; ++e) {
        const float kv = (float)kb[st][p][e];
        const float qv = (float)qb[st][p][e];
        sk += kv * kv;
        sq += qv * qv;
      }
    sk += __shfl_xor(sk, 16, 64); sk += __shfl_xor(sk, 32, 64);
    sq += __shfl_xor(sq, 16, 64); sq += __shfl_xor(sq, 32, 64);
    if (q == 0) {
      dk[bh * N_ + nbase + st * 16 + r] = f2bf(sk * DIAGC);
      dq[bh * N_ + nbase + st * 16 + r] = f2bf(sq * DIAGC);
    }
  }
  __syncthreads();
  float km = -3e38f;
  float qm[4] = {-3e38f, -3e38f, -3e38f, -3e38f};
  for (int mt = 0; mt < 17; ++mt) {
    const bf16x8 p0 = *(const bf16x8*)&sP[mt * 16 + r][q * 8];
    const bf16x8 p1 = *(const bf16x8*)&sP[mt * 16 + r][32 + q * 8];
#pragma unroll
    for (int st = 0; st < 4; ++st) {
      f32x4 ka = (f32x4){0.f, 0.f, 0.f, 0.f};
      ka = MFMA16(p0, kb[st][0], ka);
      ka = MFMA16(p1, kb[st][1], ka);
      f32x4 qa = (f32x4){0.f, 0.f, 0.f, 0.f};
      qa = MFMA16(p0, qb[st][0], qa);
      qa = MFMA16(p1, qb[st][1], qa);
#pragma unroll
      for (int i = 0; i < 4; ++i) {
        const int m = mt * 16 + q * 4 + i;
        if (m < M_) {
          km = fmaxf(km, ka[i]);
          qm[st] = fmaxf(qm[st], qa[i]);
        }
      }
    }
  }
  // Q: per-row raw max -- combine the 4 q-groups (m coverage) per row
#pragma unroll
  for (int st = 0; st < 4; ++st) {
    float v = qm[st];
    v = fmaxf(v, __shfl_xor(v, 16, 64));
    v = fmaxf(v, __shfl_xor(v, 32, 64));
    if (q == 0) rmaxq[bh * N_ + nbase + st * 16 + r] = v;
  }
  // K: block max -> atomic
  for (int s2 = 1; s2 < 64; s2 <<= 1) km = fmaxf(km, __shfl_xor(km, s2, 64));
  if (lane == 0) wm[wv] = km;
  __syncthreads();
  if (tid == 0) {
    const float m = fmaxf(fmaxf(wm[0], wm[1]), fmaxf(wm[2], wm[3])) * NORMC;
    atomicMaxF(&kmax[bh], m);
  }
}

// ---------------- fused: td -> exp -> kp; ctx += kp x VT; ksum ----------------
__global__ __launch_bounds__(256) void ctxfused_mfma(
    const unsigned short* __restrict__ K, const unsigned short* __restrict__ VT,
    const unsigned short* __restrict__ projp, const unsigned short* __restrict__ diag_k,
    const float* __restrict__ kmaxv, float* __restrict__ ksuma,
    float* __restrict__ slab) {
  __shared__ unsigned short kll[64][72];
  __shared__ unsigned short vtl[64][72];
  __shared__ unsigned short kpl[64][72];
  __shared__ float dgl[64];
  const int bh = blockIdx.x, m0 = blockIdx.y * 64, zi = blockIdx.z;
  const int nbase = zi * 512;
  const int tid = threadIdx.x;
  const int wv = tid >> 6, lane = tid & 63;
  const int r = lane & 15, q = lane >> 4;
  const int b_ = bh >> 3, h = bh & 7;
  const float km = kmaxv[bh];
  const unsigned short* prow = projp + (size_t)(m0 + wv * 16 + r) * DH_;
  const bf16x8 p0 = *(const bf16x8*)(prow + q * 8);
  const bf16x8 p1 = *(const bf16x8*)(prow + 32 + q * 8);
  const unsigned short* kbase = K + (size_t)(b_ * N_) * DIM_ + h * DH_;
  const unsigned short* vbase = VT + (size_t)bh * DH_ * N_;
  f32x4 cacc[4];
#pragma unroll
  for (int i = 0; i < 4; ++i) cacc[i] = (f32x4){0.f, 0.f, 0.f, 0.f};
  float ksa[4] = {0.f, 0.f, 0.f, 0.f};
  for (int nc = 0; nc < 8; ++nc) {
    const int n0c = nbase + nc * 64;
#pragma unroll
    for (int j = 0; j < 4; ++j) {
      const int idx = tid + j * 256;
      const int rr = idx >> 4, c4 = (idx & 15) << 2;
      *(ushort4*)&kll[rr][c4] = *(const ushort4*)&kbase[(size_t)(n0c + rr) * DIM_ + c4];
      *(ushort4*)&vtl[rr][c4] = *(const ushort4*)&vbase[(size_t)rr * N_ + n0c + c4];
    }
    if (tid < 16) {
      const ushort4 du = *(const ushort4*)&diag_k[bh * N_ + n0c + tid * 4];
      dgl[tid * 4 + 0] = bfu(du.x); dgl[tid * 4 + 1] = bfu(du.y);
      dgl[tid * 4 + 2] = bfu(du.z); dgl[tid * 4 + 3] = bfu(du.w);
    }
    __syncthreads();
#pragma unroll
    for (int nt = 0; nt < 4; ++nt) {
      const bf16x8 kb0 = *(const bf16x8*)&kll[nt * 16 + r][q * 8];
      const bf16x8 kb1 = *(const bf16x8*)&kll[nt * 16 + r][32 + q * 8];
      f32x4 acc = (f32x4){0.f, 0.f, 0.f, 0.f};
      acc = MFMA16(p0, kb0, acc);
      acc = MFMA16(p1, kb1, acc);
      const float dgk = dgl[nt * 16 + r];
#pragma unroll
      for (int i = 0; i < 4; ++i) {
        const int m = m0 + wv * 16 + q * 4 + i;
        float kp = 0.f;
        if (m < M_) {
          const float arg = fminf(NORMC * acc[i] - dgk - km, 0.f);
          kp = RATIOC * (__expf(arg) + EPSK);
        }
        kpl[wv * 16 + q * 4 + i][nt * 16 + r] = f2bf(kp);
        ksa[i] += kp;
      }
    }
    __syncthreads();
    {
      const bf16x8 a0 = *(const bf16x8*)&kpl[wv * 16 + r][q * 8];
      const bf16x8 a1 = *(const bf16x8*)&kpl[wv * 16 + r][32 + q * 8];
#pragma unroll
      for (int ct = 0; ct < 4; ++ct) {
        const bf16x8 b0 = *(const bf16x8*)&vtl[ct * 16 + r][q * 8];
        const bf16x8 b1 = *(const bf16x8*)&vtl[ct * 16 + r][32 + q * 8];
        cacc[ct] = MFMA16(a0, b0, cacc[ct]);
        cacc[ct] = MFMA16(a1, b1, cacc[ct]);
      }
    }
    __syncthreads();
  }
#pragma unroll
  for (int i = 0; i < 4; ++i)
    for (int s2 = 1; s2 < 16; s2 <<= 1) ksa[i] += __shfl_xor(ksa[i], s2, 64);
  if (r == 0) {
#pragma unroll
    for (int i = 0; i < 4; ++i)
      atomicAdd(&ksuma[bh * MP3_ + m0 + wv * 16 + q * 4 + i], ksa[i]);
  }
  float* sl = slab + (size_t)(bh * NZ_ + zi) * SLABM_ * DH_;
#pragma unroll
  for (int ct = 0; ct < 4; ++ct) {
#pragma unroll
    for (int i = 0; i < 4; ++i) {
      const int m = m0 + wv * 16 + q * 4 + i;
      if (m < SLABM_) sl[(size_t)m * DH_ + ct * 16 + r] = cacc[ct][i];
    }
  }
}

// ---------------- pack: reduce 8 z-slabs [m][d] fp32 -> transpose -> ctxT [d][288] bf16 ----
__global__ __launch_bounds__(256) void pack_kernel(const float* __restrict__ slab,
                                                   unsigned short* __restrict__ ctxT) {
  __shared__ float t[64][65];
  const int bh = blockIdx.x, m0 = blockIdx.y * 64;
  const int tid = threadIdx.x;
  const int mr = tid >> 4, d4 = (tid & 15) * 4;
#pragma unroll
  for (int pass = 0; pass < 4; ++pass) {
    const int ml = pass * 16 + mr;
    const int m = m0 + ml;
    float4 s = {0.f, 0.f, 0.f, 0.f};
    if (m < SLABM_) {
#pragma unroll
      for (int z = 0; z < NZ_; ++z) {
        const float4 v =
            *(const float4*)&slab[((size_t)(bh * NZ_ + z) * SLABM_ + m) * DH_ + d4];
        s.x += v.x; s.y += v.y; s.z += v.z; s.w += v.w;
      }
    }
    t[ml][d4 + 0] = s.x; t[ml][d4 + 1] = s.y; t[ml][d4 + 2] = s.z; t[ml][d4 + 3] = s.w;
  }
  __syncthreads();
  const int mc = tid & 63, dbase = tid >> 6;
  const int mo = m0 + mc;
  if (mo < MP2_) {
#pragma unroll
    for (int j = 0; j < 16; ++j) {
      const int d = dbase + j * 4;
      ctxT[((size_t)bh * DH_ + d) * MP2_ + mo] = f2bf(t[mc][d]);
    }
  }
}

// ---------------- fused QP + out GEMM: LDS-staged proj (time-shared with qp tile) ----------------
__global__ __launch_bounds__(256) void qpout_mfma(
    const unsigned short* __restrict__ Qb, const unsigned short* __restrict__ projp,
    const float* __restrict__ rmaxq,
    const unsigned short* __restrict__ diag_q, const float* __restrict__ ksuma,
    const unsigned short* __restrict__ ctxT, unsigned short* __restrict__ attn) {
  __shared__ union SM {
    unsigned short sP[MP_][72];      // 39168 B  (phase B)
    unsigned int qps[4][16][149];    // 38144 B  (phase C; per-wave tile, stride 149 u32)
  } sm;
  const int bh = blockIdx.x, n0 = blockIdx.y * 64;
  const int tid = threadIdx.x;
  const int wv = tid >> 6, lane = tid & 63;
  const int r = lane & 15, q = lane >> 4;
  const int b_ = bh >> 3, h = bh & 7;
  // stage proj rows 0..271 into sP (coalesced 16B chunks)
  for (int c = tid; c < MP_ * 4; c += 256) {
    const int row = c >> 2, cb = (c & 3) * 8;
    *(uint4*)&sm.sP[row][cb] = *(const uint4*)&projp[row * DH_ + cb];
  }
  bf16x8 qb0, qb1;
  {
    const unsigned short* qrow = Qb + (size_t)(b_ * N_ + n0 + wv * 16 + r) * DIM_ + h * DH_;
    qb0 = *(const bf16x8*)(qrow + q * 8);
    qb1 = *(const bf16x8*)(qrow + 32 + q * 8);
  }
  const float rm = rmaxq[bh * N_ + n0 + wv * 16 + r];
  const float dg = bfu(diag_q[bh * N_ + n0 + wv * 16 + r]);
  const float Cl = LOG2R - dg * LOG2E - rm * KA;
  __syncthreads();
  // phase B: td -> exp+pack -> registers; denominator partial (rounded qp)
  unsigned int pk0[17], pk1[17];
  float part = 0.f;
#pragma unroll
  for (int mt = 0; mt < 17; ++mt) {
    const bf16x8 p0 = *(const bf16x8*)&sm.sP[mt * 16 + r][q * 8];
    const bf16x8 p1 = *(const bf16x8*)&sm.sP[mt * 16 + r][32 + q * 8];
    f32x4 acc = (f32x4){0.f, 0.f, 0.f, 0.f};
    acc = MFMA16(p0, qb0, acc);
    acc = MFMA16(p1, qb1, acc);
    const f32x4 kl = *(const f32x4*)&ksuma[bh * MP3_ + mt * 16 + q * 4];
    {
      const float s0 = fminf(acc[0] * KA + Cl, LOG2R);
      const float s1 = fminf(acc[1] * KA + Cl, LOG2R);
      const float e0 = exp2f(s0) + REPS;
      const float e1 = exp2f(s1) + REPS;
      unsigned int pkk;
      asm("v_cvt_pk_bf16_f32 %0, %1, %2" : "=v"(pkk) : "v"(e0), "v"(e1));
      pk0[mt] = pkk;
      union { unsigned int u; float f; } lo, hi;
      lo.u = pkk << 16; hi.u = pkk & 0xffff0000u;
      part += lo.f * kl[0] + hi.f * kl[1];
    }
    {
      const float s0 = fminf(acc[2] * KA + Cl, LOG2R);
      const float s1 = fminf(acc[3] * KA + Cl, LOG2R);
      const float e0 = exp2f(s0) + REPS;
      const float e1 = exp2f(s1) + REPS;
      unsigned int pkk;
      asm("v_cvt_pk_bf16_f32 %0, %1, %2" : "=v"(pkk) : "v"(e0), "v"(e1));
      pk1[mt] = pkk;
      union { unsigned int u; float f; } lo, hi;
      lo.u = pkk << 16; hi.u = pkk & 0xffff0000u;
      part += lo.f * kl[2] + hi.f * kl[3];
    }
  }
  __syncthreads();  // all waves done reading sP; LDS becomes qps
  // dump packed qp regs -> wave-private qps tile (row r, u32 cols mt*8 + q*2)
#pragma unroll
  for (int mt = 0; mt < 17; ++mt)
    *(uint2*)&sm.qps[wv][r][mt * 8 + q * 2] = make_uint2(pk0[mt], pk1[mt]);
  // zero pad u32 cols 136..143 (bf16 cols 272..287)
  *(uint2*)&sm.qps[wv][r][136 + q * 2] = make_uint2(0u, 0u);
  part += __shfl_xor(part, 16, 64);
  part += __shfl_xor(part, 32, 64);
  const float dinv = 1.f / fmaxf(part, 1e-30f);
  // Phase C: out = qp . ctxT (K = 288); A-frags from wave-private LDS tile
  f32x4 oacc[4];
#pragma unroll
  for (int i = 0; i < 4; ++i) oacc[i] = (f32x4){0.f, 0.f, 0.f, 0.f};
  const unsigned short* cbase = ctxT + (size_t)bh * DH_ * MP2_;
#pragma unroll
  for (int kc = 0; kc < 9; ++kc) {
    const bf16x8 af = *(const bf16x8*)&sm.qps[wv][r][kc * 16 + q * 4];
#pragma unroll
    for (int dt = 0; dt < 4; ++dt) {
      const bf16x8 bfr = *(const bf16x8*)&cbase[(size_t)(dt * 16 + r) * MP2_ + kc * 32 + q * 8];
      oacc[dt] = MFMA16(af, bfr, oacc[dt]);
    }
  }
  // dinv lives at lane with r = n-local; output rows n-local = q*4+i
  float dv[4];
#pragma unroll
  for (int i = 0; i < 4; ++i)
    dv[i] = __shfl(dinv, (lane & 48) | (q * 4 + i), 64);
#pragma unroll
  for (int dt = 0; dt < 4; ++dt) {
    const int d = dt * 16 + r;
#pragma unroll
    for (int i = 0; i < 4; ++i) {
      const int nn = wv * 16 + q * 4 + i;
      attn[(size_t)(b_ * N_ + n0 + nn) * DIM_ + h * DH_ + d] = f2bf(oacc[dt][i] * dv[i]);
    }
  }
}

// ---------------- final: 128x128 MFMA GEMM + residual, global_load_lds staging ----------------
__global__ __launch_bounds__(256) void final_mfma(
    const unsigned short* __restrict__ attn, const unsigned short* __restrict__ Wo,
    const float* __restrict__ bo, const float* __restrict__ x,
    float* __restrict__ out) {
  __shared__ unsigned short As[128 * 64];
  __shared__ unsigned short Bs[128 * 64];
  const int t0 = blockIdx.x * 128, e0 = blockIdx.y * 128;
  const int tid = threadIdx.x;
  const int wv = tid >> 6, lane = tid & 63;
  const int r = lane & 15, q = lane >> 4;
  const int wr = (wv >> 1) * 64, wc = (wv & 1) * 64;
  f32x4 acc[4][4];
#pragma unroll
  for (int i = 0; i < 4; ++i)
#pragma unroll
    for (int j = 0; j < 4; ++j) acc[i][j] = (f32x4){0.f, 0.f, 0.f, 0.f};
  const int lrow = lane >> 3, lcol = (lane & 7) * 8;
  for (int k0 = 0; k0 < DIM_; k0 += 64) {
#pragma unroll
    for (int j = 0; j < 4; ++j) {
      const int rr = wv * 32 + j * 8;
      gload16(&attn[(size_t)(t0 + rr + lrow) * DIM_ + k0 + lcol], &As[rr * 64]);
      gload16(&Wo[(size_t)(e0 + rr + lrow) * DIM_ + k0 + lcol], &Bs[rr * 64]);
    }
    __syncthreads();
#pragma unroll
    for (int kc = 0; kc < 2; ++kc) {
      bf16x8 af[4], bfr[4];
#pragma unroll
      for (int rt = 0; rt < 4; ++rt)
        af[rt] = *(const bf16x8*)&As[(wr + rt * 16 + r) * 64 + kc * 32 + q * 8];
#pragma unroll
      for (int ct = 0; ct < 4; ++ct)
        bfr[ct] = *(const bf16x8*)&Bs[(wc + ct * 16 + r) * 64 + kc * 32 + q * 8];
#pragma unroll
      for (int rt = 0; rt < 4; ++rt)
#pragma unroll
        for (int ct = 0; ct < 4; ++ct)
          acc[rt][ct] = MFMA16(af[rt], bfr[ct], acc[rt][ct]);
    }
    __syncthreads();
  }
#pragma unroll
  for (int rt = 0; rt < 4; ++rt) {
#pragma unroll
    for (int ct = 0; ct < 4; ++ct) {
      const int c = e0 + wc + ct * 16 + r;
      const float bov = bo[c];
#pragma unroll
      for (int i = 0; i < 4; ++i) {
        const int t = t0 + wr + rt * 16 + q * 4 + i;
        out[(size_t)t * DIM_ + c] = acc[rt][ct][i] + bov + x[(size_t)t * DIM_ + c];
      }
    }
  }
}

extern "C" void kernel_launch(void* const* d_in, const int* in_sizes, int n_in,
                              void* d_out, int out_size, void* d_ws, size_t ws_size,
                              hipStream_t stream) {
  const float* x = (const float*)d_in[0];
  const float* Wq = (const float*)d_in[1];
  const float* Wk = (const float*)d_in[2];
  const float* Wv = (const float*)d_in[3];
  const float* Wo = (const float*)d_in[4];
  const float* bo = (const float*)d_in[5];
  const float* proj = (const float*)d_in[6];
  char* ws = (char*)d_ws;
  unsigned short* projp = (unsigned short*)(ws + PROJP_B);
  float* kmax = (float*)(ws + KMAX_B);
  float* ksuma = (float*)(ws + KSUMA_B);
  float* ctxa = (float*)(ws + CTXA_B);
  unsigned short* ctxT = (unsigned short*)(ws + CTXT_B);
  unsigned short* diag_q = (unsigned short*)(ws + DIAGQ_B);
  unsigned short* diag_k = (unsigned short*)(ws + DIAGK_B);
  unsigned short* xbf = (unsigned short*)(ws + XBF_B);
  unsigned short* wqb = (unsigned short*)(ws + WQ_B);
  unsigned short* wkb = (unsigned short*)(ws + WK_B);
  unsigned short* wvb = (unsigned short*)(ws + WV_B);
  unsigned short* wob = (unsigned short*)(ws + WO_B);
  unsigned short* Q = (unsigned short*)(ws + Q_B);
  unsigned short* K = (unsigned short*)(ws + K_B);
  unsigned short* VT = (unsigned short*)(ws + VT_B);
  float* rmaxq = (float*)(ws + RMAXQ_B);
  unsigned short* attn = K;  // K dead after ctxfused_mfma
  float* out = (float*)d_out;

  prep_kernel<<<1024, 256, 0, stream>>>(x, Wq, Wk, Wv, Wo, proj,
                                        xbf, wqb, wkb, wvb, wob, projp, kmax, ksuma);
  qkv_mfma<<<dim3(NT_ / 128, DIM_ / 128, 3), 256, 0, stream>>>(xbf, wqb, wkb, wvb, Q, K, VT);
  kmax_mfma<<<dim3(BH_, N_ / 256), 256, 0, stream>>>(K, Q, projp, kmax, rmaxq, diag_q, diag_k);
  ctxfused_mfma<<<dim3(BH_, 5, NZ_), 256, 0, stream>>>(K, VT, projp, diag_k, kmax, ksuma, ctxa);
  pack_kernel<<<dim3(BH_, 5), 256, 0, stream>>>(ctxa, ctxT);
  qpout_mfma<<<dim3(BH_, 64), 256, 0, stream>>>(Q, projp, rmaxq, diag_q, ksuma, ctxT, attn);
  final_mfma<<<dim3(NT_ / 128, DIM_ / 128), 256, 0, stream>>>(attn, wob, bo, x, out);
}

// Round 11
// 269.770 us; speedup vs baseline: 1.3170x; 1.0205x over previous
//
#include <hip/hip_runtime.h>

#define N_ 4096
#define DIM_ 512
#define H_ 8
#define DH_ 64
#define M_ 266
#define MP_ 272      // ksum/qp live range padded to 272 (17 tiles of 16)
#define MP2_ 288     // out-GEMM K padded to 9 chunks of 32
#define MP3_ 320     // ksuma / projp m padded to 5 chunks of 64
#define SLABM_ 280   // ctx partial-slab m extent (>= M_=266, trimmed to fit overlay)
#define NZ_ 8        // n-split for ctxfused
#define NT_ 16384
#define BH_ 32

#define NORMC 0.3535533905932738f   // 64^-0.25
#define RATIOC 0.06131393394849658f // 266^-0.5
#define EPSK 1e-4f
#define DIAGC 0.0625f               // 0.5 * normalizer^2
// folded exp2 constants: qp = exp2(min(raw*KA + Cl, LOG2R)) + REPS
#define KA 0.51006971f              // NORMC * log2(e)
#define LOG2R -4.0276408f           // log2(RATIOC)
#define LOG2E 1.4426950408889634f
#define REPS 6.131393e-6f           // RATIOC * EPSK

// ---- ws layout (byte offsets), total ~71.5 MB ----
// ctx slabs (18,350,080 B) overlay xbf+wqb+wkb+wvb, dead after qkv_mfma.
#define PROJP_B 0ul            // 40960
#define KMAX_B  40960ul        // 128
#define KSUMA_B 41088ul        // 40960
#define WO_B    82048ul        // 524288
#define CTXT_B  606336ul       // 1179648
#define DIAGQ_B 1785984ul      // 262144
#define DIAGK_B 2048128ul      // 262144
#define XBF_B   2310272ul      // 16777216
#define WQ_B    19087488ul     // 524288
#define WK_B    19611776ul     // 524288
#define WV_B    20136064ul     // 524288
#define CTXA_B  2310272ul      // == XBF_B, 32*8*280*64*4 = 18350080 (ends at Q_B)
#define Q_B     20660352ul     // 16777216
#define K_B     37437568ul     // 16777216
#define VT_B    54214784ul     // 16777216
#define RMAXQ_B 70992000ul     // 524288 (32*4096 f32) -> end 71,516,288

typedef __bf16 bf16x8 __attribute__((ext_vector_type(8)));
typedef float f32x4 __attribute__((ext_vector_type(4)));
#define MFMA16(a, b, c) __builtin_amdgcn_mfma_f32_16x16x32_bf16((a), (b), (c), 0, 0, 0)

// async global->LDS, 16B per lane; LDS dest = wave-uniform base + lane*16
typedef __attribute__((address_space(1))) const unsigned int* gas_t;
typedef __attribute__((address_space(3))) unsigned int* las_t;
__device__ __forceinline__ void gload16(const void* g, void* l) {
  __builtin_amdgcn_global_load_lds((gas_t)g, (las_t)l, 16, 0, 0);
}

__device__ __forceinline__ float bfu(unsigned short u) {
  union { unsigned int i; float f; } x; x.i = ((unsigned int)u) << 16; return x.f;
}
__device__ __forceinline__ unsigned short f2bf(float f) {
  union { float f; unsigned int i; } u; u.f = f;
  unsigned int r = u.i + 0x7fffu + ((u.i >> 16) & 1u);
  return (unsigned short)(r >> 16);
}
__device__ __forceinline__ void atomicMaxF(float* addr, float val) {
  int* ai = (int*)addr;
  while (true) {
    float cur = __int_as_float(*(volatile int*)ai);
    if (val <= cur) break;
    int old = atomicCAS(ai, __float_as_int(cur), __float_as_int(val));
    if (old == __float_as_int(cur)) break;
  }
}

// ---------------- prep: all fp32->bf16 conversions + proj pad + inits (1 launch) ----------------
__global__ void prep_kernel(const float* __restrict__ x, const float* __restrict__ Wq,
                            const float* __restrict__ Wk, const float* __restrict__ Wv,
                            const float* __restrict__ Wo, const float* __restrict__ proj,
                            unsigned short* __restrict__ xbf, unsigned short* __restrict__ wqb,
                            unsigned short* __restrict__ wkb, unsigned short* __restrict__ wvb,
                            unsigned short* __restrict__ wob,
                            unsigned short* __restrict__ projp,
                            float* __restrict__ kmax, float* __restrict__ ksuma) {
  const int t0 = blockIdx.x * 256 + threadIdx.x;
  const int stride = gridDim.x * 256;
  for (int i = t0; i < 8388608 / 4; i += stride) {
    const float4 v = ((const float4*)x)[i];
    ushort4 u;
    u.x = f2bf(v.x); u.y = f2bf(v.y); u.z = f2bf(v.z); u.w = f2bf(v.w);
    ((ushort4*)xbf)[i] = u;
  }
  const float* wsrc[4] = {Wq, Wk, Wv, Wo};
  unsigned short* wdst[4] = {wqb, wkb, wvb, wob};
#pragma unroll
  for (int w = 0; w < 4; ++w) {
    for (int i = t0; i < 262144 / 4; i += stride) {
      const float4 v = ((const float4*)wsrc[w])[i];
      ushort4 u;
      u.x = f2bf(v.x); u.y = f2bf(v.y); u.z = f2bf(v.z); u.w = f2bf(v.w);
      ((ushort4*)wdst[w])[i] = u;
    }
  }
  for (int j = t0; j < MP3_ * DH_; j += stride)
    projp[j] = (j < M_ * DH_) ? f2bf(proj[j]) : (unsigned short)0;
  for (int j = t0; j < BH_; j += stride) kmax[j] = -3e38f;
  for (int j = t0; j < BH_ * MP3_; j += stride) ksuma[j] = 0.f;
}

// ---------------- QKV projection: 128x128 MFMA GEMM, global_load_lds staging ----------------
// r7-proven structure: single-buffer staging (4 blocks/CU), direct ushort4 epilogue
// (measured write-clean: 50.2 MB = Q+K+VT ideal). Only diff vs r7: none in this kernel.
__global__ __launch_bounds__(256) void qkv_mfma(
    const unsigned short* __restrict__ x, const unsigned short* __restrict__ Wq,
    const unsigned short* __restrict__ Wk, const unsigned short* __restrict__ Wv,
    unsigned short* __restrict__ Q, unsigned short* __restrict__ K,
    unsigned short* __restrict__ VT) {
  __shared__ unsigned short As[128 * 64];
  __shared__ unsigned short Bs[128 * 64];
  const int z = blockIdx.z;
  const unsigned short* W = (z == 0) ? Wq : (z == 1) ? Wk : Wv;
  const int t0 = blockIdx.x * 128, e0 = blockIdx.y * 128;
  const int tid = threadIdx.x;
  const int wv = tid >> 6, lane = tid & 63;
  const int r = lane & 15, q = lane >> 4;
  const int wr = (wv >> 1) * 64, wc = (wv & 1) * 64;
  f32x4 acc[4][4];
#pragma unroll
  for (int i = 0; i < 4; ++i)
#pragma unroll
    for (int j = 0; j < 4; ++j) acc[i][j] = (f32x4){0.f, 0.f, 0.f, 0.f};
  // staging: wave wv covers rows wv*32 + j*8 + (lane>>3), col (lane&7)*8
  const int lrow = lane >> 3, lcol = (lane & 7) * 8;
  for (int k0 = 0; k0 < DIM_; k0 += 64) {
#pragma unroll
    for (int j = 0; j < 4; ++j) {
      const int rr = wv * 32 + j * 8;
      gload16(&x[(size_t)(t0 + rr + lrow) * DIM_ + k0 + lcol], &As[rr * 64]);
      gload16(&W[(size_t)(e0 + rr + lrow) * DIM_ + k0 + lcol], &Bs[rr * 64]);
    }
    __syncthreads();
#pragma unroll
    for (int kc = 0; kc < 2; ++kc) {
      bf16x8 af[4], bfr[4];
#pragma unroll
      for (int rt = 0; rt < 4; ++rt)
        af[rt] = *(const bf16x8*)&As[(wr + rt * 16 + r) * 64 + kc * 32 + q * 8];
#pragma unroll
      for (int ct = 0; ct < 4; ++ct)
        bfr[ct] = *(const bf16x8*)&Bs[(wc + ct * 16 + r) * 64 + kc * 32 + q * 8];
#pragma unroll
      for (int rt = 0; rt < 4; ++rt)
#pragma unroll
        for (int ct = 0; ct < 4; ++ct)
          acc[rt][ct] = MFMA16(af[rt], bfr[ct], acc[rt][ct]);
    }
    __syncthreads();
  }
  if (z < 2) {
    unsigned short* dst = (z == 0) ? Q : K;
#pragma unroll
    for (int rt = 0; rt < 4; ++rt) {
#pragma unroll
      for (int ct = 0; ct < 4; ++ct) {
        const int e = e0 + wc + ct * 16 + r;
#pragma unroll
        for (int i = 0; i < 4; ++i) {
          const int t = t0 + wr + rt * 16 + q * 4 + i;
          dst[(size_t)t * DIM_ + e] = f2bf(acc[rt][ct][i]);
        }
      }
    }
  } else {
#pragma unroll
    for (int rt = 0; rt < 4; ++rt) {
      const int t = t0 + wr + rt * 16 + q * 4;
      const int b_ = t >> 12, n = t & (N_ - 1);
#pragma unroll
      for (int ct = 0; ct < 4; ++ct) {
        const int e = e0 + wc + ct * 16 + r;
        const int h = e >> 6, dh = e & 63;
        ushort4 pk;
        pk.x = f2bf(acc[rt][ct][0]); pk.y = f2bf(acc[rt][ct][1]);
        pk.z = f2bf(acc[rt][ct][2]); pk.w = f2bf(acc[rt][ct][3]);
        *(ushort4*)&VT[((size_t)((b_ * H_ + h) * DH_ + dh)) * N_ + n] = pk;
      }
    }
  }
}

// ---------------- kmax/qmax (MFMA, merged) + diag: K global max, Q per-row max, diag_q/k ----------------
__global__ __launch_bounds__(256) void kmax_mfma(
    const unsigned short* __restrict__ K, const unsigned short* __restrict__ Qb,
    const unsigned short* __restrict__ projp,
    float* __restrict__ kmax, float* __restrict__ rmaxq,
    unsigned short* __restrict__ dq, unsigned short* __restrict__ dk) {
  __shared__ unsigned short sP[MP_][72];
  __shared__ float wm[4];
  const int bh = blockIdx.x, n0 = blockIdx.y * 256;
  const int tid = threadIdx.x;
  const int wv = tid >> 6, lane = tid & 63;
  const int r = lane & 15, q = lane >> 4;
  const int b_ = bh >> 3, h = bh & 7;
  // stage proj rows 0..271 (coalesced 16B chunks)
  for (int c = tid; c < MP_ * 4; c += 256) {
    const int row = c >> 2, cb = (c & 3) * 8;
    *(uint4*)&sP[row][cb] = *(const uint4*)&projp[row * DH_ + cb];
  }
  // load 4 K-strips + 4 Q-strips: rows nbase + st*16 + r
  bf16x8 kb[4][2], qb[4][2];
  const int nbase = n0 + wv * 64;
#pragma unroll
  for (int st = 0; st < 4; ++st) {
    const size_t off = (size_t)(b_ * N_ + nbase + st * 16 + r) * DIM_ + h * DH_;
    kb[st][0] = *(const bf16x8*)(K + off + q * 8);
    kb[st][1] = *(const bf16x8*)(K + off + 32 + q * 8);
    qb[st][0] = *(const bf16x8*)(Qb + off + q * 8);
    qb[st][1] = *(const bf16x8*)(Qb + off + 32 + q * 8);
  }
  // diag (merged): each lane holds 16 of the row's 64 values; q-butterfly completes the sum
#pragma unroll
  for (int st = 0; st < 4; ++st) {
    float sk = 0.f, sq = 0.f;
#pragma unroll
    for (int p = 0; p < 2; ++p)
#pragma unroll
      for (int e = 0; e < 8; ++e) {
        const float kv = (float)kb[st][p][e];
        const float qv = (float)qb[st][p][e];
        sk += kv * kv;
        sq += qv * qv;
      }
    sk += __shfl_xor(sk, 16, 64); sk += __shfl_xor(sk, 32, 64);
    sq += __shfl_xor(sq, 16, 64); sq += __shfl_xor(sq, 32, 64);
    if (q == 0) {
      dk[bh * N_ + nbase + st * 16 + r] = f2bf(sk * DIAGC);
      dq[bh * N_ + nbase + st * 16 + r] = f2bf(sq * DIAGC);
    }
  }
  __syncthreads();
  float km = -3e38f;
  float qm[4] = {-3e38f, -3e38f, -3e38f, -3e38f};
  for (int mt = 0; mt < 17; ++mt) {
    const bf16x8 p0 = *(const bf16x8*)&sP[mt * 16 + r][q * 8];
    const bf16x8 p1 = *(const bf16x8*)&sP[mt * 16 + r][32 + q * 8];
#pragma unroll
    for (int st = 0; st < 4; ++st) {
      f32x4 ka = (f32x4){0.f, 0.f, 0.f, 0.f};
      ka = MFMA16(p0, kb[st][0], ka);
      ka = MFMA16(p1, kb[st][1], ka);
      f32x4 qa = (f32x4){0.f, 0.f, 0.f, 0.f};
      qa = MFMA16(p0, qb[st][0], qa);
      qa = MFMA16(p1, qb[st][1], qa);
#pragma unroll
      for (int i = 0; i < 4; ++i) {
        const int m = mt * 16 + q * 4 + i;
        if (m < M_) {
          km = fmaxf(km, ka[i]);
          qm[st] = fmaxf(qm[st], qa[i]);
        }
      }
    }
  }
  // Q: per-row raw max -- combine the 4 q-groups (m coverage) per row
#pragma unroll
  for (int st = 0; st < 4; ++st) {
    float v = qm[st];
    v = fmaxf(v, __shfl_xor(v, 16, 64));
    v = fmaxf(v, __shfl_xor(v, 32, 64));
    if (q == 0) rmaxq[bh * N_ + nbase + st * 16 + r] = v;
  }
  // K: block max -> atomic
  for (int s2 = 1; s2 < 64; s2 <<= 1) km = fmaxf(km, __shfl_xor(km, s2, 64));
  if (lane == 0) wm[wv] = km;
  __syncthreads();
  if (tid == 0) {
    const float m = fmaxf(fmaxf(wm[0], wm[1]), fmaxf(wm[2], wm[3])) * NORMC;
    atomicMaxF(&kmax[bh], m);
  }
}

// ---------------- fused: td -> exp -> kp; ctx += kp x VT; ksum ----------------
__global__ __launch_bounds__(256) void ctxfused_mfma(
    const unsigned short* __restrict__ K, const unsigned short* __restrict__ VT,
    const unsigned short* __restrict__ projp, const unsigned short* __restrict__ diag_k,
    const float* __restrict__ kmaxv, float* __restrict__ ksuma,
    float* __restrict__ slab) {
  __shared__ unsigned short kll[64][72];
  __shared__ unsigned short vtl[64][72];
  __shared__ unsigned short kpl[64][72];
  __shared__ float dgl[64];
  const int bh = blockIdx.x, m0 = blockIdx.y * 64, zi = blockIdx.z;
  const int nbase = zi * 512;
  const int tid = threadIdx.x;
  const int wv = tid >> 6, lane = tid & 63;
  const int r = lane & 15, q = lane >> 4;
  const int b_ = bh >> 3, h = bh & 7;
  const float km = kmaxv[bh];
  const unsigned short* prow = projp + (size_t)(m0 + wv * 16 + r) * DH_;
  const bf16x8 p0 = *(const bf16x8*)(prow + q * 8);
  const bf16x8 p1 = *(const bf16x8*)(prow + 32 + q * 8);
  const unsigned short* kbase = K + (size_t)(b_ * N_) * DIM_ + h * DH_;
  const unsigned short* vbase = VT + (size_t)bh * DH_ * N_;
  f32x4 cacc[4];
#pragma unroll
  for (int i = 0; i < 4; ++i) cacc[i] = (f32x4){0.f, 0.f, 0.f, 0.f};
  float ksa[4] = {0.f, 0.f, 0.f, 0.f};
  for (int nc = 0; nc < 8; ++nc) {
    const int n0c = nbase + nc * 64;
#pragma unroll
    for (int j = 0; j < 4; ++j) {
      const int idx = tid + j * 256;
      const int rr = idx >> 4, c4 = (idx & 15) << 2;
      *(ushort4*)&kll[rr][c4] = *(const ushort4*)&kbase[(size_t)(n0c + rr) * DIM_ + c4];
      *(ushort4*)&vtl[rr][c4] = *(const ushort4*)&vbase[(size_t)rr * N_ + n0c + c4];
    }
    if (tid < 16) {
      const ushort4 du = *(const ushort4*)&diag_k[bh * N_ + n0c + tid * 4];
      dgl[tid * 4 + 0] = bfu(du.x); dgl[tid * 4 + 1] = bfu(du.y);
      dgl[tid * 4 + 2] = bfu(du.z); dgl[tid * 4 + 3] = bfu(du.w);
    }
    __syncthreads();
#pragma unroll
    for (int nt = 0; nt < 4; ++nt) {
      const bf16x8 kb0 = *(const bf16x8*)&kll[nt * 16 + r][q * 8];
      const bf16x8 kb1 = *(const bf16x8*)&kll[nt * 16 + r][32 + q * 8];
      f32x4 acc = (f32x4){0.f, 0.f, 0.f, 0.f};
      acc = MFMA16(p0, kb0, acc);
      acc = MFMA16(p1, kb1, acc);
      const float dgk = dgl[nt * 16 + r];
#pragma unroll
      for (int i = 0; i < 4; ++i) {
        const int m = m0 + wv * 16 + q * 4 + i;
        float kp = 0.f;
        if (m < M_) {
          const float arg = fminf(NORMC * acc[i] - dgk - km, 0.f);
          kp = RATIOC * (__expf(arg) + EPSK);
        }
        kpl[wv * 16 + q * 4 + i][nt * 16 + r] = f2bf(kp);
        ksa[i] += kp;
      }
    }
    __syncthreads();
    {
      const bf16x8 a0 = *(const bf16x8*)&kpl[wv * 16 + r][q * 8];
      const bf16x8 a1 = *(const bf16x8*)&kpl[wv * 16 + r][32 + q * 8];
#pragma unroll
      for (int ct = 0; ct < 4; ++ct) {
        const bf16x8 b0 = *(const bf16x8*)&vtl[ct * 16 + r][q * 8];
        const bf16x8 b1 = *(const bf16x8*)&vtl[ct * 16 + r][32 + q * 8];
        cacc[ct] = MFMA16(a0, b0, cacc[ct]);
        cacc[ct] = MFMA16(a1, b1, cacc[ct]);
      }
    }
    __syncthreads();
  }
#pragma unroll
  for (int i = 0; i < 4; ++i)
    for (int s2 = 1; s2 < 16; s2 <<= 1) ksa[i] += __shfl_xor(ksa[i], s2, 64);
  if (r == 0) {
#pragma unroll
    for (int i = 0; i < 4; ++i)
      atomicAdd(&ksuma[bh * MP3_ + m0 + wv * 16 + q * 4 + i], ksa[i]);
  }
  float* sl = slab + (size_t)(bh * NZ_ + zi) * SLABM_ * DH_;
#pragma unroll
  for (int ct = 0; ct < 4; ++ct) {
#pragma unroll
    for (int i = 0; i < 4; ++i) {
      const int m = m0 + wv * 16 + q * 4 + i;
      if (m < SLABM_) sl[(size_t)m * DH_ + ct * 16 + r] = cacc[ct][i];
    }
  }
}

// ---------------- pack: reduce 8 z-slabs [m][d] fp32 -> transpose -> ctxT [d][288] bf16 ----
__global__ __launch_bounds__(256) void pack_kernel(const float* __restrict__ slab,
                                                   unsigned short* __restrict__ ctxT) {
  __shared__ float t[64][65];
  const int bh = blockIdx.x, m0 = blockIdx.y * 64;
  const int tid = threadIdx.x;
  const int mr = tid >> 4, d4 = (tid & 15) * 4;
#pragma unroll
  for (int pass = 0; pass < 4; ++pass) {
    const int ml = pass * 16 + mr;
    const int m = m0 + ml;
    float4 s = {0.f, 0.f, 0.f, 0.f};
    if (m < SLABM_) {
#pragma unroll
      for (int z = 0; z < NZ_; ++z) {
        const float4 v =
            *(const float4*)&slab[((size_t)(bh * NZ_ + z) * SLABM_ + m) * DH_ + d4];
        s.x += v.x; s.y += v.y; s.z += v.z; s.w += v.w;
      }
    }
    t[ml][d4 + 0] = s.x; t[ml][d4 + 1] = s.y; t[ml][d4 + 2] = s.z; t[ml][d4 + 3] = s.w;
  }
  __syncthreads();
  const int mc = tid & 63, dbase = tid >> 6;
  const int mo = m0 + mc;
  if (mo < MP2_) {
#pragma unroll
    for (int j = 0; j < 16; ++j) {
      const int d = dbase + j * 4;
      ctxT[((size_t)bh * DH_ + d) * MP2_ + mo] = f2bf(t[mc][d]);
    }
  }
}

// ---------------- fused QP + out GEMM: LDS-staged proj (time-shared with qp tile) ----------------
__global__ __launch_bounds__(256) void qpout_mfma(
    const unsigned short* __restrict__ Qb, const unsigned short* __restrict__ projp,
    const float* __restrict__ rmaxq,
    const unsigned short* __restrict__ diag_q, const float* __restrict__ ksuma,
    const unsigned short* __restrict__ ctxT, unsigned short* __restrict__ attn) {
  __shared__ union SM {
    unsigned short sP[MP_][72];      // 39168 B  (phase B)
    unsigned int qps[4][16][149];    // 38144 B  (phase C; per-wave tile, stride 149 u32)
  } sm;
  const int bh = blockIdx.x, n0 = blockIdx.y * 64;
  const int tid = threadIdx.x;
  const int wv = tid >> 6, lane = tid & 63;
  const int r = lane & 15, q = lane >> 4;
  const int b_ = bh >> 3, h = bh & 7;
  // stage proj rows 0..271 into sP (coalesced 16B chunks)
  for (int c = tid; c < MP_ * 4; c += 256) {
    const int row = c >> 2, cb = (c & 3) * 8;
    *(uint4*)&sm.sP[row][cb] = *(const uint4*)&projp[row * DH_ + cb];
  }
  bf16x8 qb0, qb1;
  {
    const unsigned short* qrow = Qb + (size_t)(b_ * N_ + n0 + wv * 16 + r) * DIM_ + h * DH_;
    qb0 = *(const bf16x8*)(qrow + q * 8);
    qb1 = *(const bf16x8*)(qrow + 32 + q * 8);
  }
  const float rm = rmaxq[bh * N_ + n0 + wv * 16 + r];
  const float dg = bfu(diag_q[bh * N_ + n0 + wv * 16 + r]);
  const float Cl = LOG2R - dg * LOG2E - rm * KA;
  __syncthreads();
  // phase B: td -> exp+pack -> registers; denominator partial (rounded qp)
  unsigned int pk0[17], pk1[17];
  float part = 0.f;
#pragma unroll
  for (int mt = 0; mt < 17; ++mt) {
    const bf16x8 p0 = *(const bf16x8*)&sm.sP[mt * 16 + r][q * 8];
    const bf16x8 p1 = *(const bf16x8*)&sm.sP[mt * 16 + r][32 + q * 8];
    f32x4 acc = (f32x4){0.f, 0.f, 0.f, 0.f};
    acc = MFMA16(p0, qb0, acc);
    acc = MFMA16(p1, qb1, acc);
    const f32x4 kl = *(const f32x4*)&ksuma[bh * MP3_ + mt * 16 + q * 4];
    {
      const float s0 = fminf(acc[0] * KA + Cl, LOG2R);
      const float s1 = fminf(acc[1] * KA + Cl, LOG2R);
      const float e0 = exp2f(s0) + REPS;
      const float e1 = exp2f(s1) + REPS;
      unsigned int pkk;
      asm("v_cvt_pk_bf16_f32 %0, %1, %2" : "=v"(pkk) : "v"(e0), "v"(e1));
      pk0[mt] = pkk;
      union { unsigned int u; float f; } lo, hi;
      lo.u = pkk << 16; hi.u = pkk & 0xffff0000u;
      part += lo.f * kl[0] + hi.f * kl[1];
    }
    {
      const float s0 = fminf(acc[2] * KA + Cl, LOG2R);
      const float s1 = fminf(acc[3] * KA + Cl, LOG2R);
      const float e0 = exp2f(s0) + REPS;
      const float e1 = exp2f(s1) + REPS;
      unsigned int pkk;
      asm("v_cvt_pk_bf16_f32 %0, %1, %2" : "=v"(pkk) : "v"(e0), "v"(e1));
      pk1[mt] = pkk;
      union { unsigned int u; float f; } lo, hi;
      lo.u = pkk << 16; hi.u = pkk & 0xffff0000u;
      part += lo.f * kl[2] + hi.f * kl[3];
    }
  }
  __syncthreads();  // all waves done reading sP; LDS becomes qps
  // dump packed qp regs -> wave-private qps tile (row r, u32 cols mt*8 + q*2)
#pragma unroll
  for (int mt = 0; mt < 17; ++mt)
    *(uint2*)&sm.qps[wv][r][mt * 8 + q * 2] = make_uint2(pk0[mt], pk1[mt]);
  // zero pad u32 cols 136..143 (bf16 cols 272..287)
  *(uint2*)&sm.qps[wv][r][136 + q * 2] = make_uint2(0u, 0u);
  part += __shfl_xor(part, 16, 64);
  part += __shfl_xor(part, 32, 64);
  const float dinv = 1.f / fmaxf(part, 1e-30f);
  // Phase C: out = qp . ctxT (K = 288); A-frags from wave-private LDS tile
  f32x4 oacc[4];
#pragma unroll
  for (int i = 0; i < 4; ++i) oacc[i] = (f32x4){0.f, 0.f, 0.f, 0.f};
  const unsigned short* cbase = ctxT + (size_t)bh * DH_ * MP2_;
#pragma unroll
  for (int kc = 0; kc < 9; ++kc) {
    const bf16x8 af = *(const bf16x8*)&sm.qps[wv][r][kc * 16 + q * 4];
#pragma unroll
    for (int dt = 0; dt < 4; ++dt) {
      const bf16x8 bfr = *(const bf16x8*)&cbase[(size_t)(dt * 16 + r) * MP2_ + kc * 32 + q * 8];
      oacc[dt] = MFMA16(af, bfr, oacc[dt]);
    }
  }
  // dinv lives at lane with r = n-local; output rows n-local = q*4+i
  float dv[4];
#pragma unroll
  for (int i = 0; i < 4; ++i)
    dv[i] = __shfl(dinv, (lane & 48) | (q * 4 + i), 64);
#pragma unroll
  for (int dt = 0; dt < 4; ++dt) {
    const int d = dt * 16 + r;
#pragma unroll
    for (int i = 0; i < 4; ++i) {
      const int nn = wv * 16 + q * 4 + i;
      attn[(size_t)(b_ * N_ + n0 + nn) * DIM_ + h * DH_ + d] = f2bf(oacc[dt][i] * dv[i]);
    }
  }
}

// ---------------- final: 128x128 MFMA GEMM + residual, global_load_lds staging ----------------
__global__ __launch_bounds__(256) void final_mfma(
    const unsigned short* __restrict__ attn, const unsigned short* __restrict__ Wo,
    const float* __restrict__ bo, const float* __restrict__ x,
    float* __restrict__ out) {
  __shared__ unsigned short As[128 * 64];
  __shared__ unsigned short Bs[128 * 64];
  const int t0 = blockIdx.x * 128, e0 = blockIdx.y * 128;
  const int tid = threadIdx.x;
  const int wv = tid >> 6, lane = tid & 63;
  const int r = lane & 15, q = lane >> 4;
  const int wr = (wv >> 1) * 64, wc = (wv & 1) * 64;
  f32x4 acc[4][4];
#pragma unroll
  for (int i = 0; i < 4; ++i)
#pragma unroll
    for (int j = 0; j < 4; ++j) acc[i][j] = (f32x4){0.f, 0.f, 0.f, 0.f};
  const int lrow = lane >> 3, lcol = (lane & 7) * 8;
  for (int k0 = 0; k0 < DIM_; k0 += 64) {
#pragma unroll
    for (int j = 0; j < 4; ++j) {
      const int rr = wv * 32 + j * 8;
      gload16(&attn[(size_t)(t0 + rr + lrow) * DIM_ + k0 + lcol], &As[rr * 64]);
      gload16(&Wo[(size_t)(e0 + rr + lrow) * DIM_ + k0 + lcol], &Bs[rr * 64]);
    }
    __syncthreads();
#pragma unroll
    for (int kc = 0; kc < 2; ++kc) {
      bf16x8 af[4], bfr[4];
#pragma unroll
      for (int rt = 0; rt < 4; ++rt)
        af[rt] = *(const bf16x8*)&As[(wr + rt * 16 + r) * 64 + kc * 32 + q * 8];
#pragma unroll
      for (int ct = 0; ct < 4; ++ct)
        bfr[ct] = *(const bf16x8*)&Bs[(wc + ct * 16 + r) * 64 + kc * 32 + q * 8];
#pragma unroll
      for (int rt = 0; rt < 4; ++rt)
#pragma unroll
        for (int ct = 0; ct < 4; ++ct)
          acc[rt][ct] = MFMA16(af[rt], bfr[ct], acc[rt][ct]);
    }
    __syncthreads();
  }
#pragma unroll
  for (int rt = 0; rt < 4; ++rt) {
#pragma unroll
    for (int ct = 0; ct < 4; ++ct) {
      const int c = e0 + wc + ct * 16 + r;
      const float bov = bo[c];
#pragma unroll
      for (int i = 0; i < 4; ++i) {
        const int t = t0 + wr + rt * 16 + q * 4 + i;
        out[(size_t)t * DIM_ + c] = acc[rt][ct][i] + bov + x[(size_t)t * DIM_ + c];
      }
    }
  }
}

extern "C" void kernel_launch(void* const* d_in, const int* in_sizes, int n_in,
                              void* d_out, int out_size, void* d_ws, size_t ws_size,
                              hipStream_t stream) {
  const float* x = (const float*)d_in[0];
  const float* Wq = (const float*)d_in[1];
  const float* Wk = (const float*)d_in[2];
  const float* Wv = (const float*)d_in[3];
  const float* Wo = (const float*)d_in[4];
  const float* bo = (const float*)d_in[5];
  const float* proj = (const float*)d_in[6];
  char* ws = (char*)d_ws;
  unsigned short* projp = (unsigned short*)(ws + PROJP_B);
  float* kmax = (float*)(ws + KMAX_B);
  float* ksuma = (float*)(ws + KSUMA_B);
  float* ctxa = (float*)(ws + CTXA_B);
  unsigned short* ctxT = (unsigned short*)(ws + CTXT_B);
  unsigned short* diag_q = (unsigned short*)(ws + DIAGQ_B);
  unsigned short* diag_k = (unsigned short*)(ws + DIAGK_B);
  unsigned short* xbf = (unsigned short*)(ws + XBF_B);
  unsigned short* wqb = (unsigned short*)(ws + WQ_B);
  unsigned short* wkb = (unsigned short*)(ws + WK_B);
  unsigned short* wvb = (unsigned short*)(ws + WV_B);
  unsigned short* wob = (unsigned short*)(ws + WO_B);
  unsigned short* Q = (unsigned short*)(ws + Q_B);
  unsigned short* K = (unsigned short*)(ws + K_B);
  unsigned short* VT = (unsigned short*)(ws + VT_B);
  float* rmaxq = (float*)(ws + RMAXQ_B);
  unsigned short* attn = K;  // K dead after ctxfused_mfma
  float* out = (float*)d_out;

  prep_kernel<<<1024, 256, 0, stream>>>(x, Wq, Wk, Wv, Wo, proj,
                                        xbf, wqb, wkb, wvb, wob, projp, kmax, ksuma);
  qkv_mfma<<<dim3(NT_ / 128, DIM_ / 128, 3), 256, 0, stream>>>(xbf, wqb, wkb, wvb, Q, K, VT);
  kmax_mfma<<<dim3(BH_, N_ / 256), 256, 0, stream>>>(K, Q, projp, kmax, rmaxq, diag_q, diag_k);
  ctxfused_mfma<<<dim3(BH_, 5, NZ_), 256, 0, stream>>>(K, VT, projp, diag_k, kmax, ksuma, ctxa);
  pack_kernel<<<dim3(BH_, 5), 256, 0, stream>>>(ctxa, ctxT);
  qpout_mfma<<<dim3(BH_, 64), 256, 0, stream>>>(Q, projp, rmaxq, diag_q, ksuma, ctxT, attn);
  final_mfma<<<dim3(NT_ / 128, DIM_ / 128), 256, 0, stream>>>(attn, wob, bo, x, out);
}